// Round 1
// 473.612 us; speedup vs baseline: 1.1107x; 1.1107x over previous
//
#include <hip/hip_runtime.h>
#include <hip/hip_bf16.h>

#define S_LEN 4096
#define HDIM  2048
#define NHQ   8
#define NKVH  2
#define DHEAD 256
#define WIN   512
#define NQKV  3072   // fused q+k+v projection width (2048 + 512 + 512)

typedef __hip_bfloat16 bf16_t;
using fragAB = __attribute__((ext_vector_type(8))) short;  // 8 bf16
using fragC  = __attribute__((ext_vector_type(4))) float;  // 4 fp32

typedef unsigned int u32;
typedef const __attribute__((address_space(1))) u32* gas_ptr;
typedef __attribute__((address_space(3))) u32* las_ptr;

__device__ __forceinline__ void async_copy16(const void* g, void* l) {
  __builtin_amdgcn_global_load_lds((gas_ptr)g, (las_ptr)l, 16, 0, 0);
}

#define NEG_BIG (-3.0e38f)

__device__ __forceinline__ void split2(float x, bf16_t& hi, bf16_t& lo) {
  bf16_t h = __float2bfloat16(x);
  hi = h;
  lo = __float2bfloat16(x - (float)h);
}

// ---------------------------------------------------------------------------
// Elementwise split fp32 -> bf16 hi + bf16 lo  (n multiple of 1024)
// ---------------------------------------------------------------------------
__global__ __launch_bounds__(256) void split_f32(
    const float* __restrict__ in, bf16_t* __restrict__ hi,
    bf16_t* __restrict__ lo, int n) {
  int i = (blockIdx.x * 256 + threadIdx.x) * 4;
  if (i >= n) return;
  float4 v = *(const float4*)(in + i);
  split2(v.x, hi[i + 0], lo[i + 0]);
  split2(v.y, hi[i + 1], lo[i + 1]);
  split2(v.z, hi[i + 2], lo[i + 2]);
  split2(v.w, hi[i + 3], lo[i + 3]);
}

// ---------------------------------------------------------------------------
// Transpose+convert fp32 [R][C] -> bf16 [C][R]
// ---------------------------------------------------------------------------
__global__ __launch_bounds__(256) void transpose_cvt(
    const float* __restrict__ in, bf16_t* __restrict__ out, int R, int C) {
  __shared__ bf16_t tile[32][33];
  int c0 = blockIdx.x * 32, r0 = blockIdx.y * 32;
  int tx = threadIdx.x & 31, ty = threadIdx.x >> 5;
#pragma unroll
  for (int i = 0; i < 4; ++i)
    tile[ty + i * 8][tx] = __float2bfloat16(in[(size_t)(r0 + ty + i * 8) * C + c0 + tx]);
  __syncthreads();
#pragma unroll
  for (int i = 0; i < 4; ++i)
    out[(size_t)(c0 + ty + i * 8) * R + r0 + tx] = tile[tx][ty + i * 8];
}

// ---------------------------------------------------------------------------
// Transpose+split fp32 [R][C] -> bf16 hi [C][R], bf16 lo [C][R]
// ---------------------------------------------------------------------------
__global__ __launch_bounds__(256) void transpose_split(
    const float* __restrict__ in, bf16_t* __restrict__ hiT,
    bf16_t* __restrict__ loT, int R, int C) {
  __shared__ bf16_t th[32][33];
  __shared__ bf16_t tl[32][33];
  int c0 = blockIdx.x * 32, r0 = blockIdx.y * 32;
  int tx = threadIdx.x & 31, ty = threadIdx.x >> 5;
#pragma unroll
  for (int i = 0; i < 4; ++i) {
    float x = in[(size_t)(r0 + ty + i * 8) * C + c0 + tx];
    bf16_t h, l; split2(x, h, l);
    th[ty + i * 8][tx] = h;
    tl[ty + i * 8][tx] = l;
  }
  __syncthreads();
#pragma unroll
  for (int i = 0; i < 4; ++i) {
    hiT[(size_t)(c0 + ty + i * 8) * R + r0 + tx] = th[tx][ty + i * 8];
    loT[(size_t)(c0 + ty + i * 8) * R + r0 + tx] = tl[tx][ty + i * 8];
  }
}

// ---------------------------------------------------------------------------
// Plain GEMM: C[M][N] = A[M][K]*Bt[N][K]^T; bf16 in, fp32 accum, OutT out.
// ---------------------------------------------------------------------------
template <typename OutT>
__global__ __launch_bounds__(256) void gemm_bt(
    const bf16_t* __restrict__ A, const bf16_t* __restrict__ Bt,
    OutT* __restrict__ C, int M, int N, int K) {
  __shared__ __align__(16) bf16_t As[128 * 32];
  __shared__ __align__(16) bf16_t Bs[128 * 32];
  const int t = threadIdx.x;
  const int wave = t >> 6, lane = t & 63;
  const int quad = lane >> 4, l16 = lane & 15;
  const int m0 = blockIdx.y * 128, n0 = blockIdx.x * 128;
  const int wm = (wave >> 1) * 64, wn = (wave & 1) * 64;

  fragC zero4 = {0.f, 0.f, 0.f, 0.f};
  fragC acc[4][4];
#pragma unroll
  for (int i = 0; i < 4; ++i)
#pragma unroll
    for (int j = 0; j < 4; ++j) acc[i][j] = zero4;

  int rowS[2], colS[2];
#pragma unroll
  for (int i = 0; i < 2; ++i) {
    int e = (wave * 2048 + i * 1024 + lane * 16) >> 1;
    rowS[i] = e >> 5;
    colS[i] = e & 31;
  }

  for (int k0 = 0; k0 < K; k0 += 32) {
#pragma unroll
    for (int i = 0; i < 2; ++i) {
      async_copy16(A + (size_t)(m0 + rowS[i]) * K + k0 + colS[i],
                   (char*)As + wave * 2048 + i * 1024);
      async_copy16(Bt + (size_t)(n0 + rowS[i]) * K + k0 + colS[i],
                   (char*)Bs + wave * 2048 + i * 1024);
    }
    __syncthreads();
    fragAB af[4], bfr[4];
#pragma unroll
    for (int i = 0; i < 4; ++i) {
      af[i]  = *(const fragAB*)((const char*)As + (wm + i * 16 + l16) * 64 + quad * 16);
      bfr[i] = *(const fragAB*)((const char*)Bs + (wn + i * 16 + l16) * 64 + quad * 16);
    }
#pragma unroll
    for (int i = 0; i < 4; ++i)
#pragma unroll
      for (int j = 0; j < 4; ++j)
        acc[i][j] = __builtin_amdgcn_mfma_f32_16x16x32_bf16(af[i], bfr[j], acc[i][j], 0, 0, 0);
    __syncthreads();
  }

#pragma unroll
  for (int i = 0; i < 4; ++i)
#pragma unroll
    for (int j = 0; j < 4; ++j)
#pragma unroll
      for (int r = 0; r < 4; ++r) {
        int row = m0 + wm + i * 16 + quad * 4 + r;
        int col = n0 + wn + j * 16 + l16;
        float v = acc[i][j][r];
        if constexpr (sizeof(OutT) == 2)
          C[(size_t)row * N + col] = (OutT)__float2bfloat16(v);
        else
          C[(size_t)row * N + col] = (OutT)v;
      }
}

// ---------------------------------------------------------------------------
// Split-precision GEMM v2: C = Ah*Bh + Ah*Bl + Al*Bh, pipelined.
// BM=256, BN=192, BK=32, 512 threads (8 waves, 2M x 4N).
// Double-buffered LDS (112 KB), counted vmcnt, raw barriers, T2 XOR swizzle,
// setprio around MFMA clusters. Each wave issues exactly 7 global_load_lds
// per K-step in consumption order: B(3), A-region 0..3.
// ---------------------------------------------------------------------------
#define OFF_AH 0
#define OFF_AL 16384
#define OFF_BH 32768
#define OFF_BL 45056
#define BUFSZ  57344

#define VMCNT_(n) asm volatile("s_waitcnt vmcnt(" #n ")" ::: "memory")
#define VMCNT(n) VMCNT_(n)
#define BARRIER()                     \
  {                                   \
    asm volatile("" ::: "memory");    \
    __builtin_amdgcn_s_barrier();     \
    asm volatile("" ::: "memory");    \
  }

#define MFMA_(a, b, c) __builtin_amdgcn_mfma_f32_16x16x32_bf16(a, b, c, 0, 0, 0)

#define LOADB()                                                   \
  _Pragma("unroll")                                               \
  for (int j = 0; j < 3; ++j) {                                   \
    const char* bp_ = bufc + (wn + j * 16 + l16) * 64 + rdq;      \
    bh[j] = *(const fragAB*)(bp_ + OFF_BH);                       \
    bl[j] = *(const fragAB*)(bp_ + OFF_BL);                       \
  }

#define PHASEP(p)                                                        \
  {                                                                      \
    const char* a0p_ = bufc + (wm + (2 * (p)) * 16 + l16) * 64 + rdq;    \
    const char* a1p_ = bufc + (wm + (2 * (p) + 1) * 16 + l16) * 64 + rdq;\
    fragAB ah0 = *(const fragAB*)(a0p_ + OFF_AH);                        \
    fragAB al0 = *(const fragAB*)(a0p_ + OFF_AL);                        \
    fragAB ah1 = *(const fragAB*)(a1p_ + OFF_AH);                        \
    fragAB al1 = *(const fragAB*)(a1p_ + OFF_AL);                        \
    __builtin_amdgcn_s_setprio(1);                                       \
    _Pragma("unroll")                                                    \
    for (int j = 0; j < 3; ++j) {                                        \
      acc[2 * (p)][j]     = MFMA_(al0, bh[j], acc[2 * (p)][j]);          \
      acc[2 * (p)][j]     = MFMA_(ah0, bl[j], acc[2 * (p)][j]);          \
      acc[2 * (p)][j]     = MFMA_(ah0, bh[j], acc[2 * (p)][j]);          \
      acc[2 * (p) + 1][j] = MFMA_(al1, bh[j], acc[2 * (p) + 1][j]);      \
      acc[2 * (p) + 1][j] = MFMA_(ah1, bl[j], acc[2 * (p) + 1][j]);      \
      acc[2 * (p) + 1][j] = MFMA_(ah1, bh[j], acc[2 * (p) + 1][j]);      \
    }                                                                    \
    __builtin_amdgcn_s_setprio(0);                                       \
  }

__global__ __launch_bounds__(512, 2) void gemm_split2(
    const bf16_t* __restrict__ Ah, const bf16_t* __restrict__ Al,
    const bf16_t* __restrict__ Bh, const bf16_t* __restrict__ Bl,
    float* __restrict__ C, int M, int N, int K) {
  __shared__ __align__(16) char lds[2 * BUFSZ];
  const int t = threadIdx.x;
  const int wave = t >> 6, lane = t & 63;
  const int quad = lane >> 4, l16 = lane & 15;
  const int m0 = blockIdx.y * 256, n0 = blockIdx.x * 192;
  const int wm = (wave >> 2) * 128, wn = (wave & 3) * 48;
  // T2 read swizzle: phys 16B-slot of (row r, col-16B q) = r*4 + (q ^ ((r>>1)&3)).
  // For all read rows here (r>>1)&3 == (l16>>1)&3.
  const int rdq = (quad ^ ((l16 >> 1) & 3)) * 16;

  // Per-lane global source offset inside a 16-row x 32-col chunk (inverse swizzle):
  // lane l writes phys slot base+l -> fetches row (l>>2), col16 (l&3)^((l>>3)&3).
  const size_t laneOff =
      (size_t)(lane >> 2) * K * 2 + 16 * ((lane & 3) ^ ((lane >> 3) & 3));

  // 7 staging chunks per wave per K-step, in consumption order.
  const char* gsrc[7];
  int ldsOff[7];
#pragma unroll
  for (int pos = 0; pos < 3; ++pos) {
    int c = wave + 8 * pos;            // 0..23: Bh chunks 0..11, Bl chunks 0..11
    if (c < 12) {
      gsrc[pos]   = (const char*)Bh + (size_t)(n0 + 16 * c) * K * 2 + laneOff;
      ldsOff[pos] = OFF_BH + c * 1024;
    } else {
      gsrc[pos]   = (const char*)Bl + (size_t)(n0 + 16 * (c - 12)) * K * 2 + laneOff;
      ldsOff[pos] = OFF_BL + (c - 12) * 1024;
    }
  }
#pragma unroll
  for (int p = 0; p < 4; ++p) {
    // A region p = rows {32p..32p+31} U {128+32p..128+32p+31} (what phase p reads).
    int sub = wave & 3;
    int R0 = ((sub >> 1) & 1) * 128 + 32 * p + (sub & 1) * 16;
    const char* base = (const char*)(wave < 4 ? Ah : Al);
    gsrc[3 + p]   = base + (size_t)(m0 + R0) * K * 2 + laneOff;
    ldsOff[3 + p] = (wave < 4 ? OFF_AH : OFF_AL) + R0 * 64;
  }

  fragC zero4 = {0.f, 0.f, 0.f, 0.f};
  fragC acc[8][3];
#pragma unroll
  for (int i = 0; i < 8; ++i)
#pragma unroll
    for (int j = 0; j < 3; ++j) acc[i][j] = zero4;

  char* ldsc = (char*)lds;
  // prologue: stage K-step 0 into buffer 0
#pragma unroll
  for (int ps = 0; ps < 7; ++ps) async_copy16(gsrc[ps], ldsc + ldsOff[ps]);
#pragma unroll
  for (int ps = 0; ps < 7; ++ps) gsrc[ps] += 64;

  fragAB bh[3], bl[3];
  int cur = 0;
  const int NS = K / 32;
  for (int it = 0; it < NS - 1; ++it) {
    const char* bufc = ldsc + cur * BUFSZ;
    char* nb = ldsc + (cur ^ 1) * BUFSZ;
    // issue next K-step's 7 chunks (stay in flight across barriers)
#pragma unroll
    for (int ps = 0; ps < 7; ++ps) async_copy16(gsrc[ps], nb + ldsOff[ps]);
#pragma unroll
    for (int ps = 0; ps < 7; ++ps) gsrc[ps] += 64;
    // 14 outstanding; oldest 4 = this step's B + A-region0
    VMCNT(10); BARRIER();
    LOADB();
    PHASEP(0);
    VMCNT(9); BARRIER();
    PHASEP(1);
    VMCNT(8); BARRIER();
    PHASEP(2);
    VMCNT(7); BARRIER();
    PHASEP(3);
    BARRIER();  // all waves done reading bufc before next iter overwrites it
    cur ^= 1;
  }
  {  // final K-step: nothing in flight beyond this step's 7 chunks
    const char* bufc = ldsc + cur * BUFSZ;
    VMCNT(3); BARRIER();
    LOADB();
    PHASEP(0);
    VMCNT(2); BARRIER();
    PHASEP(1);
    VMCNT(1); BARRIER();
    PHASEP(2);
    VMCNT(0); BARRIER();
    PHASEP(3);
  }

#pragma unroll
  for (int i = 0; i < 8; ++i)
#pragma unroll
    for (int j = 0; j < 3; ++j)
#pragma unroll
      for (int r = 0; r < 4; ++r) {
        int row = m0 + wm + i * 16 + quad * 4 + r;
        int col = n0 + wn + j * 16 + l16;
        C[(size_t)row * N + col] = acc[i][j][r];
      }
}

// ---------------------------------------------------------------------------
// RMS-norm (+fp32 weight) + RoPE, fp32 in -> split bf16 hi/lo out.
// proj row stride inStride, head-block starts at inOff. Output stride outStride.
// ---------------------------------------------------------------------------
__global__ __launch_bounds__(256) void rmsnorm_rope_split(
    const float* __restrict__ proj, const float* __restrict__ w,
    const float* __restrict__ cosb, const float* __restrict__ sinb,
    bf16_t* __restrict__ qhi, bf16_t* __restrict__ qlo,
    int inStride, int inOff, int outStride) {
  int s = blockIdx.x, h = blockIdx.y, d = threadIdx.x;
  float x = proj[(size_t)s * inStride + inOff + h * DHEAD + d];
  float ss = x * x;
  ss += __shfl_xor(ss, 1);  ss += __shfl_xor(ss, 2);  ss += __shfl_xor(ss, 4);
  ss += __shfl_xor(ss, 8);  ss += __shfl_xor(ss, 16); ss += __shfl_xor(ss, 32);
  __shared__ float part[4];
  __shared__ float xs[DHEAD];
  if ((threadIdx.x & 63) == 0) part[threadIdx.x >> 6] = ss;
  __syncthreads();
  float tot = part[0] + part[1] + part[2] + part[3];
  float r = rsqrtf(tot * (1.0f / DHEAD) + 1e-6f);
  float xn = x * r * w[d];
  xs[d] = xn;
  __syncthreads();
  float other = xs[(d + 128) & 255];
  float rot = (d < 128) ? -other : other;
  float y = xn * cosb[(size_t)s * DHEAD + d] + rot * sinb[(size_t)s * DHEAD + d];
  bf16_t h2, l2; split2(y, h2, l2);
  size_t oidx = (size_t)s * outStride + h * DHEAD + d;
  qhi[oidx] = h2;
  qlo[oidx] = l2;
}

// ---------------------------------------------------------------------------
// RMS-norm (no weight), fp32 in (stride/offset), bf16 out transposed [NKV][D][S]
// ---------------------------------------------------------------------------
__global__ __launch_bounds__(256) void rmsnorm_vT(
    const float* __restrict__ proj, bf16_t* __restrict__ vt,
    int inStride, int inOff) {
  int s = blockIdx.x, h = blockIdx.y, d = threadIdx.x;
  float x = proj[(size_t)s * inStride + inOff + h * DHEAD + d];
  float ss = x * x;
  ss += __shfl_xor(ss, 1);  ss += __shfl_xor(ss, 2);  ss += __shfl_xor(ss, 4);
  ss += __shfl_xor(ss, 8);  ss += __shfl_xor(ss, 16); ss += __shfl_xor(ss, 32);
  __shared__ float part[4];
  if ((threadIdx.x & 63) == 0) part[threadIdx.x >> 6] = ss;
  __syncthreads();
  float tot = part[0] + part[1] + part[2] + part[3];
  float r = rsqrtf(tot * (1.0f / DHEAD) + 1e-6f);
  vt[((size_t)h * DHEAD + d) * S_LEN + s] = __float2bfloat16(x * r);
}

// ---------------------------------------------------------------------------
// Flash attention, sliding window 512, NO score scale, GQA G=4.
// K/V staged in LDS per 32-key step, XOR source-swizzled (see R6 notes).
// ---------------------------------------------------------------------------
__global__ __launch_bounds__(256) void attn_split(
    const bf16_t* __restrict__ Qhi, const bf16_t* __restrict__ Qlo,
    const bf16_t* __restrict__ Khi, const bf16_t* __restrict__ Klo,
    const bf16_t* __restrict__ Vt, bf16_t* __restrict__ Aout) {
  const int h = blockIdx.y;
  const int qb = blockIdx.x * 64;
  const int wave = threadIdx.x >> 6, lane = threadIdx.x & 63;
  const int quad = lane >> 4, l16 = lane & 15;
  const int qw = qb + wave * 16;
  const int kv = h >> 2;  // G = 4
  const bf16_t* Qh_ = Qhi + h * DHEAD;   // row stride NHQ*DHEAD
  const bf16_t* Ql_ = Qlo + h * DHEAD;
  const bf16_t* Kh_ = Khi + kv * DHEAD;  // row stride NKVH*DHEAD
  const bf16_t* Kl_ = Klo + kv * DHEAD;
  const bf16_t* Vh_ = Vt + (size_t)kv * DHEAD * S_LEN;

  __shared__ __align__(16) bf16_t KshH[32 * 256];
  __shared__ __align__(16) bf16_t KshL[32 * 256];
  __shared__ __align__(16) bf16_t Vsh[256 * 32];
  __shared__ __align__(16) bf16_t Plds[4][16 * 32];

  fragAB qfh[8], qfl[8];
#pragma unroll
  for (int c = 0; c < 8; ++c) {
    size_t off = (size_t)(qw + l16) * (NHQ * DHEAD) + c * 32 + quad * 8;
    qfh[c] = *(const fragAB*)(Qh_ + off);
    qfl[c] = *(const fragAB*)(Ql_ + off);
  }

  int kRow[4], kCol[4], vRow[4], vCol[4];
#pragma unroll
  for (int i = 0; i < 4; ++i) {
    int ci = (i * 4 + wave) * 64 + lane;
    int r = ci >> 5, sc = ci & 31;
    kRow[i] = r;
    kCol[i] = (sc ^ r) * 8;
    int rv = ci >> 2, scv = ci & 3;
    vRow[i] = rv;
    vCol[i] = (scv ^ (rv & 3)) * 8;
  }

  fragC zero4 = {0.f, 0.f, 0.f, 0.f};
  fragC o_acc[16];
#pragma unroll
  for (int c = 0; c < 16; ++c) o_acc[c] = zero4;
  float m_run[4] = {NEG_BIG, NEG_BIG, NEG_BIG, NEG_BIG};
  float l_run[4] = {0.f, 0.f, 0.f, 0.f};
  const float LOG2E = 1.4426950408889634f;

  int k_lo = qb - (WIN - 1);
  if (k_lo < 0) k_lo = 0;
  k_lo &= ~31;

  for (int kb = k_lo; kb < qb + 64; kb += 32) {
#pragma unroll
    for (int i = 0; i < 4; ++i) {
      size_t dst = (size_t)(i * 4 + wave) * 1024;
      size_t koff = (size_t)(kb + kRow[i]) * (NKVH * DHEAD) + kCol[i];
      async_copy16(Kh_ + koff, (char*)KshH + dst);
      async_copy16(Kl_ + koff, (char*)KshL + dst);
      async_copy16(Vh_ + (size_t)vRow[i] * S_LEN + kb + vCol[i], (char*)Vsh + dst);
    }
    __syncthreads();

    fragC s0 = zero4, s1 = zero4;
#pragma unroll
    for (int c = 0; c < 8; ++c) {
      int j = c * 4 + quad;
      int off0 = (l16 * 32 + (j ^ l16)) * 16;
      int off1 = ((16 + l16) * 32 + (j ^ (16 + l16))) * 16;
      fragAB kh0 = *(const fragAB*)((const char*)KshH + off0);
      fragAB kl0 = *(const fragAB*)((const char*)KshL + off0);
      fragAB kh1 = *(const fragAB*)((const char*)KshH + off1);
      fragAB kl1 = *(const fragAB*)((const char*)KshL + off1);
      s0 = __builtin_amdgcn_mfma_f32_16x16x32_bf16(qfl[c], kh0, s0, 0, 0, 0);
      s0 = __builtin_amdgcn_mfma_f32_16x16x32_bf16(qfh[c], kl0, s0, 0, 0, 0);
      s0 = __builtin_amdgcn_mfma_f32_16x16x32_bf16(qfh[c], kh0, s0, 0, 0, 0);
      s1 = __builtin_amdgcn_mfma_f32_16x16x32_bf16(qfl[c], kh1, s1, 0, 0, 0);
      s1 = __builtin_amdgcn_mfma_f32_16x16x32_bf16(qfh[c], kl1, s1, 0, 0, 0);
      s1 = __builtin_amdgcn_mfma_f32_16x16x32_bf16(qfh[c], kh1, s1, 0, 0, 0);
    }

    float p0[4], p1[4], alpha[4];
#pragma unroll
    for (int r = 0; r < 4; ++r) {
      int qi = qw + quad * 4 + r;
      int k0i = kb + l16;
      int k1i = k0i + 16;
      bool v0 = (k0i <= qi) && (qi - k0i < WIN);
      bool v1 = (k1i <= qi) && (qi - k1i < WIN);
      float sv0 = v0 ? s0[r] : NEG_BIG;
      float sv1 = v1 ? s1[r] : NEG_BIG;
      float mx = fmaxf(sv0, sv1);
      mx = fmaxf(mx, __shfl_xor(mx, 1));
      mx = fmaxf(mx, __shfl_xor(mx, 2));
      mx = fmaxf(mx, __shfl_xor(mx, 4));
      mx = fmaxf(mx, __shfl_xor(mx, 8));
      float mn = fmaxf(m_run[r], mx);
      float a  = exp2f(fmaxf(m_run[r] - mn, -80.f) * LOG2E);
      float e0 = v0 ? exp2f(fmaxf(s0[r] - mn, -80.f) * LOG2E) : 0.f;
      float e1 = v1 ? exp2f(fmaxf(s1[r] - mn, -80.f) * LOG2E) : 0.f;
      float rs = e0 + e1;
      rs += __shfl_xor(rs, 1);
      rs += __shfl_xor(rs, 2);
      rs += __shfl_xor(rs, 4);
      rs += __shfl_xor(rs, 8);
      l_run[r] = l_run[r] * a + rs;
      m_run[r] = mn;
      alpha[r] = a; p0[r] = e0; p1[r] = e1;
    }
#pragma unroll
    for (int c = 0; c < 16; ++c)
#pragma unroll
      for (int r = 0; r < 4; ++r) o_acc[c][r] *= alpha[r];

    bf16_t* Pw = Plds[wave];
#pragma unroll
    for (int r = 0; r < 4; ++r) {
      Pw[(quad * 4 + r) * 32 + l16]      = __float2bfloat16(p0[r]);
      Pw[(quad * 4 + r) * 32 + 16 + l16] = __float2bfloat16(p1[r]);
    }
    fragAB pf = *(const fragAB*)((const char*)Pw + l16 * 64 + quad * 16);

#pragma unroll
    for (int c = 0; c < 16; ++c) {
      int d = c * 16 + l16;
      int offv = (d * 4 + (quad ^ (d & 3))) * 16;
      fragAB vf = *(const fragAB*)((const char*)Vsh + offv);
      o_acc[c] = __builtin_amdgcn_mfma_f32_16x16x32_bf16(pf, vf, o_acc[c], 0, 0, 0);
    }
    __syncthreads();
  }

  float inv_l[4];
#pragma unroll
  for (int r = 0; r < 4; ++r) inv_l[r] = 1.0f / l_run[r];
#pragma unroll
  for (int c = 0; c < 16; ++c)
#pragma unroll
    for (int r = 0; r < 4; ++r) {
      int row = qw + quad * 4 + r;
      int col = h * DHEAD + c * 16 + l16;
      Aout[(size_t)row * (NHQ * DHEAD) + col] = __float2bfloat16(o_acc[c][r] * inv_l[r]);
    }
}

// ---------------------------------------------------------------------------
extern "C" void kernel_launch(void* const* d_in, const int* in_sizes, int n_in,
                              void* d_out, int out_size, void* d_ws, size_t ws_size,
                              hipStream_t stream) {
  const float* hid  = (const float*)d_in[0];
  const float* w_q  = (const float*)d_in[1];
  const float* w_k  = (const float*)d_in[2];
  const float* w_v  = (const float*)d_in[3];
  const float* w_o  = (const float*)d_in[4];
  const float* qnw  = (const float*)d_in[5];
  const float* knw  = (const float*)d_in[6];
  const float* cosb = (const float*)d_in[7];
  const float* sinb = (const float*)d_in[8];
  float* outp = (float*)d_out;

  // Workspace (bf16 slots, M1 = 1<<20), peak 52M slots = 104 MiB:
  //  [ 0: 8M)  hidh  -> qh  (after qkv gemm)
  //  [ 8:16M)  hidl  -> ql
  //  [16:22M)  wTh (3072x2048) -> kh[16:18M), kl[18:20M), vt[20:22M) after gemm
  //  [22:28M)  wTl   -> woT[22:26M) after gemm
  //  [28:52M)  projqkv f32 (4096x3072) -> aout[28:36M) after norms
  const size_t M1 = 1048576;
  bf16_t* w = (bf16_t*)d_ws;
  bf16_t* hidh  = w;
  bf16_t* qh    = w;                         // alias hidh
  bf16_t* hidl  = w + 8 * M1;
  bf16_t* ql    = w + 8 * M1;                // alias hidl
  bf16_t* wTh   = w + 16 * M1;
  bf16_t* kh    = w + 16 * M1;               // alias wTh
  bf16_t* kl    = w + 18 * M1;
  bf16_t* vt    = w + 20 * M1;
  bf16_t* wTl   = w + 22 * M1;
  bf16_t* woT   = w + 22 * M1;               // alias wTl
  float*  projqkv = (float*)(w + 28 * M1);
  bf16_t* aout  = w + 28 * M1;               // alias projqkv (after norms)

  // phase 0: split hidden; split-transpose [wq|wk|wv] into fused wT [3072][2048]
  split_f32<<<(S_LEN * HDIM) / 1024, 256, 0, stream>>>(hid, hidh, hidl, S_LEN * HDIM);
  transpose_split<<<dim3((NHQ * DHEAD) / 32, HDIM / 32), 256, 0, stream>>>(
      w_q, wTh, wTl, HDIM, NHQ * DHEAD);
  transpose_split<<<dim3((NKVH * DHEAD) / 32, HDIM / 32), 256, 0, stream>>>(
      w_k, wTh + (size_t)(NHQ * DHEAD) * HDIM, wTl + (size_t)(NHQ * DHEAD) * HDIM,
      HDIM, NKVH * DHEAD);
  transpose_split<<<dim3((NKVH * DHEAD) / 32, HDIM / 32), 256, 0, stream>>>(
      w_v, wTh + (size_t)(NHQ * DHEAD + NKVH * DHEAD) * HDIM,
      wTl + (size_t)(NHQ * DHEAD + NKVH * DHEAD) * HDIM, HDIM, NKVH * DHEAD);

  // phase 1: fused q+k+v split projection, pipelined 256x192 tiles
  //          grid 16x16 = 256 blocks = exactly 1 per CU
  gemm_split2<<<dim3(NQKV / 192, S_LEN / 256), 512, 0, stream>>>(
      hidh, hidl, wTh, wTl, projqkv, S_LEN, NQKV, HDIM);

  // phase 2: norms (hid/wT dead -> qh/ql/kh/kl/vt targets)
  rmsnorm_rope_split<<<dim3(S_LEN, NHQ), 256, 0, stream>>>(
      projqkv, qnw, cosb, sinb, qh, ql, NQKV, 0, NHQ * DHEAD);
  rmsnorm_rope_split<<<dim3(S_LEN, NKVH), 256, 0, stream>>>(
      projqkv, knw, cosb, sinb, kh, kl, NQKV, NHQ * DHEAD, NKVH * DHEAD);
  rmsnorm_vT<<<dim3(S_LEN, NKVH), 256, 0, stream>>>(
      projqkv, vt, NQKV, NHQ * DHEAD + NKVH * DHEAD);

  // phase 3: w_o transpose into dead wTl region
  transpose_cvt<<<dim3(HDIM / 32, (NHQ * DHEAD) / 32), 256, 0, stream>>>(w_o, woT, NHQ * DHEAD, HDIM);

  // phase 4: attention -> aout (dead projqkv region)
  attn_split<<<dim3(S_LEN / 64, NHQ), 256, 0, stream>>>(qh, ql, kh, kl, vt, aout);

  // phase 5: output projection -> fp32 d_out (512 blocks = 2.0/CU uniform)
  gemm_bt<float><<<dim3(HDIM / 128, S_LEN / 128), 256, 0, stream>>>(aout, woT, outp, S_LEN, HDIM, NHQ * DHEAD);
}

// Round 2
// 457.739 us; speedup vs baseline: 1.1492x; 1.0347x over previous
//
#include <hip/hip_runtime.h>
#include <hip/hip_bf16.h>

#define S_LEN 4096
#define HDIM  2048
#define NHQ   8
#define NKVH  2
#define DHEAD 256
#define WIN   512
#define NQKV  3072   // fused q+k+v projection width (2048 + 512 + 512)

typedef __hip_bfloat16 bf16_t;
using fragAB = __attribute__((ext_vector_type(8))) short;  // 8 bf16
using fragC  = __attribute__((ext_vector_type(4))) float;  // 4 fp32

typedef unsigned int u32;
typedef const __attribute__((address_space(1))) u32* gas_ptr;
typedef __attribute__((address_space(3))) u32* las_ptr;

__device__ __forceinline__ void async_copy16(const void* g, void* l) {
  __builtin_amdgcn_global_load_lds((gas_ptr)g, (las_ptr)l, 16, 0, 0);
}

#define NEG_BIG (-3.0e38f)

__device__ __forceinline__ void split2(float x, bf16_t& hi, bf16_t& lo) {
  bf16_t h = __float2bfloat16(x);
  hi = h;
  lo = __float2bfloat16(x - (float)h);
}

// ---------------------------------------------------------------------------
// Elementwise split fp32 -> bf16 hi + bf16 lo  (n multiple of 1024)
// ---------------------------------------------------------------------------
__global__ __launch_bounds__(256) void split_f32(
    const float* __restrict__ in, bf16_t* __restrict__ hi,
    bf16_t* __restrict__ lo, int n) {
  int i = (blockIdx.x * 256 + threadIdx.x) * 4;
  if (i >= n) return;
  float4 v = *(const float4*)(in + i);
  split2(v.x, hi[i + 0], lo[i + 0]);
  split2(v.y, hi[i + 1], lo[i + 1]);
  split2(v.z, hi[i + 2], lo[i + 2]);
  split2(v.w, hi[i + 3], lo[i + 3]);
}

// ---------------------------------------------------------------------------
// Transpose+convert fp32 [R][C] -> bf16 [C][R]
// ---------------------------------------------------------------------------
__global__ __launch_bounds__(256) void transpose_cvt(
    const float* __restrict__ in, bf16_t* __restrict__ out, int R, int C) {
  __shared__ bf16_t tile[32][33];
  int c0 = blockIdx.x * 32, r0 = blockIdx.y * 32;
  int tx = threadIdx.x & 31, ty = threadIdx.x >> 5;
#pragma unroll
  for (int i = 0; i < 4; ++i)
    tile[ty + i * 8][tx] = __float2bfloat16(in[(size_t)(r0 + ty + i * 8) * C + c0 + tx]);
  __syncthreads();
#pragma unroll
  for (int i = 0; i < 4; ++i)
    out[(size_t)(c0 + ty + i * 8) * R + r0 + tx] = tile[tx][ty + i * 8];
}

// ---------------------------------------------------------------------------
// Transpose+split fp32 [R][C] -> bf16 hi [C][R], bf16 lo [C][R]
// ---------------------------------------------------------------------------
__global__ __launch_bounds__(256) void transpose_split(
    const float* __restrict__ in, bf16_t* __restrict__ hiT,
    bf16_t* __restrict__ loT, int R, int C) {
  __shared__ bf16_t th[32][33];
  __shared__ bf16_t tl[32][33];
  int c0 = blockIdx.x * 32, r0 = blockIdx.y * 32;
  int tx = threadIdx.x & 31, ty = threadIdx.x >> 5;
#pragma unroll
  for (int i = 0; i < 4; ++i) {
    float x = in[(size_t)(r0 + ty + i * 8) * C + c0 + tx];
    bf16_t h, l; split2(x, h, l);
    th[ty + i * 8][tx] = h;
    tl[ty + i * 8][tx] = l;
  }
  __syncthreads();
#pragma unroll
  for (int i = 0; i < 4; ++i) {
    hiT[(size_t)(c0 + ty + i * 8) * R + r0 + tx] = th[tx][ty + i * 8];
    loT[(size_t)(c0 + ty + i * 8) * R + r0 + tx] = tl[tx][ty + i * 8];
  }
}

// ---------------------------------------------------------------------------
// Shared helpers for pipelined GEMMs
// ---------------------------------------------------------------------------
#define VMCNT_(n) asm volatile("s_waitcnt vmcnt(" #n ")" ::: "memory")
#define VMCNT(n) VMCNT_(n)
#define BARRIER()                     \
  {                                   \
    asm volatile("" ::: "memory");    \
    __builtin_amdgcn_s_barrier();     \
    asm volatile("" ::: "memory");    \
  }

#define MFMA_(a, b, c) __builtin_amdgcn_mfma_f32_16x16x32_bf16(a, b, c, 0, 0, 0)

// ---------------------------------------------------------------------------
// Split-precision GEMM v3: C = Ah*Bh + Ah*Bl + Al*Bh, pipelined.
// BM=256, BN=192, BK=32, 512 threads (8 waves, 2M x 4N).
// Double-buffered LDS (112 KB), counted vmcnt, raw barriers, T2 XOR swizzle,
// setprio around MFMA clusters. A-fragment registers double-buffered: phase
// p+1's ds_reads issue before phase p's MFMA cluster so LDS latency hides
// under MFMAs (m201-style). 4 barriers/iter.
// ---------------------------------------------------------------------------
#define OFF_AH 0
#define OFF_AL 16384
#define OFF_BH 32768
#define OFF_BL 45056
#define BUFSZ  57344

#define LOADB()                                                   \
  _Pragma("unroll")                                               \
  for (int j = 0; j < 3; ++j) {                                   \
    const char* bp_ = bufc + (wn + j * 16 + l16) * 64 + rdq;      \
    bh[j] = *(const fragAB*)(bp_ + OFF_BH);                       \
    bl[j] = *(const fragAB*)(bp_ + OFF_BL);                       \
  }

struct ARegs { fragAB ah0, al0, ah1, al1; };

__device__ __forceinline__ void lda_split(ARegs& r, const char* bufc, int wm,
                                          int p, int l16, int rdq) {
  const char* a0 = bufc + (wm + (2 * p) * 16 + l16) * 64 + rdq;
  const char* a1 = a0 + 16 * 64;
  r.ah0 = *(const fragAB*)(a0 + OFF_AH);
  r.al0 = *(const fragAB*)(a0 + OFF_AL);
  r.ah1 = *(const fragAB*)(a1 + OFF_AH);
  r.al1 = *(const fragAB*)(a1 + OFF_AL);
}

__device__ __forceinline__ void mfma_split(fragC (&acc)[8][3], const ARegs& r,
                                           const fragAB (&bh)[3],
                                           const fragAB (&bl)[3], int p) {
  __builtin_amdgcn_s_setprio(1);
#pragma unroll
  for (int j = 0; j < 3; ++j) {
    acc[2 * p][j]     = MFMA_(r.al0, bh[j], acc[2 * p][j]);
    acc[2 * p + 1][j] = MFMA_(r.al1, bh[j], acc[2 * p + 1][j]);
  }
#pragma unroll
  for (int j = 0; j < 3; ++j) {
    acc[2 * p][j]     = MFMA_(r.ah0, bl[j], acc[2 * p][j]);
    acc[2 * p + 1][j] = MFMA_(r.ah1, bl[j], acc[2 * p + 1][j]);
  }
#pragma unroll
  for (int j = 0; j < 3; ++j) {
    acc[2 * p][j]     = MFMA_(r.ah0, bh[j], acc[2 * p][j]);
    acc[2 * p + 1][j] = MFMA_(r.ah1, bh[j], acc[2 * p + 1][j]);
  }
  __builtin_amdgcn_s_setprio(0);
}

__global__ __launch_bounds__(512, 2) void gemm_split2(
    const bf16_t* __restrict__ Ah, const bf16_t* __restrict__ Al,
    const bf16_t* __restrict__ Bh, const bf16_t* __restrict__ Bl,
    float* __restrict__ C, int M, int N, int K) {
  __shared__ __align__(16) char lds[2 * BUFSZ];
  const int t = threadIdx.x;
  const int wave = t >> 6, lane = t & 63;
  const int quad = lane >> 4, l16 = lane & 15;
  const int m0 = blockIdx.y * 256, n0 = blockIdx.x * 192;
  const int wm = (wave >> 2) * 128, wn = (wave & 3) * 48;
  // T2 read swizzle: phys 16B-slot of (row r, col-16B q) = q ^ ((r>>1)&3).
  const int rdq = (quad ^ ((l16 >> 1) & 3)) * 16;

  // Per-lane global source offset inside a 16-row x 32-col chunk (inverse swizzle).
  const size_t laneOff =
      (size_t)(lane >> 2) * K * 2 + 16 * ((lane & 3) ^ ((lane >> 3) & 3));

  // 7 staging chunks per wave per K-step, in consumption order.
  const char* gsrc[7];
  int ldsOff[7];
#pragma unroll
  for (int pos = 0; pos < 3; ++pos) {
    int c = wave + 8 * pos;            // 0..23: Bh chunks 0..11, Bl chunks 0..11
    if (c < 12) {
      gsrc[pos]   = (const char*)Bh + (size_t)(n0 + 16 * c) * K * 2 + laneOff;
      ldsOff[pos] = OFF_BH + c * 1024;
    } else {
      gsrc[pos]   = (const char*)Bl + (size_t)(n0 + 16 * (c - 12)) * K * 2 + laneOff;
      ldsOff[pos] = OFF_BL + (c - 12) * 1024;
    }
  }
#pragma unroll
  for (int p = 0; p < 4; ++p) {
    int sub = wave & 3;
    int R0 = ((sub >> 1) & 1) * 128 + 32 * p + (sub & 1) * 16;
    const char* base = (const char*)(wave < 4 ? Ah : Al);
    gsrc[3 + p]   = base + (size_t)(m0 + R0) * K * 2 + laneOff;
    ldsOff[3 + p] = (wave < 4 ? OFF_AH : OFF_AL) + R0 * 64;
  }

  fragC zero4 = {0.f, 0.f, 0.f, 0.f};
  fragC acc[8][3];
#pragma unroll
  for (int i = 0; i < 8; ++i)
#pragma unroll
    for (int j = 0; j < 3; ++j) acc[i][j] = zero4;

  char* ldsc = (char*)lds;
  // prologue: stage K-step 0 into buffer 0
#pragma unroll
  for (int ps = 0; ps < 7; ++ps) async_copy16(gsrc[ps], ldsc + ldsOff[ps]);
#pragma unroll
  for (int ps = 0; ps < 7; ++ps) gsrc[ps] += 64;

  fragAB bh[3], bl[3];
  ARegs r0, r1;
  int cur = 0;
  const int NS = K / 32;
  for (int it = 0; it < NS - 1; ++it) {
    const char* bufc = ldsc + cur * BUFSZ;
    char* nb = ldsc + (cur ^ 1) * BUFSZ;
    // issue next K-step's 7 chunks (stay in flight across barriers)
#pragma unroll
    for (int ps = 0; ps < 7; ++ps) async_copy16(gsrc[ps], nb + ldsOff[ps]);
#pragma unroll
    for (int ps = 0; ps < 7; ++ps) gsrc[ps] += 64;
    // 14 outstanding; oldest 5 = this step's B + A0 + A1
    VMCNT(9); BARRIER();
    LOADB();
    lda_split(r0, bufc, wm, 0, l16, rdq);
    lda_split(r1, bufc, wm, 1, l16, rdq);
    mfma_split(acc, r0, bh, bl, 0);
    VMCNT(8); BARRIER();           // A2 region landed
    lda_split(r0, bufc, wm, 2, l16, rdq);
    mfma_split(acc, r1, bh, bl, 1);
    VMCNT(7); BARRIER();           // A3 region landed
    lda_split(r1, bufc, wm, 3, l16, rdq);
    mfma_split(acc, r0, bh, bl, 2);
    mfma_split(acc, r1, bh, bl, 3);
    BARRIER();  // all waves done reading bufc before next iter overwrites it
    cur ^= 1;
  }
  {  // final K-step: only this step's 7 chunks in flight
    const char* bufc = ldsc + cur * BUFSZ;
    VMCNT(2); BARRIER();
    LOADB();
    lda_split(r0, bufc, wm, 0, l16, rdq);
    lda_split(r1, bufc, wm, 1, l16, rdq);
    mfma_split(acc, r0, bh, bl, 0);
    VMCNT(1); BARRIER();
    lda_split(r0, bufc, wm, 2, l16, rdq);
    mfma_split(acc, r1, bh, bl, 1);
    VMCNT(0); BARRIER();
    lda_split(r1, bufc, wm, 3, l16, rdq);
    mfma_split(acc, r0, bh, bl, 2);
    mfma_split(acc, r1, bh, bl, 3);
  }

#pragma unroll
  for (int i = 0; i < 8; ++i)
#pragma unroll
    for (int j = 0; j < 3; ++j)
#pragma unroll
      for (int r = 0; r < 4; ++r) {
        int row = m0 + wm + i * 16 + quad * 4 + r;
        int col = n0 + wn + j * 16 + l16;
        C[(size_t)row * N + col] = acc[i][j][r];
      }
}

// ---------------------------------------------------------------------------
// Plain GEMM v2 (output projection): C[M][N] = A[M][K]*Bt[N][K]^T, fp32 out.
// BM=256, BN=128, BK=64, 512 threads (8 waves as 2M x 4N -> wave tile 128x32).
// Same pipelined schedule as gemm_split2: double-buffered LDS (96 KB),
// counted vmcnt, prefetched A-fragment registers, XOR-swizzled 128B rows.
// ---------------------------------------------------------------------------
#define BT_OFF_A 0
#define BT_OFF_B 32768
#define BT_BUFSZ 49152

struct ARegs2 { fragAB a[2][2]; };  // [row-in-pair][k-slice]

__device__ __forceinline__ void lda_bt(ARegs2& r, const char* bufc, int wm,
                                       int p, int l16, int quad, int rx) {
#pragma unroll
  for (int u = 0; u < 2; ++u)
#pragma unroll
    for (int ks = 0; ks < 2; ++ks)
      r.a[u][ks] = *(const fragAB*)(bufc + BT_OFF_A +
                                    (wm + (2 * p + u) * 16 + l16) * 128 +
                                    (((ks * 4 + quad) ^ rx) * 16));
}

__device__ __forceinline__ void mfma_bt(fragC (&acc)[8][2], const ARegs2& r,
                                        const fragAB (&b)[2][2], int p) {
  __builtin_amdgcn_s_setprio(1);
#pragma unroll
  for (int ks = 0; ks < 2; ++ks)
#pragma unroll
    for (int j = 0; j < 2; ++j) {
      acc[2 * p][j]     = MFMA_(r.a[0][ks], b[j][ks], acc[2 * p][j]);
      acc[2 * p + 1][j] = MFMA_(r.a[1][ks], b[j][ks], acc[2 * p + 1][j]);
    }
  __builtin_amdgcn_s_setprio(0);
}

__global__ __launch_bounds__(512, 2) void gemm_bt2(
    const bf16_t* __restrict__ A, const bf16_t* __restrict__ Bt,
    float* __restrict__ C, int M, int N, int K) {
  __shared__ __align__(16) char lds[2 * BT_BUFSZ];
  const int t = threadIdx.x;
  const int wave = t >> 6, lane = t & 63;
  const int quad = lane >> 4, l16 = lane & 15;
  const int m0 = blockIdx.y * 256, n0 = blockIdx.x * 128;
  const int wm = (wave >> 2) * 128, wn = (wave & 3) * 32;
  const int rx = l16 & 7;  // row-XOR for 8-slot swizzle (128B rows)

  // chunk = 8 rows x 64 cols (128B rows). lane l stages row l>>3,
  // logical col16 (l&7)^((l>>3)&7) -> LDS phys slot l&7 (inverse swizzle).
  const size_t laneOff =
      (size_t)(lane >> 3) * K * 2 + 16 * ((lane & 7) ^ ((lane >> 3) & 7));

  // 6 staging chunks per wave per K-step, in consumption order: B,B,A0..A3.
  const char* gsrc[6];
  int ldsOff[6];
#pragma unroll
  for (int pos = 0; pos < 2; ++pos) {
    int c = wave + 8 * pos;  // B chunks 0..15, rows [8c,8c+8)
    gsrc[pos]   = (const char*)Bt + (size_t)(n0 + 8 * c) * K * 2 + laneOff;
    ldsOff[pos] = BT_OFF_B + c * 1024;
  }
#pragma unroll
  for (int p = 0; p < 4; ++p) {
    int R0 = (wave >> 2) * 128 + 32 * p + (wave & 3) * 8;
    gsrc[2 + p]   = (const char*)A + (size_t)(m0 + R0) * K * 2 + laneOff;
    ldsOff[2 + p] = BT_OFF_A + R0 * 128;
  }

  fragC zero4 = {0.f, 0.f, 0.f, 0.f};
  fragC acc[8][2];
#pragma unroll
  for (int i = 0; i < 8; ++i)
#pragma unroll
    for (int j = 0; j < 2; ++j) acc[i][j] = zero4;

  char* ldsc = (char*)lds;
#pragma unroll
  for (int ps = 0; ps < 6; ++ps) async_copy16(gsrc[ps], ldsc + ldsOff[ps]);
#pragma unroll
  for (int ps = 0; ps < 6; ++ps) gsrc[ps] += 128;

  fragAB bfr[2][2];
  ARegs2 r0, r1;
  int cur = 0;
  const int NS = K / 64;
  for (int it = 0; it < NS - 1; ++it) {
    const char* bufc = ldsc + cur * BT_BUFSZ;
    char* nb = ldsc + (cur ^ 1) * BT_BUFSZ;
#pragma unroll
    for (int ps = 0; ps < 6; ++ps) async_copy16(gsrc[ps], nb + ldsOff[ps]);
#pragma unroll
    for (int ps = 0; ps < 6; ++ps) gsrc[ps] += 128;
    // 12 outstanding; oldest 4 = B,B,A0,A1
    VMCNT(8); BARRIER();
#pragma unroll
    for (int j = 0; j < 2; ++j)
#pragma unroll
      for (int ks = 0; ks < 2; ++ks)
        bfr[j][ks] = *(const fragAB*)(bufc + BT_OFF_B +
                                      (wn + j * 16 + l16) * 128 +
                                      (((ks * 4 + quad) ^ rx) * 16));
    lda_bt(r0, bufc, wm, 0, l16, quad, rx);
    lda_bt(r1, bufc, wm, 1, l16, quad, rx);
    mfma_bt(acc, r0, bfr, 0);
    VMCNT(7); BARRIER();           // A2 landed
    lda_bt(r0, bufc, wm, 2, l16, quad, rx);
    mfma_bt(acc, r1, bfr, 1);
    VMCNT(6); BARRIER();           // A3 landed
    lda_bt(r1, bufc, wm, 3, l16, quad, rx);
    mfma_bt(acc, r0, bfr, 2);
    mfma_bt(acc, r1, bfr, 3);
    BARRIER();
    cur ^= 1;
  }
  {
    const char* bufc = ldsc + cur * BT_BUFSZ;
    VMCNT(2); BARRIER();
#pragma unroll
    for (int j = 0; j < 2; ++j)
#pragma unroll
      for (int ks = 0; ks < 2; ++ks)
        bfr[j][ks] = *(const fragAB*)(bufc + BT_OFF_B +
                                      (wn + j * 16 + l16) * 128 +
                                      (((ks * 4 + quad) ^ rx) * 16));
    lda_bt(r0, bufc, wm, 0, l16, quad, rx);
    lda_bt(r1, bufc, wm, 1, l16, quad, rx);
    mfma_bt(acc, r0, bfr, 0);
    VMCNT(1); BARRIER();
    lda_bt(r0, bufc, wm, 2, l16, quad, rx);
    mfma_bt(acc, r1, bfr, 1);
    VMCNT(0); BARRIER();
    lda_bt(r1, bufc, wm, 3, l16, quad, rx);
    mfma_bt(acc, r0, bfr, 2);
    mfma_bt(acc, r1, bfr, 3);
  }

#pragma unroll
  for (int i = 0; i < 8; ++i)
#pragma unroll
    for (int j = 0; j < 2; ++j)
#pragma unroll
      for (int r = 0; r < 4; ++r) {
        int row = m0 + wm + i * 16 + quad * 4 + r;
        int col = n0 + wn + j * 16 + l16;
        C[(size_t)row * N + col] = acc[i][j][r];
      }
}

// ---------------------------------------------------------------------------
// RMS-norm (+fp32 weight) + RoPE, fp32 in -> split bf16 hi/lo out.
// proj row stride inStride, head-block starts at inOff. Output stride outStride.
// ---------------------------------------------------------------------------
__global__ __launch_bounds__(256) void rmsnorm_rope_split(
    const float* __restrict__ proj, const float* __restrict__ w,
    const float* __restrict__ cosb, const float* __restrict__ sinb,
    bf16_t* __restrict__ qhi, bf16_t* __restrict__ qlo,
    int inStride, int inOff, int outStride) {
  int s = blockIdx.x, h = blockIdx.y, d = threadIdx.x;
  float x = proj[(size_t)s * inStride + inOff + h * DHEAD + d];
  float ss = x * x;
  ss += __shfl_xor(ss, 1);  ss += __shfl_xor(ss, 2);  ss += __shfl_xor(ss, 4);
  ss += __shfl_xor(ss, 8);  ss += __shfl_xor(ss, 16); ss += __shfl_xor(ss, 32);
  __shared__ float part[4];
  __shared__ float xs[DHEAD];
  if ((threadIdx.x & 63) == 0) part[threadIdx.x >> 6] = ss;
  __syncthreads();
  float tot = part[0] + part[1] + part[2] + part[3];
  float r = rsqrtf(tot * (1.0f / DHEAD) + 1e-6f);
  float xn = x * r * w[d];
  xs[d] = xn;
  __syncthreads();
  float other = xs[(d + 128) & 255];
  float rot = (d < 128) ? -other : other;
  float y = xn * cosb[(size_t)s * DHEAD + d] + rot * sinb[(size_t)s * DHEAD + d];
  bf16_t h2, l2; split2(y, h2, l2);
  size_t oidx = (size_t)s * outStride + h * DHEAD + d;
  qhi[oidx] = h2;
  qlo[oidx] = l2;
}

// ---------------------------------------------------------------------------
// RMS-norm (no weight), fp32 in (stride/offset), bf16 out transposed [NKV][D][S]
// ---------------------------------------------------------------------------
__global__ __launch_bounds__(256) void rmsnorm_vT(
    const float* __restrict__ proj, bf16_t* __restrict__ vt,
    int inStride, int inOff) {
  int s = blockIdx.x, h = blockIdx.y, d = threadIdx.x;
  float x = proj[(size_t)s * inStride + inOff + h * DHEAD + d];
  float ss = x * x;
  ss += __shfl_xor(ss, 1);  ss += __shfl_xor(ss, 2);  ss += __shfl_xor(ss, 4);
  ss += __shfl_xor(ss, 8);  ss += __shfl_xor(ss, 16); ss += __shfl_xor(ss, 32);
  __shared__ float part[4];
  if ((threadIdx.x & 63) == 0) part[threadIdx.x >> 6] = ss;
  __syncthreads();
  float tot = part[0] + part[1] + part[2] + part[3];
  float r = rsqrtf(tot * (1.0f / DHEAD) + 1e-6f);
  vt[((size_t)h * DHEAD + d) * S_LEN + s] = __float2bfloat16(x * r);
}

// ---------------------------------------------------------------------------
// Flash attention, sliding window 512, NO score scale, GQA G=4.
// K/V staged in LDS per 32-key step, XOR source-swizzled (see R6 notes).
// ---------------------------------------------------------------------------
__global__ __launch_bounds__(256) void attn_split(
    const bf16_t* __restrict__ Qhi, const bf16_t* __restrict__ Qlo,
    const bf16_t* __restrict__ Khi, const bf16_t* __restrict__ Klo,
    const bf16_t* __restrict__ Vt, bf16_t* __restrict__ Aout) {
  const int h = blockIdx.y;
  const int qb = blockIdx.x * 64;
  const int wave = threadIdx.x >> 6, lane = threadIdx.x & 63;
  const int quad = lane >> 4, l16 = lane & 15;
  const int qw = qb + wave * 16;
  const int kv = h >> 2;  // G = 4
  const bf16_t* Qh_ = Qhi + h * DHEAD;   // row stride NHQ*DHEAD
  const bf16_t* Ql_ = Qlo + h * DHEAD;
  const bf16_t* Kh_ = Khi + kv * DHEAD;  // row stride NKVH*DHEAD
  const bf16_t* Kl_ = Klo + kv * DHEAD;
  const bf16_t* Vh_ = Vt + (size_t)kv * DHEAD * S_LEN;

  __shared__ __align__(16) bf16_t KshH[32 * 256];
  __shared__ __align__(16) bf16_t KshL[32 * 256];
  __shared__ __align__(16) bf16_t Vsh[256 * 32];
  __shared__ __align__(16) bf16_t Plds[4][16 * 32];

  fragAB qfh[8], qfl[8];
#pragma unroll
  for (int c = 0; c < 8; ++c) {
    size_t off = (size_t)(qw + l16) * (NHQ * DHEAD) + c * 32 + quad * 8;
    qfh[c] = *(const fragAB*)(Qh_ + off);
    qfl[c] = *(const fragAB*)(Ql_ + off);
  }

  int kRow[4], kCol[4], vRow[4], vCol[4];
#pragma unroll
  for (int i = 0; i < 4; ++i) {
    int ci = (i * 4 + wave) * 64 + lane;
    int r = ci >> 5, sc = ci & 31;
    kRow[i] = r;
    kCol[i] = (sc ^ r) * 8;
    int rv = ci >> 2, scv = ci & 3;
    vRow[i] = rv;
    vCol[i] = (scv ^ (rv & 3)) * 8;
  }

  fragC zero4 = {0.f, 0.f, 0.f, 0.f};
  fragC o_acc[16];
#pragma unroll
  for (int c = 0; c < 16; ++c) o_acc[c] = zero4;
  float m_run[4] = {NEG_BIG, NEG_BIG, NEG_BIG, NEG_BIG};
  float l_run[4] = {0.f, 0.f, 0.f, 0.f};
  const float LOG2E = 1.4426950408889634f;

  int k_lo = qb - (WIN - 1);
  if (k_lo < 0) k_lo = 0;
  k_lo &= ~31;

  for (int kb = k_lo; kb < qb + 64; kb += 32) {
#pragma unroll
    for (int i = 0; i < 4; ++i) {
      size_t dst = (size_t)(i * 4 + wave) * 1024;
      size_t koff = (size_t)(kb + kRow[i]) * (NKVH * DHEAD) + kCol[i];
      async_copy16(Kh_ + koff, (char*)KshH + dst);
      async_copy16(Kl_ + koff, (char*)KshL + dst);
      async_copy16(Vh_ + (size_t)vRow[i] * S_LEN + kb + vCol[i], (char*)Vsh + dst);
    }
    __syncthreads();

    fragC s0 = zero4, s1 = zero4;
#pragma unroll
    for (int c = 0; c < 8; ++c) {
      int j = c * 4 + quad;
      int off0 = (l16 * 32 + (j ^ l16)) * 16;
      int off1 = ((16 + l16) * 32 + (j ^ (16 + l16))) * 16;
      fragAB kh0 = *(const fragAB*)((const char*)KshH + off0);
      fragAB kl0 = *(const fragAB*)((const char*)KshL + off0);
      fragAB kh1 = *(const fragAB*)((const char*)KshH + off1);
      fragAB kl1 = *(const fragAB*)((const char*)KshL + off1);
      s0 = __builtin_amdgcn_mfma_f32_16x16x32_bf16(qfl[c], kh0, s0, 0, 0, 0);
      s0 = __builtin_amdgcn_mfma_f32_16x16x32_bf16(qfh[c], kl0, s0, 0, 0, 0);
      s0 = __builtin_amdgcn_mfma_f32_16x16x32_bf16(qfh[c], kh0, s0, 0, 0, 0);
      s1 = __builtin_amdgcn_mfma_f32_16x16x32_bf16(qfl[c], kh1, s1, 0, 0, 0);
      s1 = __builtin_amdgcn_mfma_f32_16x16x32_bf16(qfh[c], kl1, s1, 0, 0, 0);
      s1 = __builtin_amdgcn_mfma_f32_16x16x32_bf16(qfh[c], kh1, s1, 0, 0, 0);
    }

    float p0[4], p1[4], alpha[4];
#pragma unroll
    for (int r = 0; r < 4; ++r) {
      int qi = qw + quad * 4 + r;
      int k0i = kb + l16;
      int k1i = k0i + 16;
      bool v0 = (k0i <= qi) && (qi - k0i < WIN);
      bool v1 = (k1i <= qi) && (qi - k1i < WIN);
      float sv0 = v0 ? s0[r] : NEG_BIG;
      float sv1 = v1 ? s1[r] : NEG_BIG;
      float mx = fmaxf(sv0, sv1);
      mx = fmaxf(mx, __shfl_xor(mx, 1));
      mx = fmaxf(mx, __shfl_xor(mx, 2));
      mx = fmaxf(mx, __shfl_xor(mx, 4));
      mx = fmaxf(mx, __shfl_xor(mx, 8));
      float mn = fmaxf(m_run[r], mx);
      float a  = exp2f(fmaxf(m_run[r] - mn, -80.f) * LOG2E);
      float e0 = v0 ? exp2f(fmaxf(s0[r] - mn, -80.f) * LOG2E) : 0.f;
      float e1 = v1 ? exp2f(fmaxf(s1[r] - mn, -80.f) * LOG2E) : 0.f;
      float rs = e0 + e1;
      rs += __shfl_xor(rs, 1);
      rs += __shfl_xor(rs, 2);
      rs += __shfl_xor(rs, 4);
      rs += __shfl_xor(rs, 8);
      l_run[r] = l_run[r] * a + rs;
      m_run[r] = mn;
      alpha[r] = a; p0[r] = e0; p1[r] = e1;
    }
#pragma unroll
    for (int c = 0; c < 16; ++c)
#pragma unroll
      for (int r = 0; r < 4; ++r) o_acc[c][r] *= alpha[r];

    bf16_t* Pw = Plds[wave];
#pragma unroll
    for (int r = 0; r < 4; ++r) {
      Pw[(quad * 4 + r) * 32 + l16]      = __float2bfloat16(p0[r]);
      Pw[(quad * 4 + r) * 32 + 16 + l16] = __float2bfloat16(p1[r]);
    }
    fragAB pf = *(const fragAB*)((const char*)Pw + l16 * 64 + quad * 16);

#pragma unroll
    for (int c = 0; c < 16; ++c) {
      int d = c * 16 + l16;
      int offv = (d * 4 + (quad ^ (d & 3))) * 16;
      fragAB vf = *(const fragAB*)((const char*)Vsh + offv);
      o_acc[c] = __builtin_amdgcn_mfma_f32_16x16x32_bf16(pf, vf, o_acc[c], 0, 0, 0);
    }
    __syncthreads();
  }

  float inv_l[4];
#pragma unroll
  for (int r = 0; r < 4; ++r) inv_l[r] = 1.0f / l_run[r];
#pragma unroll
  for (int c = 0; c < 16; ++c)
#pragma unroll
    for (int r = 0; r < 4; ++r) {
      int row = qw + quad * 4 + r;
      int col = h * DHEAD + c * 16 + l16;
      Aout[(size_t)row * (NHQ * DHEAD) + col] = __float2bfloat16(o_acc[c][r] * inv_l[r]);
    }
}

// ---------------------------------------------------------------------------
extern "C" void kernel_launch(void* const* d_in, const int* in_sizes, int n_in,
                              void* d_out, int out_size, void* d_ws, size_t ws_size,
                              hipStream_t stream) {
  const float* hid  = (const float*)d_in[0];
  const float* w_q  = (const float*)d_in[1];
  const float* w_k  = (const float*)d_in[2];
  const float* w_v  = (const float*)d_in[3];
  const float* w_o  = (const float*)d_in[4];
  const float* qnw  = (const float*)d_in[5];
  const float* knw  = (const float*)d_in[6];
  const float* cosb = (const float*)d_in[7];
  const float* sinb = (const float*)d_in[8];
  float* outp = (float*)d_out;

  // Workspace (bf16 slots, M1 = 1<<20), peak 52M slots = 104 MiB:
  //  [ 0: 8M)  hidh  -> qh  (after qkv gemm)
  //  [ 8:16M)  hidl  -> ql
  //  [16:22M)  wTh (3072x2048) -> kh[16:18M), kl[18:20M), vt[20:22M) after gemm
  //  [22:28M)  wTl   -> woT[22:26M) after gemm
  //  [28:52M)  projqkv f32 (4096x3072) -> aout[28:36M) after norms
  const size_t M1 = 1048576;
  bf16_t* w = (bf16_t*)d_ws;
  bf16_t* hidh  = w;
  bf16_t* qh    = w;                         // alias hidh
  bf16_t* hidl  = w + 8 * M1;
  bf16_t* ql    = w + 8 * M1;                // alias hidl
  bf16_t* wTh   = w + 16 * M1;
  bf16_t* kh    = w + 16 * M1;               // alias wTh
  bf16_t* kl    = w + 18 * M1;
  bf16_t* vt    = w + 20 * M1;
  bf16_t* wTl   = w + 22 * M1;
  bf16_t* woT   = w + 22 * M1;               // alias wTl
  float*  projqkv = (float*)(w + 28 * M1);
  bf16_t* aout  = w + 28 * M1;               // alias projqkv (after norms)

  // phase 0: split hidden; split-transpose [wq|wk|wv] into fused wT [3072][2048]
  split_f32<<<(S_LEN * HDIM) / 1024, 256, 0, stream>>>(hid, hidh, hidl, S_LEN * HDIM);
  transpose_split<<<dim3((NHQ * DHEAD) / 32, HDIM / 32), 256, 0, stream>>>(
      w_q, wTh, wTl, HDIM, NHQ * DHEAD);
  transpose_split<<<dim3((NKVH * DHEAD) / 32, HDIM / 32), 256, 0, stream>>>(
      w_k, wTh + (size_t)(NHQ * DHEAD) * HDIM, wTl + (size_t)(NHQ * DHEAD) * HDIM,
      HDIM, NKVH * DHEAD);
  transpose_split<<<dim3((NKVH * DHEAD) / 32, HDIM / 32), 256, 0, stream>>>(
      w_v, wTh + (size_t)(NHQ * DHEAD + NKVH * DHEAD) * HDIM,
      wTl + (size_t)(NHQ * DHEAD + NKVH * DHEAD) * HDIM, HDIM, NKVH * DHEAD);

  // phase 1: fused q+k+v split projection, pipelined 256x192 tiles
  //          grid 16x16 = 256 blocks = exactly 1 per CU
  gemm_split2<<<dim3(NQKV / 192, S_LEN / 256), 512, 0, stream>>>(
      hidh, hidl, wTh, wTl, projqkv, S_LEN, NQKV, HDIM);

  // phase 2: norms (hid/wT dead -> qh/ql/kh/kl/vt targets)
  rmsnorm_rope_split<<<dim3(S_LEN, NHQ), 256, 0, stream>>>(
      projqkv, qnw, cosb, sinb, qh, ql, NQKV, 0, NHQ * DHEAD);
  rmsnorm_rope_split<<<dim3(S_LEN, NKVH), 256, 0, stream>>>(
      projqkv, knw, cosb, sinb, kh, kl, NQKV, NHQ * DHEAD, NKVH * DHEAD);
  rmsnorm_vT<<<dim3(S_LEN, NKVH), 256, 0, stream>>>(
      projqkv, vt, NQKV, NHQ * DHEAD + NKVH * DHEAD);

  // phase 3: w_o transpose into dead wTl region
  transpose_cvt<<<dim3(HDIM / 32, (NHQ * DHEAD) / 32), 256, 0, stream>>>(w_o, woT, NHQ * DHEAD, HDIM);

  // phase 4: attention -> aout (dead projqkv region)
  attn_split<<<dim3(S_LEN / 64, NHQ), 256, 0, stream>>>(qh, ql, kh, kl, vt, aout);

  // phase 5: output projection -> fp32 d_out, pipelined 256x128 tiles
  //          grid 16x16 = 256 blocks = exactly 1 per CU
  gemm_bt2<<<dim3(HDIM / 128, S_LEN / 256), 512, 0, stream>>>(
      aout, woT, outp, S_LEN, HDIM, NHQ * DHEAD);
}

// Round 3
// 440.047 us; speedup vs baseline: 1.1954x; 1.0402x over previous
//
#include <hip/hip_runtime.h>
#include <hip/hip_bf16.h>

#define S_LEN 4096
#define HDIM  2048
#define NHQ   8
#define NKVH  2
#define DHEAD 256
#define WIN   512
#define NQKV  3072   // fused q+k+v projection width (2048 + 512 + 512)

typedef __hip_bfloat16 bf16_t;
using fragAB = __attribute__((ext_vector_type(8))) short;  // 8 bf16
using fragC  = __attribute__((ext_vector_type(4))) float;  // 4 fp32

typedef unsigned int u32;
typedef const __attribute__((address_space(1))) u32* gas_ptr;
typedef __attribute__((address_space(3))) u32* las_ptr;

__device__ __forceinline__ void async_copy16(const void* g, void* l) {
  __builtin_amdgcn_global_load_lds((gas_ptr)g, (las_ptr)l, 16, 0, 0);
}

#define NEG_BIG (-3.0e38f)

__device__ __forceinline__ void split2(float x, bf16_t& hi, bf16_t& lo) {
  bf16_t h = __float2bfloat16(x);
  hi = h;
  lo = __float2bfloat16(x - (float)h);
}

// ---------------------------------------------------------------------------
// Elementwise split fp32 -> bf16 hi + bf16 lo  (n multiple of 1024)
// ---------------------------------------------------------------------------
__global__ __launch_bounds__(256) void split_f32(
    const float* __restrict__ in, bf16_t* __restrict__ hi,
    bf16_t* __restrict__ lo, int n) {
  int i = (blockIdx.x * 256 + threadIdx.x) * 4;
  if (i >= n) return;
  float4 v = *(const float4*)(in + i);
  split2(v.x, hi[i + 0], lo[i + 0]);
  split2(v.y, hi[i + 1], lo[i + 1]);
  split2(v.z, hi[i + 2], lo[i + 2]);
  split2(v.w, hi[i + 3], lo[i + 3]);
}

// ---------------------------------------------------------------------------
// Transpose+convert fp32 [R][C] -> bf16 [C][R]
// ---------------------------------------------------------------------------
__global__ __launch_bounds__(256) void transpose_cvt(
    const float* __restrict__ in, bf16_t* __restrict__ out, int R, int C) {
  __shared__ bf16_t tile[32][33];
  int c0 = blockIdx.x * 32, r0 = blockIdx.y * 32;
  int tx = threadIdx.x & 31, ty = threadIdx.x >> 5;
#pragma unroll
  for (int i = 0; i < 4; ++i)
    tile[ty + i * 8][tx] = __float2bfloat16(in[(size_t)(r0 + ty + i * 8) * C + c0 + tx]);
  __syncthreads();
#pragma unroll
  for (int i = 0; i < 4; ++i)
    out[(size_t)(c0 + ty + i * 8) * R + r0 + tx] = tile[tx][ty + i * 8];
}

// ---------------------------------------------------------------------------
// Transpose+split fp32 [R][C] -> bf16 hi [C][R], bf16 lo [C][R]
// ---------------------------------------------------------------------------
__global__ __launch_bounds__(256) void transpose_split(
    const float* __restrict__ in, bf16_t* __restrict__ hiT,
    bf16_t* __restrict__ loT, int R, int C) {
  __shared__ bf16_t th[32][33];
  __shared__ bf16_t tl[32][33];
  int c0 = blockIdx.x * 32, r0 = blockIdx.y * 32;
  int tx = threadIdx.x & 31, ty = threadIdx.x >> 5;
#pragma unroll
  for (int i = 0; i < 4; ++i) {
    float x = in[(size_t)(r0 + ty + i * 8) * C + c0 + tx];
    bf16_t h, l; split2(x, h, l);
    th[ty + i * 8][tx] = h;
    tl[ty + i * 8][tx] = l;
  }
  __syncthreads();
#pragma unroll
  for (int i = 0; i < 4; ++i) {
    hiT[(size_t)(c0 + ty + i * 8) * R + r0 + tx] = th[tx][ty + i * 8];
    loT[(size_t)(c0 + ty + i * 8) * R + r0 + tx] = tl[tx][ty + i * 8];
  }
}

// ---------------------------------------------------------------------------
// Shared helpers for pipelined GEMMs
// ---------------------------------------------------------------------------
#define VMCNT_(n) asm volatile("s_waitcnt vmcnt(" #n ")" ::: "memory")
#define VMCNT(n) VMCNT_(n)
#define BARRIER()                     \
  {                                   \
    asm volatile("" ::: "memory");    \
    __builtin_amdgcn_s_barrier();     \
    asm volatile("" ::: "memory");    \
  }

#define MFMA_(a, b, c) __builtin_amdgcn_mfma_f32_16x16x32_bf16(a, b, c, 0, 0, 0)

// ---------------------------------------------------------------------------
// Split-precision GEMM v4: C = Ah*Bh + Ah*Bl + Al*Bh, pipelined.
// BM=256, BN=192, BK=32, 512 threads (8 waves, 2M x 4N).
// Double-buffered LDS (112 KB). ONE barrier + one vmcnt(0) per K-step:
// loads for step i+1 are issued AFTER the step-i barrier into the other
// buffer, so vmcnt(0) at the top of step i+1 waits on loads issued a full
// K-step (~4500 cyc) earlier -> free drain. The single barrier guarantees
// both "everyone's loads landed" (each wave vmcnt(0)'d its own) and
// "everyone finished reading the buffer about to be overwritten".
// ---------------------------------------------------------------------------
#define OFF_AH 0
#define OFF_AL 16384
#define OFF_BH 32768
#define OFF_BL 45056
#define BUFSZ  57344

#define LOADB()                                                   \
  _Pragma("unroll")                                               \
  for (int j = 0; j < 3; ++j) {                                   \
    const char* bp_ = bufc + (wn + j * 16 + l16) * 64 + rdq;      \
    bh[j] = *(const fragAB*)(bp_ + OFF_BH);                       \
    bl[j] = *(const fragAB*)(bp_ + OFF_BL);                       \
  }

struct ARegs { fragAB ah0, al0, ah1, al1; };

__device__ __forceinline__ void lda_split(ARegs& r, const char* bufc, int wm,
                                          int p, int l16, int rdq) {
  const char* a0 = bufc + (wm + (2 * p) * 16 + l16) * 64 + rdq;
  const char* a1 = a0 + 16 * 64;
  r.ah0 = *(const fragAB*)(a0 + OFF_AH);
  r.al0 = *(const fragAB*)(a0 + OFF_AL);
  r.ah1 = *(const fragAB*)(a1 + OFF_AH);
  r.al1 = *(const fragAB*)(a1 + OFF_AL);
}

__device__ __forceinline__ void mfma_split(fragC (&acc)[8][3], const ARegs& r,
                                           const fragAB (&bh)[3],
                                           const fragAB (&bl)[3], int p) {
  __builtin_amdgcn_s_setprio(1);
#pragma unroll
  for (int j = 0; j < 3; ++j) {
    acc[2 * p][j]     = MFMA_(r.al0, bh[j], acc[2 * p][j]);
    acc[2 * p + 1][j] = MFMA_(r.al1, bh[j], acc[2 * p + 1][j]);
  }
#pragma unroll
  for (int j = 0; j < 3; ++j) {
    acc[2 * p][j]     = MFMA_(r.ah0, bl[j], acc[2 * p][j]);
    acc[2 * p + 1][j] = MFMA_(r.ah1, bl[j], acc[2 * p + 1][j]);
  }
#pragma unroll
  for (int j = 0; j < 3; ++j) {
    acc[2 * p][j]     = MFMA_(r.ah0, bh[j], acc[2 * p][j]);
    acc[2 * p + 1][j] = MFMA_(r.ah1, bh[j], acc[2 * p + 1][j]);
  }
  __builtin_amdgcn_s_setprio(0);
}

// step body shared by main loop and tail (reads bufc only)
#define SPLIT_STEP()                        \
  {                                         \
    LOADB();                                \
    lda_split(r0, bufc, wm, 0, l16, rdq);   \
    lda_split(r1, bufc, wm, 1, l16, rdq);   \
    mfma_split(acc, r0, bh, bl, 0);         \
    lda_split(r0, bufc, wm, 2, l16, rdq);   \
    mfma_split(acc, r1, bh, bl, 1);         \
    lda_split(r1, bufc, wm, 3, l16, rdq);   \
    mfma_split(acc, r0, bh, bl, 2);         \
    mfma_split(acc, r1, bh, bl, 3);         \
  }

__global__ __launch_bounds__(512, 2) void gemm_split2(
    const bf16_t* __restrict__ Ah, const bf16_t* __restrict__ Al,
    const bf16_t* __restrict__ Bh, const bf16_t* __restrict__ Bl,
    float* __restrict__ C, int M, int N, int K) {
  __shared__ __align__(16) char lds[2 * BUFSZ];
  const int t = threadIdx.x;
  const int wave = t >> 6, lane = t & 63;
  const int quad = lane >> 4, l16 = lane & 15;
  const int m0 = blockIdx.y * 256, n0 = blockIdx.x * 192;
  const int wm = (wave >> 2) * 128, wn = (wave & 3) * 48;
  // T2 read swizzle: phys 16B-slot of (row r, col-16B q) = q ^ ((r>>1)&3).
  const int rdq = (quad ^ ((l16 >> 1) & 3)) * 16;

  // Per-lane global source offset inside a 16-row x 32-col chunk (inverse swizzle).
  const size_t laneOff =
      (size_t)(lane >> 2) * K * 2 + 16 * ((lane & 3) ^ ((lane >> 3) & 3));

  // 7 staging chunks per wave per K-step.
  const char* gsrc[7];
  int ldsOff[7];
#pragma unroll
  for (int pos = 0; pos < 3; ++pos) {
    int c = wave + 8 * pos;            // 0..23: Bh chunks 0..11, Bl chunks 0..11
    if (c < 12) {
      gsrc[pos]   = (const char*)Bh + (size_t)(n0 + 16 * c) * K * 2 + laneOff;
      ldsOff[pos] = OFF_BH + c * 1024;
    } else {
      gsrc[pos]   = (const char*)Bl + (size_t)(n0 + 16 * (c - 12)) * K * 2 + laneOff;
      ldsOff[pos] = OFF_BL + (c - 12) * 1024;
    }
  }
#pragma unroll
  for (int p = 0; p < 4; ++p) {
    int sub = wave & 3;
    int R0 = ((sub >> 1) & 1) * 128 + 32 * p + (sub & 1) * 16;
    const char* base = (const char*)(wave < 4 ? Ah : Al);
    gsrc[3 + p]   = base + (size_t)(m0 + R0) * K * 2 + laneOff;
    ldsOff[3 + p] = (wave < 4 ? OFF_AH : OFF_AL) + R0 * 64;
  }

  fragC zero4 = {0.f, 0.f, 0.f, 0.f};
  fragC acc[8][3];
#pragma unroll
  for (int i = 0; i < 8; ++i)
#pragma unroll
    for (int j = 0; j < 3; ++j) acc[i][j] = zero4;

  char* ldsc = (char*)lds;
  // prologue: stage K-step 0 into buffer 0
#pragma unroll
  for (int ps = 0; ps < 7; ++ps) async_copy16(gsrc[ps], ldsc + ldsOff[ps]);
#pragma unroll
  for (int ps = 0; ps < 7; ++ps) gsrc[ps] += 64;

  fragAB bh[3], bl[3];
  ARegs r0, r1;
  int cur = 0;
  const int NS = K / 32;
  for (int it = 0; it < NS - 1; ++it) {
    const char* bufc = ldsc + cur * BUFSZ;
    char* nb = ldsc + (cur ^ 1) * BUFSZ;
    // drain this step's loads (issued a full K-step ago -> no stall) and
    // rendezvous; after the barrier, nb is safe to overwrite.
    VMCNT(0); BARRIER();
#pragma unroll
    for (int ps = 0; ps < 7; ++ps) async_copy16(gsrc[ps], nb + ldsOff[ps]);
#pragma unroll
    for (int ps = 0; ps < 7; ++ps) gsrc[ps] += 64;
    SPLIT_STEP();
    cur ^= 1;
  }
  {  // final K-step
    const char* bufc = ldsc + cur * BUFSZ;
    VMCNT(0); BARRIER();
    SPLIT_STEP();
  }

#pragma unroll
  for (int i = 0; i < 8; ++i)
#pragma unroll
    for (int j = 0; j < 3; ++j)
#pragma unroll
      for (int r = 0; r < 4; ++r) {
        int row = m0 + wm + i * 16 + quad * 4 + r;
        int col = n0 + wn + j * 16 + l16;
        C[(size_t)row * N + col] = acc[i][j][r];
      }
}

// ---------------------------------------------------------------------------
// Plain GEMM v3 (output projection): C[M][N] = A[M][K]*Bt[N][K]^T, fp32 out.
// BM=256, BN=128, BK=64, 512 threads (8 waves as 2M x 4N -> wave tile 128x32).
// Same 1-barrier-per-K-step schedule as gemm_split2.
// ---------------------------------------------------------------------------
#define BT_OFF_A 0
#define BT_OFF_B 32768
#define BT_BUFSZ 49152

struct ARegs2 { fragAB a[2][2]; };  // [row-in-pair][k-slice]

__device__ __forceinline__ void lda_bt(ARegs2& r, const char* bufc, int wm,
                                       int p, int l16, int quad, int rx) {
#pragma unroll
  for (int u = 0; u < 2; ++u)
#pragma unroll
    for (int ks = 0; ks < 2; ++ks)
      r.a[u][ks] = *(const fragAB*)(bufc + BT_OFF_A +
                                    (wm + (2 * p + u) * 16 + l16) * 128 +
                                    (((ks * 4 + quad) ^ rx) * 16));
}

__device__ __forceinline__ void mfma_bt(fragC (&acc)[8][2], const ARegs2& r,
                                        const fragAB (&b)[2][2], int p) {
  __builtin_amdgcn_s_setprio(1);
#pragma unroll
  for (int ks = 0; ks < 2; ++ks)
#pragma unroll
    for (int j = 0; j < 2; ++j) {
      acc[2 * p][j]     = MFMA_(r.a[0][ks], b[j][ks], acc[2 * p][j]);
      acc[2 * p + 1][j] = MFMA_(r.a[1][ks], b[j][ks], acc[2 * p + 1][j]);
    }
  __builtin_amdgcn_s_setprio(0);
}

#define BT_LOADB()                                                        \
  _Pragma("unroll")                                                       \
  for (int j = 0; j < 2; ++j)                                             \
  _Pragma("unroll")                                                       \
    for (int ks = 0; ks < 2; ++ks)                                        \
      bfr[j][ks] = *(const fragAB*)(bufc + BT_OFF_B +                     \
                                    (wn + j * 16 + l16) * 128 +           \
                                    (((ks * 4 + quad) ^ rx) * 16));

#define BT_STEP()                                 \
  {                                               \
    BT_LOADB();                                   \
    lda_bt(r0, bufc, wm, 0, l16, quad, rx);       \
    lda_bt(r1, bufc, wm, 1, l16, quad, rx);       \
    mfma_bt(acc, r0, bfr, 0);                     \
    lda_bt(r0, bufc, wm, 2, l16, quad, rx);       \
    mfma_bt(acc, r1, bfr, 1);                     \
    lda_bt(r1, bufc, wm, 3, l16, quad, rx);       \
    mfma_bt(acc, r0, bfr, 2);                     \
    mfma_bt(acc, r1, bfr, 3);                     \
  }

__global__ __launch_bounds__(512, 2) void gemm_bt2(
    const bf16_t* __restrict__ A, const bf16_t* __restrict__ Bt,
    float* __restrict__ C, int M, int N, int K) {
  __shared__ __align__(16) char lds[2 * BT_BUFSZ];
  const int t = threadIdx.x;
  const int wave = t >> 6, lane = t & 63;
  const int quad = lane >> 4, l16 = lane & 15;
  const int m0 = blockIdx.y * 256, n0 = blockIdx.x * 128;
  const int wm = (wave >> 2) * 128, wn = (wave & 3) * 32;
  const int rx = l16 & 7;  // row-XOR for 8-slot swizzle (128B rows)

  // chunk = 8 rows x 64 cols (128B rows). lane l stages row l>>3,
  // logical col16 (l&7)^((l>>3)&7) -> LDS phys slot l&7 (inverse swizzle).
  const size_t laneOff =
      (size_t)(lane >> 3) * K * 2 + 16 * ((lane & 7) ^ ((lane >> 3) & 7));

  // 6 staging chunks per wave per K-step: B,B,A0..A3.
  const char* gsrc[6];
  int ldsOff[6];
#pragma unroll
  for (int pos = 0; pos < 2; ++pos) {
    int c = wave + 8 * pos;  // B chunks 0..15, rows [8c,8c+8)
    gsrc[pos]   = (const char*)Bt + (size_t)(n0 + 8 * c) * K * 2 + laneOff;
    ldsOff[pos] = BT_OFF_B + c * 1024;
  }
#pragma unroll
  for (int p = 0; p < 4; ++p) {
    int R0 = (wave >> 2) * 128 + 32 * p + (wave & 3) * 8;
    gsrc[2 + p]   = (const char*)A + (size_t)(m0 + R0) * K * 2 + laneOff;
    ldsOff[2 + p] = BT_OFF_A + R0 * 128;
  }

  fragC zero4 = {0.f, 0.f, 0.f, 0.f};
  fragC acc[8][2];
#pragma unroll
  for (int i = 0; i < 8; ++i)
#pragma unroll
    for (int j = 0; j < 2; ++j) acc[i][j] = zero4;

  char* ldsc = (char*)lds;
#pragma unroll
  for (int ps = 0; ps < 6; ++ps) async_copy16(gsrc[ps], ldsc + ldsOff[ps]);
#pragma unroll
  for (int ps = 0; ps < 6; ++ps) gsrc[ps] += 128;

  fragAB bfr[2][2];
  ARegs2 r0, r1;
  int cur = 0;
  const int NS = K / 64;
  for (int it = 0; it < NS - 1; ++it) {
    const char* bufc = ldsc + cur * BT_BUFSZ;
    char* nb = ldsc + (cur ^ 1) * BT_BUFSZ;
    VMCNT(0); BARRIER();
#pragma unroll
    for (int ps = 0; ps < 6; ++ps) async_copy16(gsrc[ps], nb + ldsOff[ps]);
#pragma unroll
    for (int ps = 0; ps < 6; ++ps) gsrc[ps] += 128;
    BT_STEP();
    cur ^= 1;
  }
  {
    const char* bufc = ldsc + cur * BT_BUFSZ;
    VMCNT(0); BARRIER();
    BT_STEP();
  }

#pragma unroll
  for (int i = 0; i < 8; ++i)
#pragma unroll
    for (int j = 0; j < 2; ++j)
#pragma unroll
      for (int r = 0; r < 4; ++r) {
        int row = m0 + wm + i * 16 + quad * 4 + r;
        int col = n0 + wn + j * 16 + l16;
        C[(size_t)row * N + col] = acc[i][j][r];
      }
}

// ---------------------------------------------------------------------------
// RMS-norm (+fp32 weight) + RoPE, fp32 in -> split bf16 hi/lo out.
// proj row stride inStride, head-block starts at inOff. Output stride outStride.
// ---------------------------------------------------------------------------
__global__ __launch_bounds__(256) void rmsnorm_rope_split(
    const float* __restrict__ proj, const float* __restrict__ w,
    const float* __restrict__ cosb, const float* __restrict__ sinb,
    bf16_t* __restrict__ qhi, bf16_t* __restrict__ qlo,
    int inStride, int inOff, int outStride) {
  int s = blockIdx.x, h = blockIdx.y, d = threadIdx.x;
  float x = proj[(size_t)s * inStride + inOff + h * DHEAD + d];
  float ss = x * x;
  ss += __shfl_xor(ss, 1);  ss += __shfl_xor(ss, 2);  ss += __shfl_xor(ss, 4);
  ss += __shfl_xor(ss, 8);  ss += __shfl_xor(ss, 16); ss += __shfl_xor(ss, 32);
  __shared__ float part[4];
  __shared__ float xs[DHEAD];
  if ((threadIdx.x & 63) == 0) part[threadIdx.x >> 6] = ss;
  __syncthreads();
  float tot = part[0] + part[1] + part[2] + part[3];
  float r = rsqrtf(tot * (1.0f / DHEAD) + 1e-6f);
  float xn = x * r * w[d];
  xs[d] = xn;
  __syncthreads();
  float other = xs[(d + 128) & 255];
  float rot = (d < 128) ? -other : other;
  float y = xn * cosb[(size_t)s * DHEAD + d] + rot * sinb[(size_t)s * DHEAD + d];
  bf16_t h2, l2; split2(y, h2, l2);
  size_t oidx = (size_t)s * outStride + h * DHEAD + d;
  qhi[oidx] = h2;
  qlo[oidx] = l2;
}

// ---------------------------------------------------------------------------
// RMS-norm (no weight), fp32 in (stride/offset), bf16 out transposed [NKV][D][S]
// ---------------------------------------------------------------------------
__global__ __launch_bounds__(256) void rmsnorm_vT(
    const float* __restrict__ proj, bf16_t* __restrict__ vt,
    int inStride, int inOff) {
  int s = blockIdx.x, h = blockIdx.y, d = threadIdx.x;
  float x = proj[(size_t)s * inStride + inOff + h * DHEAD + d];
  float ss = x * x;
  ss += __shfl_xor(ss, 1);  ss += __shfl_xor(ss, 2);  ss += __shfl_xor(ss, 4);
  ss += __shfl_xor(ss, 8);  ss += __shfl_xor(ss, 16); ss += __shfl_xor(ss, 32);
  __shared__ float part[4];
  if ((threadIdx.x & 63) == 0) part[threadIdx.x >> 6] = ss;
  __syncthreads();
  float tot = part[0] + part[1] + part[2] + part[3];
  float r = rsqrtf(tot * (1.0f / DHEAD) + 1e-6f);
  vt[((size_t)h * DHEAD + d) * S_LEN + s] = __float2bfloat16(x * r);
}

// ---------------------------------------------------------------------------
// Flash attention, sliding window 512, NO score scale, GQA G=4.
// K/V staged in LDS per 32-key step, XOR source-swizzled (see R6 notes).
// ---------------------------------------------------------------------------
__global__ __launch_bounds__(256) void attn_split(
    const bf16_t* __restrict__ Qhi, const bf16_t* __restrict__ Qlo,
    const bf16_t* __restrict__ Khi, const bf16_t* __restrict__ Klo,
    const bf16_t* __restrict__ Vt, bf16_t* __restrict__ Aout) {
  const int h = blockIdx.y;
  const int qb = blockIdx.x * 64;
  const int wave = threadIdx.x >> 6, lane = threadIdx.x & 63;
  const int quad = lane >> 4, l16 = lane & 15;
  const int qw = qb + wave * 16;
  const int kv = h >> 2;  // G = 4
  const bf16_t* Qh_ = Qhi + h * DHEAD;   // row stride NHQ*DHEAD
  const bf16_t* Ql_ = Qlo + h * DHEAD;
  const bf16_t* Kh_ = Khi + kv * DHEAD;  // row stride NKVH*DHEAD
  const bf16_t* Kl_ = Klo + kv * DHEAD;
  const bf16_t* Vh_ = Vt + (size_t)kv * DHEAD * S_LEN;

  __shared__ __align__(16) bf16_t KshH[32 * 256];
  __shared__ __align__(16) bf16_t KshL[32 * 256];
  __shared__ __align__(16) bf16_t Vsh[256 * 32];
  __shared__ __align__(16) bf16_t Plds[4][16 * 32];

  fragAB qfh[8], qfl[8];
#pragma unroll
  for (int c = 0; c < 8; ++c) {
    size_t off = (size_t)(qw + l16) * (NHQ * DHEAD) + c * 32 + quad * 8;
    qfh[c] = *(const fragAB*)(Qh_ + off);
    qfl[c] = *(const fragAB*)(Ql_ + off);
  }

  int kRow[4], kCol[4], vRow[4], vCol[4];
#pragma unroll
  for (int i = 0; i < 4; ++i) {
    int ci = (i * 4 + wave) * 64 + lane;
    int r = ci >> 5, sc = ci & 31;
    kRow[i] = r;
    kCol[i] = (sc ^ r) * 8;
    int rv = ci >> 2, scv = ci & 3;
    vRow[i] = rv;
    vCol[i] = (scv ^ (rv & 3)) * 8;
  }

  fragC zero4 = {0.f, 0.f, 0.f, 0.f};
  fragC o_acc[16];
#pragma unroll
  for (int c = 0; c < 16; ++c) o_acc[c] = zero4;
  float m_run[4] = {NEG_BIG, NEG_BIG, NEG_BIG, NEG_BIG};
  float l_run[4] = {0.f, 0.f, 0.f, 0.f};
  const float LOG2E = 1.4426950408889634f;

  int k_lo = qb - (WIN - 1);
  if (k_lo < 0) k_lo = 0;
  k_lo &= ~31;

  for (int kb = k_lo; kb < qb + 64; kb += 32) {
#pragma unroll
    for (int i = 0; i < 4; ++i) {
      size_t dst = (size_t)(i * 4 + wave) * 1024;
      size_t koff = (size_t)(kb + kRow[i]) * (NKVH * DHEAD) + kCol[i];
      async_copy16(Kh_ + koff, (char*)KshH + dst);
      async_copy16(Kl_ + koff, (char*)KshL + dst);
      async_copy16(Vh_ + (size_t)vRow[i] * S_LEN + kb + vCol[i], (char*)Vsh + dst);
    }
    __syncthreads();

    fragC s0 = zero4, s1 = zero4;
#pragma unroll
    for (int c = 0; c < 8; ++c) {
      int j = c * 4 + quad;
      int off0 = (l16 * 32 + (j ^ l16)) * 16;
      int off1 = ((16 + l16) * 32 + (j ^ (16 + l16))) * 16;
      fragAB kh0 = *(const fragAB*)((const char*)KshH + off0);
      fragAB kl0 = *(const fragAB*)((const char*)KshL + off0);
      fragAB kh1 = *(const fragAB*)((const char*)KshH + off1);
      fragAB kl1 = *(const fragAB*)((const char*)KshL + off1);
      s0 = __builtin_amdgcn_mfma_f32_16x16x32_bf16(qfl[c], kh0, s0, 0, 0, 0);
      s0 = __builtin_amdgcn_mfma_f32_16x16x32_bf16(qfh[c], kl0, s0, 0, 0, 0);
      s0 = __builtin_amdgcn_mfma_f32_16x16x32_bf16(qfh[c], kh0, s0, 0, 0, 0);
      s1 = __builtin_amdgcn_mfma_f32_16x16x32_bf16(qfl[c], kh1, s1, 0, 0, 0);
      s1 = __builtin_amdgcn_mfma_f32_16x16x32_bf16(qfh[c], kl1, s1, 0, 0, 0);
      s1 = __builtin_amdgcn_mfma_f32_16x16x32_bf16(qfh[c], kh1, s1, 0, 0, 0);
    }

    float p0[4], p1[4], alpha[4];
#pragma unroll
    for (int r = 0; r < 4; ++r) {
      int qi = qw + quad * 4 + r;
      int k0i = kb + l16;
      int k1i = k0i + 16;
      bool v0 = (k0i <= qi) && (qi - k0i < WIN);
      bool v1 = (k1i <= qi) && (qi - k1i < WIN);
      float sv0 = v0 ? s0[r] : NEG_BIG;
      float sv1 = v1 ? s1[r] : NEG_BIG;
      float mx = fmaxf(sv0, sv1);
      mx = fmaxf(mx, __shfl_xor(mx, 1));
      mx = fmaxf(mx, __shfl_xor(mx, 2));
      mx = fmaxf(mx, __shfl_xor(mx, 4));
      mx = fmaxf(mx, __shfl_xor(mx, 8));
      float mn = fmaxf(m_run[r], mx);
      float a  = exp2f(fmaxf(m_run[r] - mn, -80.f) * LOG2E);
      float e0 = v0 ? exp2f(fmaxf(s0[r] - mn, -80.f) * LOG2E) : 0.f;
      float e1 = v1 ? exp2f(fmaxf(s1[r] - mn, -80.f) * LOG2E) : 0.f;
      float rs = e0 + e1;
      rs += __shfl_xor(rs, 1);
      rs += __shfl_xor(rs, 2);
      rs += __shfl_xor(rs, 4);
      rs += __shfl_xor(rs, 8);
      l_run[r] = l_run[r] * a + rs;
      m_run[r] = mn;
      alpha[r] = a; p0[r] = e0; p1[r] = e1;
    }
#pragma unroll
    for (int c = 0; c < 16; ++c)
#pragma unroll
      for (int r = 0; r < 4; ++r) o_acc[c][r] *= alpha[r];

    bf16_t* Pw = Plds[wave];
#pragma unroll
    for (int r = 0; r < 4; ++r) {
      Pw[(quad * 4 + r) * 32 + l16]      = __float2bfloat16(p0[r]);
      Pw[(quad * 4 + r) * 32 + 16 + l16] = __float2bfloat16(p1[r]);
    }
    fragAB pf = *(const fragAB*)((const char*)Pw + l16 * 64 + quad * 16);

#pragma unroll
    for (int c = 0; c < 16; ++c) {
      int d = c * 16 + l16;
      int offv = (d * 4 + (quad ^ (d & 3))) * 16;
      fragAB vf = *(const fragAB*)((const char*)Vsh + offv);
      o_acc[c] = __builtin_amdgcn_mfma_f32_16x16x32_bf16(pf, vf, o_acc[c], 0, 0, 0);
    }
    __syncthreads();
  }

  float inv_l[4];
#pragma unroll
  for (int r = 0; r < 4; ++r) inv_l[r] = 1.0f / l_run[r];
#pragma unroll
  for (int c = 0; c < 16; ++c)
#pragma unroll
    for (int r = 0; r < 4; ++r) {
      int row = qw + quad * 4 + r;
      int col = h * DHEAD + c * 16 + l16;
      Aout[(size_t)row * (NHQ * DHEAD) + col] = __float2bfloat16(o_acc[c][r] * inv_l[r]);
    }
}

// ---------------------------------------------------------------------------
extern "C" void kernel_launch(void* const* d_in, const int* in_sizes, int n_in,
                              void* d_out, int out_size, void* d_ws, size_t ws_size,
                              hipStream_t stream) {
  const float* hid  = (const float*)d_in[0];
  const float* w_q  = (const float*)d_in[1];
  const float* w_k  = (const float*)d_in[2];
  const float* w_v  = (const float*)d_in[3];
  const float* w_o  = (const float*)d_in[4];
  const float* qnw  = (const float*)d_in[5];
  const float* knw  = (const float*)d_in[6];
  const float* cosb = (const float*)d_in[7];
  const float* sinb = (const float*)d_in[8];
  float* outp = (float*)d_out;

  // Workspace (bf16 slots, M1 = 1<<20), peak 52M slots = 104 MiB:
  //  [ 0: 8M)  hidh  -> qh  (after qkv gemm)
  //  [ 8:16M)  hidl  -> ql
  //  [16:22M)  wTh (3072x2048) -> kh[16:18M), kl[18:20M), vt[20:22M) after gemm
  //  [22:28M)  wTl   -> woT[22:26M) after gemm
  //  [28:52M)  projqkv f32 (4096x3072) -> aout[28:36M) after norms
  const size_t M1 = 1048576;
  bf16_t* w = (bf16_t*)d_ws;
  bf16_t* hidh  = w;
  bf16_t* qh    = w;                         // alias hidh
  bf16_t* hidl  = w + 8 * M1;
  bf16_t* ql    = w + 8 * M1;                // alias hidl
  bf16_t* wTh   = w + 16 * M1;
  bf16_t* kh    = w + 16 * M1;               // alias wTh
  bf16_t* kl    = w + 18 * M1;
  bf16_t* vt    = w + 20 * M1;
  bf16_t* wTl   = w + 22 * M1;
  bf16_t* woT   = w + 22 * M1;               // alias wTl
  float*  projqkv = (float*)(w + 28 * M1);
  bf16_t* aout  = w + 28 * M1;               // alias projqkv (after norms)

  // phase 0: split hidden; split-transpose [wq|wk|wv] into fused wT [3072][2048]
  split_f32<<<(S_LEN * HDIM) / 1024, 256, 0, stream>>>(hid, hidh, hidl, S_LEN * HDIM);
  transpose_split<<<dim3((NHQ * DHEAD) / 32, HDIM / 32), 256, 0, stream>>>(
      w_q, wTh, wTl, HDIM, NHQ * DHEAD);
  transpose_split<<<dim3((NKVH * DHEAD) / 32, HDIM / 32), 256, 0, stream>>>(
      w_k, wTh + (size_t)(NHQ * DHEAD) * HDIM, wTl + (size_t)(NHQ * DHEAD) * HDIM,
      HDIM, NKVH * DHEAD);
  transpose_split<<<dim3((NKVH * DHEAD) / 32, HDIM / 32), 256, 0, stream>>>(
      w_v, wTh + (size_t)(NHQ * DHEAD + NKVH * DHEAD) * HDIM,
      wTl + (size_t)(NHQ * DHEAD + NKVH * DHEAD) * HDIM, HDIM, NKVH * DHEAD);

  // phase 1: fused q+k+v split projection, pipelined 256x192 tiles
  //          grid 16x16 = 256 blocks = exactly 1 per CU
  gemm_split2<<<dim3(NQKV / 192, S_LEN / 256), 512, 0, stream>>>(
      hidh, hidl, wTh, wTl, projqkv, S_LEN, NQKV, HDIM);

  // phase 2: norms (hid/wT dead -> qh/ql/kh/kl/vt targets)
  rmsnorm_rope_split<<<dim3(S_LEN, NHQ), 256, 0, stream>>>(
      projqkv, qnw, cosb, sinb, qh, ql, NQKV, 0, NHQ * DHEAD);
  rmsnorm_rope_split<<<dim3(S_LEN, NKVH), 256, 0, stream>>>(
      projqkv, knw, cosb, sinb, kh, kl, NQKV, NHQ * DHEAD, NKVH * DHEAD);
  rmsnorm_vT<<<dim3(S_LEN, NKVH), 256, 0, stream>>>(
      projqkv, vt, NQKV, NHQ * DHEAD + NKVH * DHEAD);

  // phase 3: w_o transpose into dead wTl region
  transpose_cvt<<<dim3(HDIM / 32, (NHQ * DHEAD) / 32), 256, 0, stream>>>(w_o, woT, NHQ * DHEAD, HDIM);

  // phase 4: attention -> aout (dead projqkv region)
  attn_split<<<dim3(S_LEN / 64, NHQ), 256, 0, stream>>>(qh, ql, kh, kl, vt, aout);

  // phase 5: output projection -> fp32 d_out, pipelined 256x128 tiles
  //          grid 16x16 = 256 blocks = exactly 1 per CU
  gemm_bt2<<<dim3(HDIM / 128, S_LEN / 256), 512, 0, stream>>>(
      aout, woT, outp, S_LEN, HDIM, NHQ * DHEAD);
}

// Round 4
// 419.392 us; speedup vs baseline: 1.2543x; 1.0492x over previous
//
#include <hip/hip_runtime.h>
#include <hip/hip_bf16.h>

#define S_LEN 4096
#define HDIM  2048
#define NHQ   8
#define NKVH  2
#define DHEAD 256
#define WIN   512
#define NQKV  3072   // fused q+k+v projection width (2048 + 512 + 512)

typedef __hip_bfloat16 bf16_t;
using fragAB = __attribute__((ext_vector_type(8))) short;  // 8 bf16
using fragC  = __attribute__((ext_vector_type(4))) float;  // 4 fp32

typedef unsigned int u32;
typedef const __attribute__((address_space(1))) u32* gas_ptr;
typedef __attribute__((address_space(3))) u32* las_ptr;

__device__ __forceinline__ void async_copy16(const void* g, void* l) {
  __builtin_amdgcn_global_load_lds((gas_ptr)g, (las_ptr)l, 16, 0, 0);
}

#define NEG_BIG (-3.0e38f)

__device__ __forceinline__ void split2(float x, bf16_t& hi, bf16_t& lo) {
  bf16_t h = __float2bfloat16(x);
  hi = h;
  lo = __float2bfloat16(x - (float)h);
}

// ---------------------------------------------------------------------------
// Elementwise split fp32 -> bf16 hi + bf16 lo  (n multiple of 1024)
// ---------------------------------------------------------------------------
__global__ __launch_bounds__(256) void split_f32(
    const float* __restrict__ in, bf16_t* __restrict__ hi,
    bf16_t* __restrict__ lo, int n) {
  int i = (blockIdx.x * 256 + threadIdx.x) * 4;
  if (i >= n) return;
  float4 v = *(const float4*)(in + i);
  split2(v.x, hi[i + 0], lo[i + 0]);
  split2(v.y, hi[i + 1], lo[i + 1]);
  split2(v.z, hi[i + 2], lo[i + 2]);
  split2(v.w, hi[i + 3], lo[i + 3]);
}

// ---------------------------------------------------------------------------
// Transpose+convert fp32 [R][C] -> bf16 [C][R]
// ---------------------------------------------------------------------------
__global__ __launch_bounds__(256) void transpose_cvt(
    const float* __restrict__ in, bf16_t* __restrict__ out, int R, int C) {
  __shared__ bf16_t tile[32][33];
  int c0 = blockIdx.x * 32, r0 = blockIdx.y * 32;
  int tx = threadIdx.x & 31, ty = threadIdx.x >> 5;
#pragma unroll
  for (int i = 0; i < 4; ++i)
    tile[ty + i * 8][tx] = __float2bfloat16(in[(size_t)(r0 + ty + i * 8) * C + c0 + tx]);
  __syncthreads();
#pragma unroll
  for (int i = 0; i < 4; ++i)
    out[(size_t)(c0 + ty + i * 8) * R + r0 + tx] = tile[tx][ty + i * 8];
}

// ---------------------------------------------------------------------------
// Transpose+split fp32 [R][C] -> bf16 hi [C][R], bf16 lo [C][R]
// ---------------------------------------------------------------------------
__global__ __launch_bounds__(256) void transpose_split(
    const float* __restrict__ in, bf16_t* __restrict__ hiT,
    bf16_t* __restrict__ loT, int R, int C) {
  __shared__ bf16_t th[32][33];
  __shared__ bf16_t tl[32][33];
  int c0 = blockIdx.x * 32, r0 = blockIdx.y * 32;
  int tx = threadIdx.x & 31, ty = threadIdx.x >> 5;
#pragma unroll
  for (int i = 0; i < 4; ++i) {
    float x = in[(size_t)(r0 + ty + i * 8) * C + c0 + tx];
    bf16_t h, l; split2(x, h, l);
    th[ty + i * 8][tx] = h;
    tl[ty + i * 8][tx] = l;
  }
  __syncthreads();
#pragma unroll
  for (int i = 0; i < 4; ++i) {
    hiT[(size_t)(c0 + ty + i * 8) * R + r0 + tx] = th[tx][ty + i * 8];
    loT[(size_t)(c0 + ty + i * 8) * R + r0 + tx] = tl[tx][ty + i * 8];
  }
}

// ---------------------------------------------------------------------------
// Shared helpers for pipelined GEMMs
// ---------------------------------------------------------------------------
#define VMCNT_(n) asm volatile("s_waitcnt vmcnt(" #n ")" ::: "memory")
#define VMCNT(n) VMCNT_(n)
#define BARRIER()                     \
  {                                   \
    asm volatile("" ::: "memory");    \
    __builtin_amdgcn_s_barrier();     \
    asm volatile("" ::: "memory");    \
  }

#define MFMA_(a, b, c) __builtin_amdgcn_mfma_f32_16x16x32_bf16(a, b, c, 0, 0, 0)

// ---------------------------------------------------------------------------
// Split-precision GEMM v4: C = Ah*Bh + Ah*Bl + Al*Bh, pipelined.
// BM=256, BN=192, BK=32, 512 threads (8 waves, 2M x 4N).
// Double-buffered LDS (112 KB). ONE barrier + one vmcnt(0) per K-step.
// ---------------------------------------------------------------------------
#define OFF_AH 0
#define OFF_AL 16384
#define OFF_BH 32768
#define OFF_BL 45056
#define BUFSZ  57344

#define LOADB()                                                   \
  _Pragma("unroll")                                               \
  for (int j = 0; j < 3; ++j) {                                   \
    const char* bp_ = bufc + (wn + j * 16 + l16) * 64 + rdq;      \
    bh[j] = *(const fragAB*)(bp_ + OFF_BH);                       \
    bl[j] = *(const fragAB*)(bp_ + OFF_BL);                       \
  }

struct ARegs { fragAB ah0, al0, ah1, al1; };

__device__ __forceinline__ void lda_split(ARegs& r, const char* bufc, int wm,
                                          int p, int l16, int rdq) {
  const char* a0 = bufc + (wm + (2 * p) * 16 + l16) * 64 + rdq;
  const char* a1 = a0 + 16 * 64;
  r.ah0 = *(const fragAB*)(a0 + OFF_AH);
  r.al0 = *(const fragAB*)(a0 + OFF_AL);
  r.ah1 = *(const fragAB*)(a1 + OFF_AH);
  r.al1 = *(const fragAB*)(a1 + OFF_AL);
}

__device__ __forceinline__ void mfma_split(fragC (&acc)[8][3], const ARegs& r,
                                           const fragAB (&bh)[3],
                                           const fragAB (&bl)[3], int p) {
  __builtin_amdgcn_s_setprio(1);
#pragma unroll
  for (int j = 0; j < 3; ++j) {
    acc[2 * p][j]     = MFMA_(r.al0, bh[j], acc[2 * p][j]);
    acc[2 * p + 1][j] = MFMA_(r.al1, bh[j], acc[2 * p + 1][j]);
  }
#pragma unroll
  for (int j = 0; j < 3; ++j) {
    acc[2 * p][j]     = MFMA_(r.ah0, bl[j], acc[2 * p][j]);
    acc[2 * p + 1][j] = MFMA_(r.ah1, bl[j], acc[2 * p + 1][j]);
  }
#pragma unroll
  for (int j = 0; j < 3; ++j) {
    acc[2 * p][j]     = MFMA_(r.ah0, bh[j], acc[2 * p][j]);
    acc[2 * p + 1][j] = MFMA_(r.ah1, bh[j], acc[2 * p + 1][j]);
  }
  __builtin_amdgcn_s_setprio(0);
}

// step body shared by main loop and tail (reads bufc only)
#define SPLIT_STEP()                        \
  {                                         \
    LOADB();                                \
    lda_split(r0, bufc, wm, 0, l16, rdq);   \
    lda_split(r1, bufc, wm, 1, l16, rdq);   \
    mfma_split(acc, r0, bh, bl, 0);         \
    lda_split(r0, bufc, wm, 2, l16, rdq);   \
    mfma_split(acc, r1, bh, bl, 1);         \
    lda_split(r1, bufc, wm, 3, l16, rdq);   \
    mfma_split(acc, r0, bh, bl, 2);         \
    mfma_split(acc, r1, bh, bl, 3);         \
  }

__global__ __launch_bounds__(512, 2) void gemm_split2(
    const bf16_t* __restrict__ Ah, const bf16_t* __restrict__ Al,
    const bf16_t* __restrict__ Bh, const bf16_t* __restrict__ Bl,
    float* __restrict__ C, int M, int N, int K) {
  __shared__ __align__(16) char lds[2 * BUFSZ];
  const int t = threadIdx.x;
  const int wave = t >> 6, lane = t & 63;
  const int quad = lane >> 4, l16 = lane & 15;
  const int m0 = blockIdx.y * 256, n0 = blockIdx.x * 192;
  const int wm = (wave >> 2) * 128, wn = (wave & 3) * 48;
  // T2 read swizzle: phys 16B-slot of (row r, col-16B q) = q ^ ((r>>1)&3).
  const int rdq = (quad ^ ((l16 >> 1) & 3)) * 16;

  // Per-lane global source offset inside a 16-row x 32-col chunk (inverse swizzle).
  const size_t laneOff =
      (size_t)(lane >> 2) * K * 2 + 16 * ((lane & 3) ^ ((lane >> 3) & 3));

  // 7 staging chunks per wave per K-step.
  const char* gsrc[7];
  int ldsOff[7];
#pragma unroll
  for (int pos = 0; pos < 3; ++pos) {
    int c = wave + 8 * pos;            // 0..23: Bh chunks 0..11, Bl chunks 0..11
    if (c < 12) {
      gsrc[pos]   = (const char*)Bh + (size_t)(n0 + 16 * c) * K * 2 + laneOff;
      ldsOff[pos] = OFF_BH + c * 1024;
    } else {
      gsrc[pos]   = (const char*)Bl + (size_t)(n0 + 16 * (c - 12)) * K * 2 + laneOff;
      ldsOff[pos] = OFF_BL + (c - 12) * 1024;
    }
  }
#pragma unroll
  for (int p = 0; p < 4; ++p) {
    int sub = wave & 3;
    int R0 = ((sub >> 1) & 1) * 128 + 32 * p + (sub & 1) * 16;
    const char* base = (const char*)(wave < 4 ? Ah : Al);
    gsrc[3 + p]   = base + (size_t)(m0 + R0) * K * 2 + laneOff;
    ldsOff[3 + p] = (wave < 4 ? OFF_AH : OFF_AL) + R0 * 64;
  }

  fragC zero4 = {0.f, 0.f, 0.f, 0.f};
  fragC acc[8][3];
#pragma unroll
  for (int i = 0; i < 8; ++i)
#pragma unroll
    for (int j = 0; j < 3; ++j) acc[i][j] = zero4;

  char* ldsc = (char*)lds;
  // prologue: stage K-step 0 into buffer 0
#pragma unroll
  for (int ps = 0; ps < 7; ++ps) async_copy16(gsrc[ps], ldsc + ldsOff[ps]);
#pragma unroll
  for (int ps = 0; ps < 7; ++ps) gsrc[ps] += 64;

  fragAB bh[3], bl[3];
  ARegs r0, r1;
  int cur = 0;
  const int NS = K / 32;
  for (int it = 0; it < NS - 1; ++it) {
    const char* bufc = ldsc + cur * BUFSZ;
    char* nb = ldsc + (cur ^ 1) * BUFSZ;
    // drain this step's loads (issued a full K-step ago -> no stall) and
    // rendezvous; after the barrier, nb is safe to overwrite.
    VMCNT(0); BARRIER();
#pragma unroll
    for (int ps = 0; ps < 7; ++ps) async_copy16(gsrc[ps], nb + ldsOff[ps]);
#pragma unroll
    for (int ps = 0; ps < 7; ++ps) gsrc[ps] += 64;
    SPLIT_STEP();
    cur ^= 1;
  }
  {  // final K-step
    const char* bufc = ldsc + cur * BUFSZ;
    VMCNT(0); BARRIER();
    SPLIT_STEP();
  }

#pragma unroll
  for (int i = 0; i < 8; ++i)
#pragma unroll
    for (int j = 0; j < 3; ++j)
#pragma unroll
      for (int r = 0; r < 4; ++r) {
        int row = m0 + wm + i * 16 + quad * 4 + r;
        int col = n0 + wn + j * 16 + l16;
        C[(size_t)row * N + col] = acc[i][j][r];
      }
}

// ---------------------------------------------------------------------------
// Plain GEMM v3 (output projection): C[M][N] = A[M][K]*Bt[N][K]^T, fp32 out.
// BM=256, BN=128, BK=64, 512 threads (8 waves as 2M x 4N -> wave tile 128x32).
// Same 1-barrier-per-K-step schedule as gemm_split2.
// ---------------------------------------------------------------------------
#define BT_OFF_A 0
#define BT_OFF_B 32768
#define BT_BUFSZ 49152

struct ARegs2 { fragAB a[2][2]; };  // [row-in-pair][k-slice]

__device__ __forceinline__ void lda_bt(ARegs2& r, const char* bufc, int wm,
                                       int p, int l16, int quad, int rx) {
#pragma unroll
  for (int u = 0; u < 2; ++u)
#pragma unroll
    for (int ks = 0; ks < 2; ++ks)
      r.a[u][ks] = *(const fragAB*)(bufc + BT_OFF_A +
                                    (wm + (2 * p + u) * 16 + l16) * 128 +
                                    (((ks * 4 + quad) ^ rx) * 16));
}

__device__ __forceinline__ void mfma_bt(fragC (&acc)[8][2], const ARegs2& r,
                                        const fragAB (&b)[2][2], int p) {
  __builtin_amdgcn_s_setprio(1);
#pragma unroll
  for (int ks = 0; ks < 2; ++ks)
#pragma unroll
    for (int j = 0; j < 2; ++j) {
      acc[2 * p][j]     = MFMA_(r.a[0][ks], b[j][ks], acc[2 * p][j]);
      acc[2 * p + 1][j] = MFMA_(r.a[1][ks], b[j][ks], acc[2 * p + 1][j]);
    }
  __builtin_amdgcn_s_setprio(0);
}

#define BT_LOADB()                                                        \
  _Pragma("unroll")                                                       \
  for (int j = 0; j < 2; ++j)                                             \
  _Pragma("unroll")                                                       \
    for (int ks = 0; ks < 2; ++ks)                                        \
      bfr[j][ks] = *(const fragAB*)(bufc + BT_OFF_B +                     \
                                    (wn + j * 16 + l16) * 128 +           \
                                    (((ks * 4 + quad) ^ rx) * 16));

#define BT_STEP()                                 \
  {                                               \
    BT_LOADB();                                   \
    lda_bt(r0, bufc, wm, 0, l16, quad, rx);       \
    lda_bt(r1, bufc, wm, 1, l16, quad, rx);       \
    mfma_bt(acc, r0, bfr, 0);                     \
    lda_bt(r0, bufc, wm, 2, l16, quad, rx);       \
    mfma_bt(acc, r1, bfr, 1);                     \
    lda_bt(r1, bufc, wm, 3, l16, quad, rx);       \
    mfma_bt(acc, r0, bfr, 2);                     \
    mfma_bt(acc, r1, bfr, 3);                     \
  }

__global__ __launch_bounds__(512, 2) void gemm_bt2(
    const bf16_t* __restrict__ A, const bf16_t* __restrict__ Bt,
    float* __restrict__ C, int M, int N, int K) {
  __shared__ __align__(16) char lds[2 * BT_BUFSZ];
  const int t = threadIdx.x;
  const int wave = t >> 6, lane = t & 63;
  const int quad = lane >> 4, l16 = lane & 15;
  const int m0 = blockIdx.y * 256, n0 = blockIdx.x * 128;
  const int wm = (wave >> 2) * 128, wn = (wave & 3) * 32;
  const int rx = l16 & 7;  // row-XOR for 8-slot swizzle (128B rows)

  // chunk = 8 rows x 64 cols (128B rows). lane l stages row l>>3,
  // logical col16 (l&7)^((l>>3)&7) -> LDS phys slot l&7 (inverse swizzle).
  const size_t laneOff =
      (size_t)(lane >> 3) * K * 2 + 16 * ((lane & 7) ^ ((lane >> 3) & 7));

  // 6 staging chunks per wave per K-step: B,B,A0..A3.
  const char* gsrc[6];
  int ldsOff[6];
#pragma unroll
  for (int pos = 0; pos < 2; ++pos) {
    int c = wave + 8 * pos;  // B chunks 0..15, rows [8c,8c+8)
    gsrc[pos]   = (const char*)Bt + (size_t)(n0 + 8 * c) * K * 2 + laneOff;
    ldsOff[pos] = BT_OFF_B + c * 1024;
  }
#pragma unroll
  for (int p = 0; p < 4; ++p) {
    int R0 = (wave >> 2) * 128 + 32 * p + (wave & 3) * 8;
    gsrc[2 + p]   = (const char*)A + (size_t)(m0 + R0) * K * 2 + laneOff;
    ldsOff[2 + p] = BT_OFF_A + R0 * 128;
  }

  fragC zero4 = {0.f, 0.f, 0.f, 0.f};
  fragC acc[8][2];
#pragma unroll
  for (int i = 0; i < 8; ++i)
#pragma unroll
    for (int j = 0; j < 2; ++j) acc[i][j] = zero4;

  char* ldsc = (char*)lds;
#pragma unroll
  for (int ps = 0; ps < 6; ++ps) async_copy16(gsrc[ps], ldsc + ldsOff[ps]);
#pragma unroll
  for (int ps = 0; ps < 6; ++ps) gsrc[ps] += 128;

  fragAB bfr[2][2];
  ARegs2 r0, r1;
  int cur = 0;
  const int NS = K / 64;
  for (int it = 0; it < NS - 1; ++it) {
    const char* bufc = ldsc + cur * BT_BUFSZ;
    char* nb = ldsc + (cur ^ 1) * BT_BUFSZ;
    VMCNT(0); BARRIER();
#pragma unroll
    for (int ps = 0; ps < 6; ++ps) async_copy16(gsrc[ps], nb + ldsOff[ps]);
#pragma unroll
    for (int ps = 0; ps < 6; ++ps) gsrc[ps] += 128;
    BT_STEP();
    cur ^= 1;
  }
  {
    const char* bufc = ldsc + cur * BT_BUFSZ;
    VMCNT(0); BARRIER();
    BT_STEP();
  }

#pragma unroll
  for (int i = 0; i < 8; ++i)
#pragma unroll
    for (int j = 0; j < 2; ++j)
#pragma unroll
      for (int r = 0; r < 4; ++r) {
        int row = m0 + wm + i * 16 + quad * 4 + r;
        int col = n0 + wn + j * 16 + l16;
        C[(size_t)row * N + col] = acc[i][j][r];
      }
}

// ---------------------------------------------------------------------------
// RMS-norm (+fp32 weight) + RoPE, fp32 in -> split bf16 hi/lo out.
// proj row stride inStride, head-block starts at inOff. Output stride outStride.
// ---------------------------------------------------------------------------
__global__ __launch_bounds__(256) void rmsnorm_rope_split(
    const float* __restrict__ proj, const float* __restrict__ w,
    const float* __restrict__ cosb, const float* __restrict__ sinb,
    bf16_t* __restrict__ qhi, bf16_t* __restrict__ qlo,
    int inStride, int inOff, int outStride) {
  int s = blockIdx.x, h = blockIdx.y, d = threadIdx.x;
  float x = proj[(size_t)s * inStride + inOff + h * DHEAD + d];
  float ss = x * x;
  ss += __shfl_xor(ss, 1);  ss += __shfl_xor(ss, 2);  ss += __shfl_xor(ss, 4);
  ss += __shfl_xor(ss, 8);  ss += __shfl_xor(ss, 16); ss += __shfl_xor(ss, 32);
  __shared__ float part[4];
  __shared__ float xs[DHEAD];
  if ((threadIdx.x & 63) == 0) part[threadIdx.x >> 6] = ss;
  __syncthreads();
  float tot = part[0] + part[1] + part[2] + part[3];
  float r = rsqrtf(tot * (1.0f / DHEAD) + 1e-6f);
  float xn = x * r * w[d];
  xs[d] = xn;
  __syncthreads();
  float other = xs[(d + 128) & 255];
  float rot = (d < 128) ? -other : other;
  float y = xn * cosb[(size_t)s * DHEAD + d] + rot * sinb[(size_t)s * DHEAD + d];
  bf16_t h2, l2; split2(y, h2, l2);
  size_t oidx = (size_t)s * outStride + h * DHEAD + d;
  qhi[oidx] = h2;
  qlo[oidx] = l2;
}

// ---------------------------------------------------------------------------
// RMS-norm (no weight), fp32 in (stride/offset), bf16 out transposed [NKV][D][S]
// ---------------------------------------------------------------------------
__global__ __launch_bounds__(256) void rmsnorm_vT(
    const float* __restrict__ proj, bf16_t* __restrict__ vt,
    int inStride, int inOff) {
  int s = blockIdx.x, h = blockIdx.y, d = threadIdx.x;
  float x = proj[(size_t)s * inStride + inOff + h * DHEAD + d];
  float ss = x * x;
  ss += __shfl_xor(ss, 1);  ss += __shfl_xor(ss, 2);  ss += __shfl_xor(ss, 4);
  ss += __shfl_xor(ss, 8);  ss += __shfl_xor(ss, 16); ss += __shfl_xor(ss, 32);
  __shared__ float part[4];
  if ((threadIdx.x & 63) == 0) part[threadIdx.x >> 6] = ss;
  __syncthreads();
  float tot = part[0] + part[1] + part[2] + part[3];
  float r = rsqrtf(tot * (1.0f / DHEAD) + 1e-6f);
  vt[((size_t)h * DHEAD + d) * S_LEN + s] = __float2bfloat16(x * r);
}

// ---------------------------------------------------------------------------
// Flash attention v2, sliding window 512, NO score scale, GQA G=4.
// Q-block=128 (8 waves x 16 rows), KV-step=64. One block per CU (grid 32x8).
// K hi/lo staged [64][256] with 5-bit XOR swizzle; V staged [256][64] with
// 3-bit XOR swizzle; P in per-wave LDS [16][64]. Per-CU barrier steps ~10
// (was ~35 at the 64-row/32-key tiling) -> per-step softmax/drain overhead
// amortized 3.5x, K/V staging traffic halved.
// ---------------------------------------------------------------------------
__global__ __launch_bounds__(512, 2) void attn_split(
    const bf16_t* __restrict__ Qhi, const bf16_t* __restrict__ Qlo,
    const bf16_t* __restrict__ Khi, const bf16_t* __restrict__ Klo,
    const bf16_t* __restrict__ Vt, bf16_t* __restrict__ Aout) {
  const int h = blockIdx.y;
  const int qb = blockIdx.x * 128;
  const int wave = threadIdx.x >> 6, lane = threadIdx.x & 63;
  const int quad = lane >> 4, l16 = lane & 15;
  const int qw = qb + wave * 16;
  const int kv = h >> 2;  // G = 4
  const bf16_t* Qh_ = Qhi + h * DHEAD;   // row stride NHQ*DHEAD
  const bf16_t* Ql_ = Qlo + h * DHEAD;
  const bf16_t* Kh_ = Khi + kv * DHEAD;  // row stride NKVH*DHEAD
  const bf16_t* Kl_ = Klo + kv * DHEAD;
  const bf16_t* Vh_ = Vt + (size_t)kv * DHEAD * S_LEN;

  __shared__ __align__(16) bf16_t KshH[64 * 256];   // 32 KB, rows = keys (512B)
  __shared__ __align__(16) bf16_t KshL[64 * 256];   // 32 KB
  __shared__ __align__(16) bf16_t Vsh[256 * 64];    // 32 KB, rows = dims (128B)
  __shared__ __align__(16) bf16_t Plds[8][16 * 64]; // 16 KB

  fragAB qfh[8], qfl[8];
#pragma unroll
  for (int c = 0; c < 8; ++c) {
    size_t off = (size_t)(qw + l16) * (NHQ * DHEAD) + c * 32 + quad * 8;
    qfh[c] = *(const fragAB*)(Qh_ + off);
    qfl[c] = *(const fragAB*)(Ql_ + off);
  }

  // staging geometry: 512 threads x 4 chunks x 16B = 32 KB per buffer.
  // K: chunk ci -> row ci>>5 (32 slots/row), phys slot ci&31 holds logical
  //    d-slot (ci&31)^(row&31). V: row ci>>3 (8 slots/row), phys slot ci&7
  //    holds logical key-slot (ci&7)^(row&7).
  int kRow[4], kCol[4], vRow[4], vCol[4];
#pragma unroll
  for (int i = 0; i < 4; ++i) {
    int ci = i * 512 + threadIdx.x;
    kRow[i] = ci >> 5;
    kCol[i] = ((ci & 31) ^ (kRow[i] & 31)) * 8;
    vRow[i] = ci >> 3;
    vCol[i] = ((ci & 7) ^ (vRow[i] & 7)) * 8;
  }

  fragC zero4 = {0.f, 0.f, 0.f, 0.f};
  fragC o_acc[16];
#pragma unroll
  for (int c = 0; c < 16; ++c) o_acc[c] = zero4;
  float m_run[4] = {NEG_BIG, NEG_BIG, NEG_BIG, NEG_BIG};
  float l_run[4] = {0.f, 0.f, 0.f, 0.f};
  const float LOG2E = 1.4426950408889634f;

  int k_lo = qb - (WIN - 1);
  if (k_lo < 0) k_lo = 0;
  k_lo &= ~63;

  for (int kb = k_lo; kb < qb + 128; kb += 64) {
#pragma unroll
    for (int i = 0; i < 4; ++i) {
      size_t dst = (size_t)(i * 512 + threadIdx.x) * 16;
      size_t koff = (size_t)(kb + kRow[i]) * (NKVH * DHEAD) + kCol[i];
      async_copy16(Kh_ + koff, (char*)KshH + dst);
      async_copy16(Kl_ + koff, (char*)KshL + dst);
      async_copy16(Vh_ + (size_t)vRow[i] * S_LEN + kb + vCol[i], (char*)Vsh + dst);
    }
    __syncthreads();

    fragC s[4] = {zero4, zero4, zero4, zero4};
#pragma unroll
    for (int c = 0; c < 8; ++c) {
      int j = c * 4 + quad;
#pragma unroll
      for (int g = 0; g < 4; ++g) {
        int row = g * 16 + l16;
        int off = (row * 32 + (j ^ (row & 31))) * 16;
        fragAB kh = *(const fragAB*)((const char*)KshH + off);
        fragAB kl = *(const fragAB*)((const char*)KshL + off);
        s[g] = __builtin_amdgcn_mfma_f32_16x16x32_bf16(qfl[c], kh, s[g], 0, 0, 0);
        s[g] = __builtin_amdgcn_mfma_f32_16x16x32_bf16(qfh[c], kl, s[g], 0, 0, 0);
        s[g] = __builtin_amdgcn_mfma_f32_16x16x32_bf16(qfh[c], kh, s[g], 0, 0, 0);
      }
    }

    float p[4][4], alpha[4];
#pragma unroll
    for (int r = 0; r < 4; ++r) {
      int qi = qw + quad * 4 + r;
      bool vld[4];
      float sv[4];
      float mx = NEG_BIG;
#pragma unroll
      for (int g = 0; g < 4; ++g) {
        int ki = kb + g * 16 + l16;
        vld[g] = (ki <= qi) && (qi - ki < WIN);
        sv[g] = vld[g] ? s[g][r] : NEG_BIG;
        mx = fmaxf(mx, sv[g]);
      }
      mx = fmaxf(mx, __shfl_xor(mx, 1));
      mx = fmaxf(mx, __shfl_xor(mx, 2));
      mx = fmaxf(mx, __shfl_xor(mx, 4));
      mx = fmaxf(mx, __shfl_xor(mx, 8));
      float mn = fmaxf(m_run[r], mx);
      float a  = exp2f(fmaxf(m_run[r] - mn, -80.f) * LOG2E);
      float rs = 0.f;
#pragma unroll
      for (int g = 0; g < 4; ++g) {
        float e = vld[g] ? exp2f(fmaxf(s[g][r] - mn, -80.f) * LOG2E) : 0.f;
        p[g][r] = e;
        rs += e;
      }
      rs += __shfl_xor(rs, 1);
      rs += __shfl_xor(rs, 2);
      rs += __shfl_xor(rs, 4);
      rs += __shfl_xor(rs, 8);
      l_run[r] = l_run[r] * a + rs;
      m_run[r] = mn;
      alpha[r] = a;
    }
#pragma unroll
    for (int c = 0; c < 16; ++c)
#pragma unroll
      for (int r = 0; r < 4; ++r) o_acc[c][r] *= alpha[r];

    bf16_t* Pw = Plds[wave];
#pragma unroll
    for (int r = 0; r < 4; ++r)
#pragma unroll
      for (int g = 0; g < 4; ++g)
        Pw[(quad * 4 + r) * 64 + g * 16 + l16] = __float2bfloat16(p[g][r]);
    fragAB pf0 = *(const fragAB*)((const char*)Pw + l16 * 128 + quad * 16);
    fragAB pf1 = *(const fragAB*)((const char*)Pw + l16 * 128 + 64 + quad * 16);

#pragma unroll
    for (int c = 0; c < 16; ++c) {
      int d = c * 16 + l16;
#pragma unroll
      for (int ks = 0; ks < 2; ++ks) {
        int offv = (d * 8 + ((ks * 4 + quad) ^ (d & 7))) * 16;
        fragAB vf = *(const fragAB*)((const char*)Vsh + offv);
        o_acc[c] = __builtin_amdgcn_mfma_f32_16x16x32_bf16(
            ks == 0 ? pf0 : pf1, vf, o_acc[c], 0, 0, 0);
      }
    }
    __syncthreads();
  }

  float inv_l[4];
#pragma unroll
  for (int r = 0; r < 4; ++r) inv_l[r] = 1.0f / l_run[r];
#pragma unroll
  for (int c = 0; c < 16; ++c)
#pragma unroll
    for (int r = 0; r < 4; ++r) {
      int row = qw + quad * 4 + r;
      int col = h * DHEAD + c * 16 + l16;
      Aout[(size_t)row * (NHQ * DHEAD) + col] = __float2bfloat16(o_acc[c][r] * inv_l[r]);
    }
}

// ---------------------------------------------------------------------------
extern "C" void kernel_launch(void* const* d_in, const int* in_sizes, int n_in,
                              void* d_out, int out_size, void* d_ws, size_t ws_size,
                              hipStream_t stream) {
  const float* hid  = (const float*)d_in[0];
  const float* w_q  = (const float*)d_in[1];
  const float* w_k  = (const float*)d_in[2];
  const float* w_v  = (const float*)d_in[3];
  const float* w_o  = (const float*)d_in[4];
  const float* qnw  = (const float*)d_in[5];
  const float* knw  = (const float*)d_in[6];
  const float* cosb = (const float*)d_in[7];
  const float* sinb = (const float*)d_in[8];
  float* outp = (float*)d_out;

  // Workspace (bf16 slots, M1 = 1<<20), peak 52M slots = 104 MiB:
  //  [ 0: 8M)  hidh  -> qh  (after qkv gemm)
  //  [ 8:16M)  hidl  -> ql
  //  [16:22M)  wTh (3072x2048) -> kh[16:18M), kl[18:20M), vt[20:22M) after gemm
  //  [22:28M)  wTl   -> woT[22:26M) after gemm
  //  [28:52M)  projqkv f32 (4096x3072) -> aout[28:36M) after norms
  const size_t M1 = 1048576;
  bf16_t* w = (bf16_t*)d_ws;
  bf16_t* hidh  = w;
  bf16_t* qh    = w;                         // alias hidh
  bf16_t* hidl  = w + 8 * M1;
  bf16_t* ql    = w + 8 * M1;                // alias hidl
  bf16_t* wTh   = w + 16 * M1;
  bf16_t* kh    = w + 16 * M1;               // alias wTh
  bf16_t* kl    = w + 18 * M1;
  bf16_t* vt    = w + 20 * M1;
  bf16_t* wTl   = w + 22 * M1;
  bf16_t* woT   = w + 22 * M1;               // alias wTl
  float*  projqkv = (float*)(w + 28 * M1);
  bf16_t* aout  = w + 28 * M1;               // alias projqkv (after norms)

  // phase 0: split hidden; split-transpose [wq|wk|wv] into fused wT [3072][2048]
  split_f32<<<(S_LEN * HDIM) / 1024, 256, 0, stream>>>(hid, hidh, hidl, S_LEN * HDIM);
  transpose_split<<<dim3((NHQ * DHEAD) / 32, HDIM / 32), 256, 0, stream>>>(
      w_q, wTh, wTl, HDIM, NHQ * DHEAD);
  transpose_split<<<dim3((NKVH * DHEAD) / 32, HDIM / 32), 256, 0, stream>>>(
      w_k, wTh + (size_t)(NHQ * DHEAD) * HDIM, wTl + (size_t)(NHQ * DHEAD) * HDIM,
      HDIM, NKVH * DHEAD);
  transpose_split<<<dim3((NKVH * DHEAD) / 32, HDIM / 32), 256, 0, stream>>>(
      w_v, wTh + (size_t)(NHQ * DHEAD + NKVH * DHEAD) * HDIM,
      wTl + (size_t)(NHQ * DHEAD + NKVH * DHEAD) * HDIM, HDIM, NKVH * DHEAD);

  // phase 1: fused q+k+v split projection, pipelined 256x192 tiles
  //          grid 16x16 = 256 blocks = exactly 1 per CU
  gemm_split2<<<dim3(NQKV / 192, S_LEN / 256), 512, 0, stream>>>(
      hidh, hidl, wTh, wTl, projqkv, S_LEN, NQKV, HDIM);

  // phase 2: norms (hid/wT dead -> qh/ql/kh/kl/vt targets)
  rmsnorm_rope_split<<<dim3(S_LEN, NHQ), 256, 0, stream>>>(
      projqkv, qnw, cosb, sinb, qh, ql, NQKV, 0, NHQ * DHEAD);
  rmsnorm_rope_split<<<dim3(S_LEN, NKVH), 256, 0, stream>>>(
      projqkv, knw, cosb, sinb, kh, kl, NQKV, NHQ * DHEAD, NKVH * DHEAD);
  rmsnorm_vT<<<dim3(S_LEN, NKVH), 256, 0, stream>>>(
      projqkv, vt, NQKV, NHQ * DHEAD + NKVH * DHEAD);

  // phase 3: w_o transpose into dead wTl region
  transpose_cvt<<<dim3(HDIM / 32, (NHQ * DHEAD) / 32), 256, 0, stream>>>(w_o, woT, NHQ * DHEAD, HDIM);

  // phase 4: attention -> aout (dead projqkv region)
  //          grid 32x8 = 256 blocks = exactly 1 per CU
  attn_split<<<dim3(S_LEN / 128, NHQ), 512, 0, stream>>>(qh, ql, kh, kl, vt, aout);

  // phase 5: output projection -> fp32 d_out, pipelined 256x128 tiles
  //          grid 16x16 = 256 blocks = exactly 1 per CU
  gemm_bt2<<<dim3(HDIM / 128, S_LEN / 256), 512, 0, stream>>>(
      aout, woT, outp, S_LEN, HDIM, NHQ * DHEAD);
}

// Round 5
// 408.740 us; speedup vs baseline: 1.2870x; 1.0261x over previous
//
#include <hip/hip_runtime.h>
#include <hip/hip_bf16.h>

#define S_LEN 4096
#define HDIM  2048
#define NHQ   8
#define NKVH  2
#define DHEAD 256
#define WIN   512
#define NQKV  3072   // fused q+k+v projection width (2048 + 512 + 512)

typedef __hip_bfloat16 bf16_t;
using fragAB = __attribute__((ext_vector_type(8))) short;  // 8 bf16
using fragC  = __attribute__((ext_vector_type(4))) float;  // 4 fp32

typedef unsigned int u32;
typedef const __attribute__((address_space(1))) u32* gas_ptr;
typedef __attribute__((address_space(3))) u32* las_ptr;

__device__ __forceinline__ void async_copy16(const void* g, void* l) {
  __builtin_amdgcn_global_load_lds((gas_ptr)g, (las_ptr)l, 16, 0, 0);
}

#define NEG_BIG (-3.0e38f)

__device__ __forceinline__ void split2(float x, bf16_t& hi, bf16_t& lo) {
  bf16_t h = __float2bfloat16(x);
  hi = h;
  lo = __float2bfloat16(x - (float)h);
}

// ---------------------------------------------------------------------------
// Elementwise split fp32 -> bf16 hi + bf16 lo  (n multiple of 1024)
// ---------------------------------------------------------------------------
__global__ __launch_bounds__(256) void split_f32(
    const float* __restrict__ in, bf16_t* __restrict__ hi,
    bf16_t* __restrict__ lo, int n) {
  int i = (blockIdx.x * 256 + threadIdx.x) * 4;
  if (i >= n) return;
  float4 v = *(const float4*)(in + i);
  split2(v.x, hi[i + 0], lo[i + 0]);
  split2(v.y, hi[i + 1], lo[i + 1]);
  split2(v.z, hi[i + 2], lo[i + 2]);
  split2(v.w, hi[i + 3], lo[i + 3]);
}

// ---------------------------------------------------------------------------
// Transpose+convert fp32 [R][C] -> bf16 [C][R]
// ---------------------------------------------------------------------------
__global__ __launch_bounds__(256) void transpose_cvt(
    const float* __restrict__ in, bf16_t* __restrict__ out, int R, int C) {
  __shared__ bf16_t tile[32][33];
  int c0 = blockIdx.x * 32, r0 = blockIdx.y * 32;
  int tx = threadIdx.x & 31, ty = threadIdx.x >> 5;
#pragma unroll
  for (int i = 0; i < 4; ++i)
    tile[ty + i * 8][tx] = __float2bfloat16(in[(size_t)(r0 + ty + i * 8) * C + c0 + tx]);
  __syncthreads();
#pragma unroll
  for (int i = 0; i < 4; ++i)
    out[(size_t)(c0 + ty + i * 8) * R + r0 + tx] = tile[tx][ty + i * 8];
}

// ---------------------------------------------------------------------------
// Fused transpose+split of [wq|wk|wv] -> wT hi/lo [3072][2048]
// output rows [0,2048) <- wq cols, [2048,2560) <- wk, [2560,3072) <- wv
// ---------------------------------------------------------------------------
__global__ __launch_bounds__(256) void transpose_split_fused(
    const float* __restrict__ wq, const float* __restrict__ wk,
    const float* __restrict__ wv, bf16_t* __restrict__ hiT,
    bf16_t* __restrict__ loT) {
  __shared__ bf16_t th[32][33];
  __shared__ bf16_t tl[32][33];
  int oc = blockIdx.x * 32;   // output row group (input col)
  int r0 = blockIdx.y * 32;   // input row
  const float* src; int C, c0;
  if (oc < 2048)      { src = wq; C = 2048; c0 = oc; }
  else if (oc < 2560) { src = wk; C = 512;  c0 = oc - 2048; }
  else                { src = wv; C = 512;  c0 = oc - 2560; }
  int tx = threadIdx.x & 31, ty = threadIdx.x >> 5;
#pragma unroll
  for (int i = 0; i < 4; ++i) {
    float x = src[(size_t)(r0 + ty + i * 8) * C + c0 + tx];
    bf16_t h, l; split2(x, h, l);
    th[ty + i * 8][tx] = h;
    tl[ty + i * 8][tx] = l;
  }
  __syncthreads();
#pragma unroll
  for (int i = 0; i < 4; ++i) {
    hiT[(size_t)(oc + ty + i * 8) * HDIM + r0 + tx] = th[tx][ty + i * 8];
    loT[(size_t)(oc + ty + i * 8) * HDIM + r0 + tx] = tl[tx][ty + i * 8];
  }
}

// ---------------------------------------------------------------------------
// Shared helpers for pipelined GEMMs
// ---------------------------------------------------------------------------
#define VMCNT_(n) asm volatile("s_waitcnt vmcnt(" #n ")" ::: "memory")
#define VMCNT(n) VMCNT_(n)
#define BARRIER()                     \
  {                                   \
    asm volatile("" ::: "memory");    \
    __builtin_amdgcn_s_barrier();     \
    asm volatile("" ::: "memory");    \
  }

#define MFMA_(a, b, c) __builtin_amdgcn_mfma_f32_16x16x32_bf16(a, b, c, 0, 0, 0)

// ---------------------------------------------------------------------------
// Split-precision GEMM v4: C = Ah*Bh + Ah*Bl + Al*Bh, pipelined.
// BM=256, BN=192, BK=32, 512 threads (8 waves, 2M x 4N).
// Double-buffered LDS (112 KB). ONE barrier + one vmcnt(0) per K-step.
// ---------------------------------------------------------------------------
#define OFF_AH 0
#define OFF_AL 16384
#define OFF_BH 32768
#define OFF_BL 45056
#define BUFSZ  57344

#define LOADB()                                                   \
  _Pragma("unroll")                                               \
  for (int j = 0; j < 3; ++j) {                                   \
    const char* bp_ = bufc + (wn + j * 16 + l16) * 64 + rdq;      \
    bh[j] = *(const fragAB*)(bp_ + OFF_BH);                       \
    bl[j] = *(const fragAB*)(bp_ + OFF_BL);                       \
  }

struct ARegs { fragAB ah0, al0, ah1, al1; };

__device__ __forceinline__ void lda_split(ARegs& r, const char* bufc, int wm,
                                          int p, int l16, int rdq) {
  const char* a0 = bufc + (wm + (2 * p) * 16 + l16) * 64 + rdq;
  const char* a1 = a0 + 16 * 64;
  r.ah0 = *(const fragAB*)(a0 + OFF_AH);
  r.al0 = *(const fragAB*)(a0 + OFF_AL);
  r.ah1 = *(const fragAB*)(a1 + OFF_AH);
  r.al1 = *(const fragAB*)(a1 + OFF_AL);
}

__device__ __forceinline__ void mfma_split(fragC (&acc)[8][3], const ARegs& r,
                                           const fragAB (&bh)[3],
                                           const fragAB (&bl)[3], int p) {
  __builtin_amdgcn_s_setprio(1);
#pragma unroll
  for (int j = 0; j < 3; ++j) {
    acc[2 * p][j]     = MFMA_(r.al0, bh[j], acc[2 * p][j]);
    acc[2 * p + 1][j] = MFMA_(r.al1, bh[j], acc[2 * p + 1][j]);
  }
#pragma unroll
  for (int j = 0; j < 3; ++j) {
    acc[2 * p][j]     = MFMA_(r.ah0, bl[j], acc[2 * p][j]);
    acc[2 * p + 1][j] = MFMA_(r.ah1, bl[j], acc[2 * p + 1][j]);
  }
#pragma unroll
  for (int j = 0; j < 3; ++j) {
    acc[2 * p][j]     = MFMA_(r.ah0, bh[j], acc[2 * p][j]);
    acc[2 * p + 1][j] = MFMA_(r.ah1, bh[j], acc[2 * p + 1][j]);
  }
  __builtin_amdgcn_s_setprio(0);
}

// step body shared by main loop and tail (reads bufc only)
#define SPLIT_STEP()                        \
  {                                         \
    LOADB();                                \
    lda_split(r0, bufc, wm, 0, l16, rdq);   \
    lda_split(r1, bufc, wm, 1, l16, rdq);   \
    mfma_split(acc, r0, bh, bl, 0);         \
    lda_split(r0, bufc, wm, 2, l16, rdq);   \
    mfma_split(acc, r1, bh, bl, 1);         \
    lda_split(r1, bufc, wm, 3, l16, rdq);   \
    mfma_split(acc, r0, bh, bl, 2);         \
    mfma_split(acc, r1, bh, bl, 3);         \
  }

__global__ __launch_bounds__(512, 2) void gemm_split2(
    const bf16_t* __restrict__ Ah, const bf16_t* __restrict__ Al,
    const bf16_t* __restrict__ Bh, const bf16_t* __restrict__ Bl,
    float* __restrict__ C, int M, int N, int K) {
  __shared__ __align__(16) char lds[2 * BUFSZ];
  const int t = threadIdx.x;
  const int wave = t >> 6, lane = t & 63;
  const int quad = lane >> 4, l16 = lane & 15;
  const int m0 = blockIdx.y * 256, n0 = blockIdx.x * 192;
  const int wm = (wave >> 2) * 128, wn = (wave & 3) * 48;
  // T2 read swizzle: phys 16B-slot of (row r, col-16B q) = q ^ ((r>>1)&3).
  const int rdq = (quad ^ ((l16 >> 1) & 3)) * 16;

  // Per-lane global source offset inside a 16-row x 32-col chunk (inverse swizzle).
  const size_t laneOff =
      (size_t)(lane >> 2) * K * 2 + 16 * ((lane & 3) ^ ((lane >> 3) & 3));

  // 7 staging chunks per wave per K-step.
  const char* gsrc[7];
  int ldsOff[7];
#pragma unroll
  for (int pos = 0; pos < 3; ++pos) {
    int c = wave + 8 * pos;            // 0..23: Bh chunks 0..11, Bl chunks 0..11
    if (c < 12) {
      gsrc[pos]   = (const char*)Bh + (size_t)(n0 + 16 * c) * K * 2 + laneOff;
      ldsOff[pos] = OFF_BH + c * 1024;
    } else {
      gsrc[pos]   = (const char*)Bl + (size_t)(n0 + 16 * (c - 12)) * K * 2 + laneOff;
      ldsOff[pos] = OFF_BL + (c - 12) * 1024;
    }
  }
#pragma unroll
  for (int p = 0; p < 4; ++p) {
    int sub = wave & 3;
    int R0 = ((sub >> 1) & 1) * 128 + 32 * p + (sub & 1) * 16;
    const char* base = (const char*)(wave < 4 ? Ah : Al);
    gsrc[3 + p]   = base + (size_t)(m0 + R0) * K * 2 + laneOff;
    ldsOff[3 + p] = (wave < 4 ? OFF_AH : OFF_AL) + R0 * 64;
  }

  fragC zero4 = {0.f, 0.f, 0.f, 0.f};
  fragC acc[8][3];
#pragma unroll
  for (int i = 0; i < 8; ++i)
#pragma unroll
    for (int j = 0; j < 3; ++j) acc[i][j] = zero4;

  char* ldsc = (char*)lds;
  // prologue: stage K-step 0 into buffer 0
#pragma unroll
  for (int ps = 0; ps < 7; ++ps) async_copy16(gsrc[ps], ldsc + ldsOff[ps]);
#pragma unroll
  for (int ps = 0; ps < 7; ++ps) gsrc[ps] += 64;

  fragAB bh[3], bl[3];
  ARegs r0, r1;
  int cur = 0;
  const int NS = K / 32;
  for (int it = 0; it < NS - 1; ++it) {
    const char* bufc = ldsc + cur * BUFSZ;
    char* nb = ldsc + (cur ^ 1) * BUFSZ;
    // drain this step's loads (issued a full K-step ago -> no stall) and
    // rendezvous; after the barrier, nb is safe to overwrite.
    VMCNT(0); BARRIER();
#pragma unroll
    for (int ps = 0; ps < 7; ++ps) async_copy16(gsrc[ps], nb + ldsOff[ps]);
#pragma unroll
    for (int ps = 0; ps < 7; ++ps) gsrc[ps] += 64;
    SPLIT_STEP();
    cur ^= 1;
  }
  {  // final K-step
    const char* bufc = ldsc + cur * BUFSZ;
    VMCNT(0); BARRIER();
    SPLIT_STEP();
  }

#pragma unroll
  for (int i = 0; i < 8; ++i)
#pragma unroll
    for (int j = 0; j < 3; ++j)
#pragma unroll
      for (int r = 0; r < 4; ++r) {
        int row = m0 + wm + i * 16 + quad * 4 + r;
        int col = n0 + wn + j * 16 + l16;
        C[(size_t)row * N + col] = acc[i][j][r];
      }
}

// ---------------------------------------------------------------------------
// Plain GEMM v3 (output projection): C[M][N] = A[M][K]*Bt[N][K]^T, fp32 out.
// BM=256, BN=128, BK=64, 512 threads (8 waves as 2M x 4N -> wave tile 128x32).
// Same 1-barrier-per-K-step schedule as gemm_split2.
// ---------------------------------------------------------------------------
#define BT_OFF_A 0
#define BT_OFF_B 32768
#define BT_BUFSZ 49152

struct ARegs2 { fragAB a[2][2]; };  // [row-in-pair][k-slice]

__device__ __forceinline__ void lda_bt(ARegs2& r, const char* bufc, int wm,
                                       int p, int l16, int quad, int rx) {
#pragma unroll
  for (int u = 0; u < 2; ++u)
#pragma unroll
    for (int ks = 0; ks < 2; ++ks)
      r.a[u][ks] = *(const fragAB*)(bufc + BT_OFF_A +
                                    (wm + (2 * p + u) * 16 + l16) * 128 +
                                    (((ks * 4 + quad) ^ rx) * 16));
}

__device__ __forceinline__ void mfma_bt(fragC (&acc)[8][2], const ARegs2& r,
                                        const fragAB (&b)[2][2], int p) {
  __builtin_amdgcn_s_setprio(1);
#pragma unroll
  for (int ks = 0; ks < 2; ++ks)
#pragma unroll
    for (int j = 0; j < 2; ++j) {
      acc[2 * p][j]     = MFMA_(r.a[0][ks], b[j][ks], acc[2 * p][j]);
      acc[2 * p + 1][j] = MFMA_(r.a[1][ks], b[j][ks], acc[2 * p + 1][j]);
    }
  __builtin_amdgcn_s_setprio(0);
}

#define BT_LOADB()                                                        \
  _Pragma("unroll")                                                       \
  for (int j = 0; j < 2; ++j)                                             \
  _Pragma("unroll")                                                       \
    for (int ks = 0; ks < 2; ++ks)                                        \
      bfr[j][ks] = *(const fragAB*)(bufc + BT_OFF_B +                     \
                                    (wn + j * 16 + l16) * 128 +           \
                                    (((ks * 4 + quad) ^ rx) * 16));

#define BT_STEP()                                 \
  {                                               \
    BT_LOADB();                                   \
    lda_bt(r0, bufc, wm, 0, l16, quad, rx);       \
    lda_bt(r1, bufc, wm, 1, l16, quad, rx);       \
    mfma_bt(acc, r0, bfr, 0);                     \
    lda_bt(r0, bufc, wm, 2, l16, quad, rx);       \
    mfma_bt(acc, r1, bfr, 1);                     \
    lda_bt(r1, bufc, wm, 3, l16, quad, rx);       \
    mfma_bt(acc, r0, bfr, 2);                     \
    mfma_bt(acc, r1, bfr, 3);                     \
  }

__global__ __launch_bounds__(512, 2) void gemm_bt2(
    const bf16_t* __restrict__ A, const bf16_t* __restrict__ Bt,
    float* __restrict__ C, int M, int N, int K) {
  __shared__ __align__(16) char lds[2 * BT_BUFSZ];
  const int t = threadIdx.x;
  const int wave = t >> 6, lane = t & 63;
  const int quad = lane >> 4, l16 = lane & 15;
  const int m0 = blockIdx.y * 256, n0 = blockIdx.x * 128;
  const int wm = (wave >> 2) * 128, wn = (wave & 3) * 32;
  const int rx = l16 & 7;  // row-XOR for 8-slot swizzle (128B rows)

  // chunk = 8 rows x 64 cols (128B rows). lane l stages row l>>3,
  // logical col16 (l&7)^((l>>3)&7) -> LDS phys slot l&7 (inverse swizzle).
  const size_t laneOff =
      (size_t)(lane >> 3) * K * 2 + 16 * ((lane & 7) ^ ((lane >> 3) & 7));

  // 6 staging chunks per wave per K-step: B,B,A0..A3.
  const char* gsrc[6];
  int ldsOff[6];
#pragma unroll
  for (int pos = 0; pos < 2; ++pos) {
    int c = wave + 8 * pos;  // B chunks 0..15, rows [8c,8c+8)
    gsrc[pos]   = (const char*)Bt + (size_t)(n0 + 8 * c) * K * 2 + laneOff;
    ldsOff[pos] = BT_OFF_B + c * 1024;
  }
#pragma unroll
  for (int p = 0; p < 4; ++p) {
    int R0 = (wave >> 2) * 128 + 32 * p + (wave & 3) * 8;
    gsrc[2 + p]   = (const char*)A + (size_t)(m0 + R0) * K * 2 + laneOff;
    ldsOff[2 + p] = BT_OFF_A + R0 * 128;
  }

  fragC zero4 = {0.f, 0.f, 0.f, 0.f};
  fragC acc[8][2];
#pragma unroll
  for (int i = 0; i < 8; ++i)
#pragma unroll
    for (int j = 0; j < 2; ++j) acc[i][j] = zero4;

  char* ldsc = (char*)lds;
#pragma unroll
  for (int ps = 0; ps < 6; ++ps) async_copy16(gsrc[ps], ldsc + ldsOff[ps]);
#pragma unroll
  for (int ps = 0; ps < 6; ++ps) gsrc[ps] += 128;

  fragAB bfr[2][2];
  ARegs2 r0, r1;
  int cur = 0;
  const int NS = K / 64;
  for (int it = 0; it < NS - 1; ++it) {
    const char* bufc = ldsc + cur * BT_BUFSZ;
    char* nb = ldsc + (cur ^ 1) * BT_BUFSZ;
    VMCNT(0); BARRIER();
#pragma unroll
    for (int ps = 0; ps < 6; ++ps) async_copy16(gsrc[ps], nb + ldsOff[ps]);
#pragma unroll
    for (int ps = 0; ps < 6; ++ps) gsrc[ps] += 128;
    BT_STEP();
    cur ^= 1;
  }
  {
    const char* bufc = ldsc + cur * BT_BUFSZ;
    VMCNT(0); BARRIER();
    BT_STEP();
  }

#pragma unroll
  for (int i = 0; i < 8; ++i)
#pragma unroll
    for (int j = 0; j < 2; ++j)
#pragma unroll
      for (int r = 0; r < 4; ++r) {
        int row = m0 + wm + i * 16 + quad * 4 + r;
        int col = n0 + wn + j * 16 + l16;
        C[(size_t)row * N + col] = acc[i][j][r];
      }
}

// ---------------------------------------------------------------------------
// Fused RMS-norm (+fp32 weight) + RoPE for q and k heads, fp32 in -> split
// bf16 hi/lo out. blockIdx.y: 0..7 = q heads, 8..9 = k heads.
// ---------------------------------------------------------------------------
__global__ __launch_bounds__(256) void rmsnorm_rope_split_qk(
    const float* __restrict__ proj, const float* __restrict__ qnw,
    const float* __restrict__ knw, const float* __restrict__ cosb,
    const float* __restrict__ sinb, bf16_t* __restrict__ qhi,
    bf16_t* __restrict__ qlo, bf16_t* __restrict__ khi,
    bf16_t* __restrict__ klo) {
  int s = blockIdx.x, hb = blockIdx.y, d = threadIdx.x;
  const float* w; bf16_t* oh; bf16_t* ol; int inOff, outStride, oBase;
  if (hb < NHQ) {
    w = qnw; oh = qhi; ol = qlo;
    inOff = hb * DHEAD; outStride = NHQ * DHEAD; oBase = hb * DHEAD;
  } else {
    int hk = hb - NHQ;
    w = knw; oh = khi; ol = klo;
    inOff = NHQ * DHEAD + hk * DHEAD; outStride = NKVH * DHEAD; oBase = hk * DHEAD;
  }
  float x = proj[(size_t)s * NQKV + inOff + d];
  float ss = x * x;
  ss += __shfl_xor(ss, 1);  ss += __shfl_xor(ss, 2);  ss += __shfl_xor(ss, 4);
  ss += __shfl_xor(ss, 8);  ss += __shfl_xor(ss, 16); ss += __shfl_xor(ss, 32);
  __shared__ float part[4];
  __shared__ float xs[DHEAD];
  if ((threadIdx.x & 63) == 0) part[threadIdx.x >> 6] = ss;
  __syncthreads();
  float tot = part[0] + part[1] + part[2] + part[3];
  float r = rsqrtf(tot * (1.0f / DHEAD) + 1e-6f);
  float xn = x * r * w[d];
  xs[d] = xn;
  __syncthreads();
  float other = xs[(d + 128) & 255];
  float rot = (d < 128) ? -other : other;
  float y = xn * cosb[(size_t)s * DHEAD + d] + rot * sinb[(size_t)s * DHEAD + d];
  bf16_t h2, l2; split2(y, h2, l2);
  size_t oidx = (size_t)s * outStride + oBase + d;
  oh[oidx] = h2;
  ol[oidx] = l2;
}

// ---------------------------------------------------------------------------
// RMS-norm (no weight) + transposed write [NKV][D][S], fully coalesced.
// Block: 32 s-rows x one kv head. Phase A: per-row norm factor (8 lanes/row).
// Phase B: 8x 32x32 LDS transpose tiles (32x33 pad), coalesced 64B writes.
// ---------------------------------------------------------------------------
__global__ __launch_bounds__(256) void rmsnorm_vT2(
    const float* __restrict__ proj, bf16_t* __restrict__ vt, int inOff) {
  __shared__ float rs_[32];
  __shared__ bf16_t tile[32][33];
  int s0 = blockIdx.x * 32, hh = blockIdx.y;
  const float* base = proj + (size_t)s0 * NQKV + inOff + hh * DHEAD;
  int t = threadIdx.x;
  int sl = t >> 3, c8 = t & 7;
  const float4* rowp = (const float4*)(base + (size_t)sl * NQKV + c8 * 32);
  float ss = 0.f;
#pragma unroll
  for (int i = 0; i < 8; ++i) {
    float4 v = rowp[i];
    ss += v.x * v.x + v.y * v.y + v.z * v.z + v.w * v.w;
  }
  ss += __shfl_xor(ss, 1); ss += __shfl_xor(ss, 2); ss += __shfl_xor(ss, 4);
  if (c8 == 0) rs_[sl] = rsqrtf(ss * (1.0f / DHEAD) + 1e-6f);
  __syncthreads();
  int tx = t & 31, ty = t >> 5;
#pragma unroll
  for (int ch = 0; ch < 8; ++ch) {
#pragma unroll
    for (int i = 0; i < 4; ++i) {
      int s_ = ty + i * 8;
      float x = base[(size_t)s_ * NQKV + ch * 32 + tx];
      tile[s_][tx] = __float2bfloat16(x * rs_[s_]);
    }
    __syncthreads();
#pragma unroll
    for (int i = 0; i < 4; ++i) {
      int dl = ty + i * 8;
      vt[((size_t)hh * DHEAD + ch * 32 + dl) * S_LEN + s0 + tx] = tile[tx][dl];
    }
    __syncthreads();
  }
}

// ---------------------------------------------------------------------------
// Flash attention v3, sliding window 512, NO score scale, GQA G=4.
// Q-block=128 (8 waves x 16 rows), KV-step=32, DOUBLE-BUFFERED K/V with one
// raw barrier + one vmcnt(0) per step (gemm_split2 schedule): step i+1's
// loads are issued right after the step-i barrier, so the drain at step i+1
// waits on loads a full step old (free). LDS 104 KB, grid 32x8 = 1 block/CU.
// ---------------------------------------------------------------------------
__global__ __launch_bounds__(512, 2) void attn_split(
    const bf16_t* __restrict__ Qhi, const bf16_t* __restrict__ Qlo,
    const bf16_t* __restrict__ Khi, const bf16_t* __restrict__ Klo,
    const bf16_t* __restrict__ Vt, bf16_t* __restrict__ Aout) {
  const int h = blockIdx.y;
  const int qb = blockIdx.x * 128;
  const int wave = threadIdx.x >> 6, lane = threadIdx.x & 63;
  const int quad = lane >> 4, l16 = lane & 15;
  const int qw = qb + wave * 16;
  const int kv = h >> 2;  // G = 4
  const bf16_t* Qh_ = Qhi + h * DHEAD;   // row stride NHQ*DHEAD
  const bf16_t* Ql_ = Qlo + h * DHEAD;
  const bf16_t* Kh_ = Khi + kv * DHEAD;  // row stride NKVH*DHEAD
  const bf16_t* Kl_ = Klo + kv * DHEAD;
  const bf16_t* Vh_ = Vt + (size_t)kv * DHEAD * S_LEN;

  __shared__ __align__(16) bf16_t KshH[2][32 * 256];  // 2x16 KB (keys x d)
  __shared__ __align__(16) bf16_t KshL[2][32 * 256];  // 2x16 KB
  __shared__ __align__(16) bf16_t Vsh[2][256 * 32];   // 2x16 KB (d x keys)
  __shared__ __align__(16) bf16_t Plds[8][16 * 32];   // 8 KB

  fragAB qfh[8], qfl[8];
#pragma unroll
  for (int c = 0; c < 8; ++c) {
    size_t off = (size_t)(qw + l16) * (NHQ * DHEAD) + c * 32 + quad * 8;
    qfh[c] = *(const fragAB*)(Qh_ + off);
    qfl[c] = *(const fragAB*)(Ql_ + off);
  }

  // staging geometry: 512 threads x 2 chunks x 16B = 16 KB per tile.
  // K: chunk ci -> key-row ci>>5 (32 slots/row), phys slot ci&31 holds
  //    logical d-slot (ci&31)^(row&31). V: d-row ci>>2 (4 slots/row), phys
  //    slot ci&3 holds logical key-slot (ci&3)^(row&3).
  int kRow[2], kCol[2], vRow[2], vCol[2];
#pragma unroll
  for (int i = 0; i < 2; ++i) {
    int ci = i * 512 + threadIdx.x;
    kRow[i] = ci >> 5;
    kCol[i] = ((ci & 31) ^ (kRow[i] & 31)) * 8;
    vRow[i] = ci >> 2;
    vCol[i] = ((ci & 3) ^ (vRow[i] & 3)) * 8;
  }

#define ASTAGE(buf, kb_)                                                     \
  _Pragma("unroll")                                                          \
  for (int i = 0; i < 2; ++i) {                                              \
    size_t dst = (size_t)(i * 512 + threadIdx.x) * 16;                       \
    size_t koff = (size_t)((kb_) + kRow[i]) * (NKVH * DHEAD) + kCol[i];      \
    async_copy16(Kh_ + koff, (char*)KshH[buf] + dst);                        \
    async_copy16(Kl_ + koff, (char*)KshL[buf] + dst);                        \
    async_copy16(Vh_ + (size_t)vRow[i] * S_LEN + (kb_) + vCol[i],            \
                 (char*)Vsh[buf] + dst);                                     \
  }

  fragC zero4 = {0.f, 0.f, 0.f, 0.f};
  fragC o_acc[16];
#pragma unroll
  for (int c = 0; c < 16; ++c) o_acc[c] = zero4;
  float m_run[4] = {NEG_BIG, NEG_BIG, NEG_BIG, NEG_BIG};
  float l_run[4] = {0.f, 0.f, 0.f, 0.f};
  const float LOG2E = 1.4426950408889634f;

  int k_lo = qb - (WIN - 1);
  if (k_lo < 0) k_lo = 0;
  k_lo &= ~31;

  // prologue: stage first KV tile into buffer 0
  ASTAGE(0, k_lo);
  int cur = 0;

  for (int kb = k_lo; kb < qb + 128; kb += 32) {
    // drain own loads for this step (issued a full step ago) + rendezvous.
    VMCNT(0); BARRIER();
    if (kb + 32 < qb + 128) {
      int nbuf = cur ^ 1;
      ASTAGE(nbuf, kb + 32);
    }
    const char* KH = (const char*)KshH[cur];
    const char* KL = (const char*)KshL[cur];
    const char* VB = (const char*)Vsh[cur];

    fragC s[2] = {zero4, zero4};
#pragma unroll
    for (int c = 0; c < 8; ++c) {
      int j = c * 4 + quad;
#pragma unroll
      for (int g = 0; g < 2; ++g) {
        int row = g * 16 + l16;
        int off = (row * 32 + (j ^ (row & 31))) * 16;
        fragAB kh = *(const fragAB*)(KH + off);
        fragAB kl = *(const fragAB*)(KL + off);
        s[g] = __builtin_amdgcn_mfma_f32_16x16x32_bf16(qfl[c], kh, s[g], 0, 0, 0);
        s[g] = __builtin_amdgcn_mfma_f32_16x16x32_bf16(qfh[c], kl, s[g], 0, 0, 0);
        s[g] = __builtin_amdgcn_mfma_f32_16x16x32_bf16(qfh[c], kh, s[g], 0, 0, 0);
      }
    }

    float p[2][4], alpha[4];
#pragma unroll
    for (int r = 0; r < 4; ++r) {
      int qi = qw + quad * 4 + r;
      bool vld[2];
      float mx = NEG_BIG;
#pragma unroll
      for (int g = 0; g < 2; ++g) {
        int ki = kb + g * 16 + l16;
        vld[g] = (ki <= qi) && (qi - ki < WIN);
        mx = fmaxf(mx, vld[g] ? s[g][r] : NEG_BIG);
      }
      mx = fmaxf(mx, __shfl_xor(mx, 1));
      mx = fmaxf(mx, __shfl_xor(mx, 2));
      mx = fmaxf(mx, __shfl_xor(mx, 4));
      mx = fmaxf(mx, __shfl_xor(mx, 8));
      float mn = fmaxf(m_run[r], mx);
      float a  = exp2f(fmaxf(m_run[r] - mn, -80.f) * LOG2E);
      float rs = 0.f;
#pragma unroll
      for (int g = 0; g < 2; ++g) {
        float e = vld[g] ? exp2f(fmaxf(s[g][r] - mn, -80.f) * LOG2E) : 0.f;
        p[g][r] = e;
        rs += e;
      }
      rs += __shfl_xor(rs, 1);
      rs += __shfl_xor(rs, 2);
      rs += __shfl_xor(rs, 4);
      rs += __shfl_xor(rs, 8);
      l_run[r] = l_run[r] * a + rs;
      m_run[r] = mn;
      alpha[r] = a;
    }
#pragma unroll
    for (int c = 0; c < 16; ++c)
#pragma unroll
      for (int r = 0; r < 4; ++r) o_acc[c][r] *= alpha[r];

    bf16_t* Pw = Plds[wave];
#pragma unroll
    for (int r = 0; r < 4; ++r)
#pragma unroll
      for (int g = 0; g < 2; ++g)
        Pw[(quad * 4 + r) * 32 + g * 16 + l16] = __float2bfloat16(p[g][r]);
    fragAB pf = *(const fragAB*)((const char*)Pw + l16 * 64 + quad * 16);

#pragma unroll
    for (int c = 0; c < 16; ++c) {
      int d = c * 16 + l16;
      int offv = (d * 4 + (quad ^ (d & 3))) * 16;
      fragAB vf = *(const fragAB*)(VB + offv);
      o_acc[c] = __builtin_amdgcn_mfma_f32_16x16x32_bf16(pf, vf, o_acc[c], 0, 0, 0);
    }
    cur ^= 1;
  }

  float inv_l[4];
#pragma unroll
  for (int r = 0; r < 4; ++r) inv_l[r] = 1.0f / l_run[r];
#pragma unroll
  for (int c = 0; c < 16; ++c)
#pragma unroll
    for (int r = 0; r < 4; ++r) {
      int row = qw + quad * 4 + r;
      int col = h * DHEAD + c * 16 + l16;
      Aout[(size_t)row * (NHQ * DHEAD) + col] = __float2bfloat16(o_acc[c][r] * inv_l[r]);
    }
#undef ASTAGE
}

// ---------------------------------------------------------------------------
extern "C" void kernel_launch(void* const* d_in, const int* in_sizes, int n_in,
                              void* d_out, int out_size, void* d_ws, size_t ws_size,
                              hipStream_t stream) {
  const float* hid  = (const float*)d_in[0];
  const float* w_q  = (const float*)d_in[1];
  const float* w_k  = (const float*)d_in[2];
  const float* w_v  = (const float*)d_in[3];
  const float* w_o  = (const float*)d_in[4];
  const float* qnw  = (const float*)d_in[5];
  const float* knw  = (const float*)d_in[6];
  const float* cosb = (const float*)d_in[7];
  const float* sinb = (const float*)d_in[8];
  float* outp = (float*)d_out;

  // Workspace (bf16 slots, M1 = 1<<20), peak 52M slots = 104 MiB:
  //  [ 0: 8M)  hidh  -> qh  (after qkv gemm)
  //  [ 8:16M)  hidl  -> ql
  //  [16:22M)  wTh (3072x2048) -> kh[16:18M), kl[18:20M), vt[20:22M) after gemm
  //  [22:28M)  wTl   -> woT[22:26M) after gemm
  //  [28:52M)  projqkv f32 (4096x3072) -> aout[28:36M) after norms
  const size_t M1 = 1048576;
  bf16_t* w = (bf16_t*)d_ws;
  bf16_t* hidh  = w;
  bf16_t* qh    = w;                         // alias hidh
  bf16_t* hidl  = w + 8 * M1;
  bf16_t* ql    = w + 8 * M1;                // alias hidl
  bf16_t* wTh   = w + 16 * M1;
  bf16_t* kh    = w + 16 * M1;               // alias wTh
  bf16_t* kl    = w + 18 * M1;
  bf16_t* vt    = w + 20 * M1;
  bf16_t* wTl   = w + 22 * M1;
  bf16_t* woT   = w + 22 * M1;               // alias wTl
  float*  projqkv = (float*)(w + 28 * M1);
  bf16_t* aout  = w + 28 * M1;               // alias projqkv (after norms)

  // phase 0: split hidden; fused split-transpose [wq|wk|wv] -> wT [3072][2048]
  split_f32<<<(S_LEN * HDIM) / 1024, 256, 0, stream>>>(hid, hidh, hidl, S_LEN * HDIM);
  transpose_split_fused<<<dim3(NQKV / 32, HDIM / 32), 256, 0, stream>>>(
      w_q, w_k, w_v, wTh, wTl);

  // phase 1: fused q+k+v split projection, pipelined 256x192 tiles
  //          grid 16x16 = 256 blocks = exactly 1 per CU
  gemm_split2<<<dim3(NQKV / 192, S_LEN / 256), 512, 0, stream>>>(
      hidh, hidl, wTh, wTl, projqkv, S_LEN, NQKV, HDIM);

  // phase 2: norms (hid/wT dead -> qh/ql/kh/kl/vt targets), q+k fused
  rmsnorm_rope_split_qk<<<dim3(S_LEN, NHQ + NKVH), 256, 0, stream>>>(
      projqkv, qnw, knw, cosb, sinb, qh, ql, kh, kl);
  rmsnorm_vT2<<<dim3(S_LEN / 32, NKVH), 256, 0, stream>>>(
      projqkv, vt, NHQ * DHEAD + NKVH * DHEAD);

  // phase 3: w_o transpose into dead wTl region
  transpose_cvt<<<dim3(HDIM / 32, (NHQ * DHEAD) / 32), 256, 0, stream>>>(w_o, woT, NHQ * DHEAD, HDIM);

  // phase 4: attention -> aout (dead projqkv region)
  //          grid 32x8 = 256 blocks = exactly 1 per CU
  attn_split<<<dim3(S_LEN / 128, NHQ), 512, 0, stream>>>(qh, ql, kh, kl, vt, aout);

  // phase 5: output projection -> fp32 d_out, pipelined 256x128 tiles
  //          grid 16x16 = 256 blocks = exactly 1 per CU
  gemm_bt2<<<dim3(HDIM / 128, S_LEN / 256), 512, 0, stream>>>(
      aout, woT, outp, S_LEN, HDIM, NHQ * DHEAD);
}

// Round 8
// 404.006 us; speedup vs baseline: 1.3021x; 1.0117x over previous
//
#include <hip/hip_runtime.h>
#include <hip/hip_bf16.h>

#define S_LEN 4096
#define HDIM  2048
#define NHQ   8
#define NKVH  2
#define DHEAD 256
#define WIN   512
#define NQKV  3072   // fused q+k+v projection width (2048 + 512 + 512)

typedef __hip_bfloat16 bf16_t;
using fragAB = __attribute__((ext_vector_type(8))) short;  // 8 bf16
using fragC  = __attribute__((ext_vector_type(4))) float;  // 4 fp32

typedef unsigned int u32;
typedef const __attribute__((address_space(1))) u32* gas_ptr;
typedef __attribute__((address_space(3))) u32* las_ptr;

__device__ __forceinline__ void async_copy16(const void* g, void* l) {
  __builtin_amdgcn_global_load_lds((gas_ptr)g, (las_ptr)l, 16, 0, 0);
}

#define NEG_BIG (-3.0e38f)

__device__ __forceinline__ void split2(float x, bf16_t& hi, bf16_t& lo) {
  bf16_t h = __float2bfloat16(x);
  hi = h;
  lo = __float2bfloat16(x - (float)h);
}

// ---------------------------------------------------------------------------
// Elementwise split fp32 -> bf16 hi + bf16 lo  (n multiple of 1024)
// ---------------------------------------------------------------------------
__global__ __launch_bounds__(256) void split_f32(
    const float* __restrict__ in, bf16_t* __restrict__ hi,
    bf16_t* __restrict__ lo, int n) {
  int i = (blockIdx.x * 256 + threadIdx.x) * 4;
  if (i >= n) return;
  float4 v = *(const float4*)(in + i);
  split2(v.x, hi[i + 0], lo[i + 0]);
  split2(v.y, hi[i + 1], lo[i + 1]);
  split2(v.z, hi[i + 2], lo[i + 2]);
  split2(v.w, hi[i + 3], lo[i + 3]);
}

// ---------------------------------------------------------------------------
// Transpose+convert fp32 [R][C] -> bf16 [C][R]
// LIFETIME NOTE: launched for w_o -> woT which ALIASES wTl; must run AFTER
// gemm_split2 has consumed wTl (round-6/7 bug: running it at phase 0
// clobbered the low-split weights before the QKV GEMM read them).
// ---------------------------------------------------------------------------
__global__ __launch_bounds__(256) void transpose_cvt(
    const float* __restrict__ in, bf16_t* __restrict__ out, int R, int C) {
  __shared__ bf16_t tile[32][33];
  int c0 = blockIdx.x * 32, r0 = blockIdx.y * 32;
  int tx = threadIdx.x & 31, ty = threadIdx.x >> 5;
#pragma unroll
  for (int i = 0; i < 4; ++i)
    tile[ty + i * 8][tx] = __float2bfloat16(in[(size_t)(r0 + ty + i * 8) * C + c0 + tx]);
  __syncthreads();
#pragma unroll
  for (int i = 0; i < 4; ++i)
    out[(size_t)(c0 + ty + i * 8) * R + r0 + tx] = tile[tx][ty + i * 8];
}

// ---------------------------------------------------------------------------
// Fused transpose+split of [wq|wk|wv] -> wT hi/lo [3072][2048]
// output rows [0,2048) <- wq cols, [2048,2560) <- wk, [2560,3072) <- wv
// ---------------------------------------------------------------------------
__global__ __launch_bounds__(256) void transpose_split_fused(
    const float* __restrict__ wq, const float* __restrict__ wk,
    const float* __restrict__ wv, bf16_t* __restrict__ hiT,
    bf16_t* __restrict__ loT) {
  __shared__ bf16_t th[32][33];
  __shared__ bf16_t tl[32][33];
  int oc = blockIdx.x * 32;   // output row group (input col)
  int r0 = blockIdx.y * 32;   // input row
  const float* src; int C, c0;
  if (oc < 2048)      { src = wq; C = 2048; c0 = oc; }
  else if (oc < 2560) { src = wk; C = 512;  c0 = oc - 2048; }
  else                { src = wv; C = 512;  c0 = oc - 2560; }
  int tx = threadIdx.x & 31, ty = threadIdx.x >> 5;
#pragma unroll
  for (int i = 0; i < 4; ++i) {
    float x = src[(size_t)(r0 + ty + i * 8) * C + c0 + tx];
    bf16_t h, l; split2(x, h, l);
    th[ty + i * 8][tx] = h;
    tl[ty + i * 8][tx] = l;
  }
  __syncthreads();
#pragma unroll
  for (int i = 0; i < 4; ++i) {
    hiT[(size_t)(oc + ty + i * 8) * HDIM + r0 + tx] = th[tx][ty + i * 8];
    loT[(size_t)(oc + ty + i * 8) * HDIM + r0 + tx] = tl[tx][ty + i * 8];
  }
}

// ---------------------------------------------------------------------------
// Shared helpers for pipelined GEMMs
// ---------------------------------------------------------------------------
#define VMCNT_(n) asm volatile("s_waitcnt vmcnt(" #n ")" ::: "memory")
#define VMCNT(n) VMCNT_(n)
#define BARRIER()                     \
  {                                   \
    asm volatile("" ::: "memory");    \
    __builtin_amdgcn_s_barrier();     \
    asm volatile("" ::: "memory");    \
  }

#define MFMA_(a, b, c) __builtin_amdgcn_mfma_f32_16x16x32_bf16(a, b, c, 0, 0, 0)

// ---------------------------------------------------------------------------
// Split-precision GEMM v4 (round-5 verified): C = Ah*Bh + Ah*Bl + Al*Bh.
// BM=256, BN=192, BK=32, 512 threads (8 waves, 2M x 4N), wave tile 128x48.
// Double-buffered LDS (112 KB), ONE barrier + one vmcnt(0) per K-step.
// XCD-chunked block swizzle (bijective relabel).
// ---------------------------------------------------------------------------
#define OFF_AH 0
#define OFF_AL 16384
#define OFF_BH 32768
#define OFF_BL 45056
#define BUFSZ  57344

#define LOADB()                                                   \
  _Pragma("unroll")                                               \
  for (int j = 0; j < 3; ++j) {                                   \
    const char* bp_ = bufc + (wn + j * 16 + l16) * 64 + rdq;      \
    bh[j] = *(const fragAB*)(bp_ + OFF_BH);                       \
    bl[j] = *(const fragAB*)(bp_ + OFF_BL);                       \
  }

struct ARegs { fragAB ah0, al0, ah1, al1; };

__device__ __forceinline__ void lda_split(ARegs& r, const char* bufc, int wm,
                                          int p, int l16, int rdq) {
  const char* a0 = bufc + (wm + (2 * p) * 16 + l16) * 64 + rdq;
  const char* a1 = a0 + 16 * 64;
  r.ah0 = *(const fragAB*)(a0 + OFF_AH);
  r.al0 = *(const fragAB*)(a0 + OFF_AL);
  r.ah1 = *(const fragAB*)(a1 + OFF_AH);
  r.al1 = *(const fragAB*)(a1 + OFF_AL);
}

__device__ __forceinline__ void mfma_split(fragC (&acc)[8][3], const ARegs& r,
                                           const fragAB (&bh)[3],
                                           const fragAB (&bl)[3], int p) {
  __builtin_amdgcn_s_setprio(1);
#pragma unroll
  for (int j = 0; j < 3; ++j) {
    acc[2 * p][j]     = MFMA_(r.al0, bh[j], acc[2 * p][j]);
    acc[2 * p + 1][j] = MFMA_(r.al1, bh[j], acc[2 * p + 1][j]);
  }
#pragma unroll
  for (int j = 0; j < 3; ++j) {
    acc[2 * p][j]     = MFMA_(r.ah0, bl[j], acc[2 * p][j]);
    acc[2 * p + 1][j] = MFMA_(r.ah1, bl[j], acc[2 * p + 1][j]);
  }
#pragma unroll
  for (int j = 0; j < 3; ++j) {
    acc[2 * p][j]     = MFMA_(r.ah0, bh[j], acc[2 * p][j]);
    acc[2 * p + 1][j] = MFMA_(r.ah1, bh[j], acc[2 * p + 1][j]);
  }
  __builtin_amdgcn_s_setprio(0);
}

// step body shared by main loop and tail (reads bufc only)
#define SPLIT_STEP()                        \
  {                                         \
    LOADB();                                \
    lda_split(r0, bufc, wm, 0, l16, rdq);   \
    lda_split(r1, bufc, wm, 1, l16, rdq);   \
    mfma_split(acc, r0, bh, bl, 0);         \
    lda_split(r0, bufc, wm, 2, l16, rdq);   \
    mfma_split(acc, r1, bh, bl, 1);         \
    lda_split(r1, bufc, wm, 3, l16, rdq);   \
    mfma_split(acc, r0, bh, bl, 2);         \
    mfma_split(acc, r1, bh, bl, 3);         \
  }

__global__ __launch_bounds__(512, 2) void gemm_split2(
    const bf16_t* __restrict__ Ah, const bf16_t* __restrict__ Al,
    const bf16_t* __restrict__ Bh, const bf16_t* __restrict__ Bl,
    float* __restrict__ C, int M, int N, int K) {
  __shared__ __align__(16) char lds[2 * BUFSZ];
  const int t = threadIdx.x;
  const int wave = t >> 6, lane = t & 63;
  const int quad = lane >> 4, l16 = lane & 15;
  // XCD-chunked swizzle (grid 16x16 = 256 = 32/XCD): bijective relabel.
  const int g = blockIdx.y * 16 + blockIdx.x;
  const int lby = (g & 7) * 2 + ((g >> 3) >> 4);
  const int lbx = (g >> 3) & 15;
  const int m0 = lby * 256, n0 = lbx * 192;
  const int wm = (wave >> 2) * 128, wn = (wave & 3) * 48;
  // T2 read swizzle: phys 16B-slot of (row r, col-16B q) = q ^ ((r>>1)&3).
  const int rdq = (quad ^ ((l16 >> 1) & 3)) * 16;

  // Per-lane global source offset inside a 16-row x 32-col chunk (inverse swizzle).
  const size_t laneOff =
      (size_t)(lane >> 2) * K * 2 + 16 * ((lane & 3) ^ ((lane >> 3) & 3));

  // 7 staging chunks per wave per K-step.
  const char* gsrc[7];
  int ldsOff[7];
#pragma unroll
  for (int pos = 0; pos < 3; ++pos) {
    int c = wave + 8 * pos;            // 0..23: Bh chunks 0..11, Bl chunks 0..11
    if (c < 12) {
      gsrc[pos]   = (const char*)Bh + (size_t)(n0 + 16 * c) * K * 2 + laneOff;
      ldsOff[pos] = OFF_BH + c * 1024;
    } else {
      gsrc[pos]   = (const char*)Bl + (size_t)(n0 + 16 * (c - 12)) * K * 2 + laneOff;
      ldsOff[pos] = OFF_BL + (c - 12) * 1024;
    }
  }
#pragma unroll
  for (int p = 0; p < 4; ++p) {
    int sub = wave & 3;
    int R0 = ((sub >> 1) & 1) * 128 + 32 * p + (sub & 1) * 16;
    const char* base = (const char*)(wave < 4 ? Ah : Al);
    gsrc[3 + p]   = base + (size_t)(m0 + R0) * K * 2 + laneOff;
    ldsOff[3 + p] = (wave < 4 ? OFF_AH : OFF_AL) + R0 * 64;
  }

  fragC zero4 = {0.f, 0.f, 0.f, 0.f};
  fragC acc[8][3];
#pragma unroll
  for (int i = 0; i < 8; ++i)
#pragma unroll
    for (int j = 0; j < 3; ++j) acc[i][j] = zero4;

  char* ldsc = (char*)lds;
  // prologue: stage K-step 0 into buffer 0
#pragma unroll
  for (int ps = 0; ps < 7; ++ps) async_copy16(gsrc[ps], ldsc + ldsOff[ps]);
#pragma unroll
  for (int ps = 0; ps < 7; ++ps) gsrc[ps] += 64;

  fragAB bh[3], bl[3];
  ARegs r0, r1;
  int cur = 0;
  const int NS = K / 32;
  for (int it = 0; it < NS - 1; ++it) {
    const char* bufc = ldsc + cur * BUFSZ;
    char* nb = ldsc + (cur ^ 1) * BUFSZ;
    // drain this step's loads (issued a full K-step ago -> no stall) and
    // rendezvous; after the barrier, nb is safe to overwrite.
    VMCNT(0); BARRIER();
#pragma unroll
    for (int ps = 0; ps < 7; ++ps) async_copy16(gsrc[ps], nb + ldsOff[ps]);
#pragma unroll
    for (int ps = 0; ps < 7; ++ps) gsrc[ps] += 64;
    SPLIT_STEP();
    cur ^= 1;
  }
  {  // final K-step
    const char* bufc = ldsc + cur * BUFSZ;
    VMCNT(0); BARRIER();
    SPLIT_STEP();
  }

#pragma unroll
  for (int i = 0; i < 8; ++i)
#pragma unroll
    for (int j = 0; j < 3; ++j)
#pragma unroll
      for (int r = 0; r < 4; ++r) {
        int row = m0 + wm + i * 16 + quad * 4 + r;
        int col = n0 + wn + j * 16 + l16;
        C[(size_t)row * N + col] = acc[i][j][r];
      }
}

// ---------------------------------------------------------------------------
// Plain GEMM v3 (output projection): C[M][N] = A[M][K]*Bt[N][K]^T, fp32 out.
// BM=256, BN=128, BK=64, 512 threads (8 waves as 2M x 4N -> wave tile 128x32).
// 1-barrier-per-K-step schedule + XCD-chunked block swizzle.
// ---------------------------------------------------------------------------
#define BT_OFF_A 0
#define BT_OFF_B 32768
#define BT_BUFSZ 49152

struct ARegs2 { fragAB a[2][2]; };  // [row-in-pair][k-slice]

__device__ __forceinline__ void lda_bt(ARegs2& r, const char* bufc, int wm,
                                       int p, int l16, int quad, int rx) {
#pragma unroll
  for (int u = 0; u < 2; ++u)
#pragma unroll
    for (int ks = 0; ks < 2; ++ks)
      r.a[u][ks] = *(const fragAB*)(bufc + BT_OFF_A +
                                    (wm + (2 * p + u) * 16 + l16) * 128 +
                                    (((ks * 4 + quad) ^ rx) * 16));
}

__device__ __forceinline__ void mfma_bt(fragC (&acc)[8][2], const ARegs2& r,
                                        const fragAB (&b)[2][2], int p) {
  __builtin_amdgcn_s_setprio(1);
#pragma unroll
  for (int ks = 0; ks < 2; ++ks)
#pragma unroll
    for (int j = 0; j < 2; ++j) {
      acc[2 * p][j]     = MFMA_(r.a[0][ks], b[j][ks], acc[2 * p][j]);
      acc[2 * p + 1][j] = MFMA_(r.a[1][ks], b[j][ks], acc[2 * p + 1][j]);
    }
  __builtin_amdgcn_s_setprio(0);
}

#define BT_LOADB()                                                        \
  _Pragma("unroll")                                                       \
  for (int j = 0; j < 2; ++j)                                             \
  _Pragma("unroll")                                                       \
    for (int ks = 0; ks < 2; ++ks)                                        \
      bfr[j][ks] = *(const fragAB*)(bufc + BT_OFF_B +                     \
                                    (wn + j * 16 + l16) * 128 +           \
                                    (((ks * 4 + quad) ^ rx) * 16));

#define BT_STEP()                                 \
  {                                               \
    BT_LOADB();                                   \
    lda_bt(r0, bufc, wm, 0, l16, quad, rx);       \
    lda_bt(r1, bufc, wm, 1, l16, quad, rx);       \
    mfma_bt(acc, r0, bfr, 0);                     \
    lda_bt(r0, bufc, wm, 2, l16, quad, rx);       \
    mfma_bt(acc, r1, bfr, 1);                     \
    lda_bt(r1, bufc, wm, 3, l16, quad, rx);       \
    mfma_bt(acc, r0, bfr, 2);                     \
    mfma_bt(acc, r1, bfr, 3);                     \
  }

__global__ __launch_bounds__(512, 2) void gemm_bt2(
    const bf16_t* __restrict__ A, const bf16_t* __restrict__ Bt,
    float* __restrict__ C, int M, int N, int K) {
  __shared__ __align__(16) char lds[2 * BT_BUFSZ];
  const int t = threadIdx.x;
  const int wave = t >> 6, lane = t & 63;
  const int quad = lane >> 4, l16 = lane & 15;
  const int g = blockIdx.y * 16 + blockIdx.x;
  const int lby = (g & 7) * 2 + ((g >> 3) >> 4);
  const int lbx = (g >> 3) & 15;
  const int m0 = lby * 256, n0 = lbx * 128;
  const int wm = (wave >> 2) * 128, wn = (wave & 3) * 32;
  const int rx = l16 & 7;  // row-XOR for 8-slot swizzle (128B rows)

  // chunk = 8 rows x 64 cols (128B rows). lane l stages row l>>3,
  // logical col16 (l&7)^((l>>3)&7) -> LDS phys slot l&7 (inverse swizzle).
  const size_t laneOff =
      (size_t)(lane >> 3) * K * 2 + 16 * ((lane & 7) ^ ((lane >> 3) & 7));

  // 6 staging chunks per wave per K-step: B,B,A0..A3.
  const char* gsrc[6];
  int ldsOff[6];
#pragma unroll
  for (int pos = 0; pos < 2; ++pos) {
    int c = wave + 8 * pos;  // B chunks 0..15, rows [8c,8c+8)
    gsrc[pos]   = (const char*)Bt + (size_t)(n0 + 8 * c) * K * 2 + laneOff;
    ldsOff[pos] = BT_OFF_B + c * 1024;
  }
#pragma unroll
  for (int p = 0; p < 4; ++p) {
    int R0 = (wave >> 2) * 128 + 32 * p + (wave & 3) * 8;
    gsrc[2 + p]   = (const char*)A + (size_t)(m0 + R0) * K * 2 + laneOff;
    ldsOff[2 + p] = BT_OFF_A + R0 * 128;
  }

  fragC zero4 = {0.f, 0.f, 0.f, 0.f};
  fragC acc[8][2];
#pragma unroll
  for (int i = 0; i < 8; ++i)
#pragma unroll
    for (int j = 0; j < 2; ++j) acc[i][j] = zero4;

  char* ldsc = (char*)lds;
#pragma unroll
  for (int ps = 0; ps < 6; ++ps) async_copy16(gsrc[ps], ldsc + ldsOff[ps]);
#pragma unroll
  for (int ps = 0; ps < 6; ++ps) gsrc[ps] += 128;

  fragAB bfr[2][2];
  ARegs2 r0, r1;
  int cur = 0;
  const int NS = K / 64;
  for (int it = 0; it < NS - 1; ++it) {
    const char* bufc = ldsc + cur * BT_BUFSZ;
    char* nb = ldsc + (cur ^ 1) * BT_BUFSZ;
    VMCNT(0); BARRIER();
#pragma unroll
    for (int ps = 0; ps < 6; ++ps) async_copy16(gsrc[ps], nb + ldsOff[ps]);
#pragma unroll
    for (int ps = 0; ps < 6; ++ps) gsrc[ps] += 128;
    BT_STEP();
    cur ^= 1;
  }
  {
    const char* bufc = ldsc + cur * BT_BUFSZ;
    VMCNT(0); BARRIER();
    BT_STEP();
  }

#pragma unroll
  for (int i = 0; i < 8; ++i)
#pragma unroll
    for (int j = 0; j < 2; ++j)
#pragma unroll
      for (int r = 0; r < 4; ++r) {
        int row = m0 + wm + i * 16 + quad * 4 + r;
        int col = n0 + wn + j * 16 + l16;
        C[(size_t)row * N + col] = acc[i][j][r];
      }
}

// ---------------------------------------------------------------------------
// Fused RMS-norm (+fp32 weight) + RoPE for q and k heads, fp32 in -> split
// bf16 hi/lo out. blockIdx.y: 0..7 = q heads, 8..9 = k heads.
// ---------------------------------------------------------------------------
__global__ __launch_bounds__(256) void rmsnorm_rope_split_qk(
    const float* __restrict__ proj, const float* __restrict__ qnw,
    const float* __restrict__ knw, const float* __restrict__ cosb,
    const float* __restrict__ sinb, bf16_t* __restrict__ qhi,
    bf16_t* __restrict__ qlo, bf16_t* __restrict__ khi,
    bf16_t* __restrict__ klo) {
  int s = blockIdx.x, hb = blockIdx.y, d = threadIdx.x;
  const float* w; bf16_t* oh; bf16_t* ol; int inOff, outStride, oBase;
  if (hb < NHQ) {
    w = qnw; oh = qhi; ol = qlo;
    inOff = hb * DHEAD; outStride = NHQ * DHEAD; oBase = hb * DHEAD;
  } else {
    int hk = hb - NHQ;
    w = knw; oh = khi; ol = klo;
    inOff = NHQ * DHEAD + hk * DHEAD; outStride = NKVH * DHEAD; oBase = hk * DHEAD;
  }
  float x = proj[(size_t)s * NQKV + inOff + d];
  float ss = x * x;
  ss += __shfl_xor(ss, 1);  ss += __shfl_xor(ss, 2);  ss += __shfl_xor(ss, 4);
  ss += __shfl_xor(ss, 8);  ss += __shfl_xor(ss, 16); ss += __shfl_xor(ss, 32);
  __shared__ float part[4];
  __shared__ float xs[DHEAD];
  if ((threadIdx.x & 63) == 0) part[threadIdx.x >> 6] = ss;
  __syncthreads();
  float tot = part[0] + part[1] + part[2] + part[3];
  float r = rsqrtf(tot * (1.0f / DHEAD) + 1e-6f);
  float xn = x * r * w[d];
  xs[d] = xn;
  __syncthreads();
  float other = xs[(d + 128) & 255];
  float rot = (d < 128) ? -other : other;
  float y = xn * cosb[(size_t)s * DHEAD + d] + rot * sinb[(size_t)s * DHEAD + d];
  bf16_t h2, l2; split2(y, h2, l2);
  size_t oidx = (size_t)s * outStride + oBase + d;
  oh[oidx] = h2;
  ol[oidx] = l2;
}

// ---------------------------------------------------------------------------
// RMS-norm (no weight) + transposed write [NKV][D][S], fully coalesced.
// ---------------------------------------------------------------------------
__global__ __launch_bounds__(256) void rmsnorm_vT2(
    const float* __restrict__ proj, bf16_t* __restrict__ vt, int inOff) {
  __shared__ float rs_[32];
  __shared__ bf16_t tile[32][33];
  int s0 = blockIdx.x * 32, hh = blockIdx.y;
  const float* base = proj + (size_t)s0 * NQKV + inOff + hh * DHEAD;
  int t = threadIdx.x;
  int sl = t >> 3, c8 = t & 7;
  const float4* rowp = (const float4*)(base + (size_t)sl * NQKV + c8 * 32);
  float ss = 0.f;
#pragma unroll
  for (int i = 0; i < 8; ++i) {
    float4 v = rowp[i];
    ss += v.x * v.x + v.y * v.y + v.z * v.z + v.w * v.w;
  }
  ss += __shfl_xor(ss, 1); ss += __shfl_xor(ss, 2); ss += __shfl_xor(ss, 4);
  if (c8 == 0) rs_[sl] = rsqrtf(ss * (1.0f / DHEAD) + 1e-6f);
  __syncthreads();
  int tx = t & 31, ty = t >> 5;
#pragma unroll
  for (int ch = 0; ch < 8; ++ch) {
#pragma unroll
    for (int i = 0; i < 4; ++i) {
      int s_ = ty + i * 8;
      float x = base[(size_t)s_ * NQKV + ch * 32 + tx];
      tile[s_][tx] = __float2bfloat16(x * rs_[s_]);
    }
    __syncthreads();
#pragma unroll
    for (int i = 0; i < 4; ++i) {
      int dl = ty + i * 8;
      vt[((size_t)hh * DHEAD + ch * 32 + dl) * S_LEN + s0 + tx] = tile[tx][dl];
    }
    __syncthreads();
  }
}

// ---------------------------------------------------------------------------
// Flash attention v4: Q=128, KV=32, dbuf, 1 barrier/step, setprio around
// MFMA clusters, XCD-chunked block swizzle.
// ---------------------------------------------------------------------------
__global__ __launch_bounds__(512, 2) void attn_split(
    const bf16_t* __restrict__ Qhi, const bf16_t* __restrict__ Qlo,
    const bf16_t* __restrict__ Khi, const bf16_t* __restrict__ Klo,
    const bf16_t* __restrict__ Vt, bf16_t* __restrict__ Aout) {
  const int g = blockIdx.y * 32 + blockIdx.x;
  const int lbx = (g & 7) * 4 + ((g >> 3) & 3);
  const int h = g >> 5;
  const int qb = lbx * 128;
  const int wave = threadIdx.x >> 6, lane = threadIdx.x & 63;
  const int quad = lane >> 4, l16 = lane & 15;
  const int qw = qb + wave * 16;
  const int kv = h >> 2;  // G = 4
  const bf16_t* Qh_ = Qhi + h * DHEAD;   // row stride NHQ*DHEAD
  const bf16_t* Ql_ = Qlo + h * DHEAD;
  const bf16_t* Kh_ = Khi + kv * DHEAD;  // row stride NKVH*DHEAD
  const bf16_t* Kl_ = Klo + kv * DHEAD;
  const bf16_t* Vh_ = Vt + (size_t)kv * DHEAD * S_LEN;

  __shared__ __align__(16) bf16_t KshH[2][32 * 256];  // 2x16 KB (keys x d)
  __shared__ __align__(16) bf16_t KshL[2][32 * 256];  // 2x16 KB
  __shared__ __align__(16) bf16_t Vsh[2][256 * 32];   // 2x16 KB (d x keys)
  __shared__ __align__(16) bf16_t Plds[8][16 * 32];   // 8 KB

  fragAB qfh[8], qfl[8];
#pragma unroll
  for (int c = 0; c < 8; ++c) {
    size_t off = (size_t)(qw + l16) * (NHQ * DHEAD) + c * 32 + quad * 8;
    qfh[c] = *(const fragAB*)(Qh_ + off);
    qfl[c] = *(const fragAB*)(Ql_ + off);
  }

  int kRow[2], kCol[2], vRow[2], vCol[2];
#pragma unroll
  for (int i = 0; i < 2; ++i) {
    int ci = i * 512 + threadIdx.x;
    kRow[i] = ci >> 5;
    kCol[i] = ((ci & 31) ^ (kRow[i] & 31)) * 8;
    vRow[i] = ci >> 2;
    vCol[i] = ((ci & 3) ^ (vRow[i] & 3)) * 8;
  }

#define ASTAGE(buf, kb_)                                                     \
  _Pragma("unroll")                                                          \
  for (int i = 0; i < 2; ++i) {                                              \
    size_t dst = (size_t)(i * 512 + threadIdx.x) * 16;                       \
    size_t koff = (size_t)((kb_) + kRow[i]) * (NKVH * DHEAD) + kCol[i];      \
    async_copy16(Kh_ + koff, (char*)KshH[buf] + dst);                        \
    async_copy16(Kl_ + koff, (char*)KshL[buf] + dst);                        \
    async_copy16(Vh_ + (size_t)vRow[i] * S_LEN + (kb_) + vCol[i],            \
                 (char*)Vsh[buf] + dst);                                     \
  }

  fragC zero4 = {0.f, 0.f, 0.f, 0.f};
  fragC o_acc[16];
#pragma unroll
  for (int c = 0; c < 16; ++c) o_acc[c] = zero4;
  float m_run[4] = {NEG_BIG, NEG_BIG, NEG_BIG, NEG_BIG};
  float l_run[4] = {0.f, 0.f, 0.f, 0.f};
  const float LOG2E = 1.4426950408889634f;

  int k_lo = qb - (WIN - 1);
  if (k_lo < 0) k_lo = 0;
  k_lo &= ~31;

  // prologue: stage first KV tile into buffer 0
  ASTAGE(0, k_lo);
  int cur = 0;

  for (int kb = k_lo; kb < qb + 128; kb += 32) {
    VMCNT(0); BARRIER();
    if (kb + 32 < qb + 128) {
      int nbuf = cur ^ 1;
      ASTAGE(nbuf, kb + 32);
    }
    const char* KH = (const char*)KshH[cur];
    const char* KL = (const char*)KshL[cur];
    const char* VB = (const char*)Vsh[cur];

    fragC s[2] = {zero4, zero4};
    __builtin_amdgcn_s_setprio(1);
#pragma unroll
    for (int c = 0; c < 8; ++c) {
      int j = c * 4 + quad;
#pragma unroll
      for (int gg = 0; gg < 2; ++gg) {
        int row = gg * 16 + l16;
        int off = (row * 32 + (j ^ (row & 31))) * 16;
        fragAB kh = *(const fragAB*)(KH + off);
        fragAB kl = *(const fragAB*)(KL + off);
        s[gg] = __builtin_amdgcn_mfma_f32_16x16x32_bf16(qfl[c], kh, s[gg], 0, 0, 0);
        s[gg] = __builtin_amdgcn_mfma_f32_16x16x32_bf16(qfh[c], kl, s[gg], 0, 0, 0);
        s[gg] = __builtin_amdgcn_mfma_f32_16x16x32_bf16(qfh[c], kh, s[gg], 0, 0, 0);
      }
    }
    __builtin_amdgcn_s_setprio(0);

    float p[2][4], alpha[4];
#pragma unroll
    for (int r = 0; r < 4; ++r) {
      int qi = qw + quad * 4 + r;
      bool vld[2];
      float mx = NEG_BIG;
#pragma unroll
      for (int gg = 0; gg < 2; ++gg) {
        int ki = kb + gg * 16 + l16;
        vld[gg] = (ki <= qi) && (qi - ki < WIN);
        mx = fmaxf(mx, vld[gg] ? s[gg][r] : NEG_BIG);
      }
      mx = fmaxf(mx, __shfl_xor(mx, 1));
      mx = fmaxf(mx, __shfl_xor(mx, 2));
      mx = fmaxf(mx, __shfl_xor(mx, 4));
      mx = fmaxf(mx, __shfl_xor(mx, 8));
      float mn = fmaxf(m_run[r], mx);
      float a  = exp2f(fmaxf(m_run[r] - mn, -80.f) * LOG2E);
      float rs = 0.f;
#pragma unroll
      for (int gg = 0; gg < 2; ++gg) {
        float e = vld[gg] ? exp2f(fmaxf(s[gg][r] - mn, -80.f) * LOG2E) : 0.f;
        p[gg][r] = e;
        rs += e;
      }
      rs += __shfl_xor(rs, 1);
      rs += __shfl_xor(rs, 2);
      rs += __shfl_xor(rs, 4);
      rs += __shfl_xor(rs, 8);
      l_run[r] = l_run[r] * a + rs;
      m_run[r] = mn;
      alpha[r] = a;
    }
#pragma unroll
    for (int c = 0; c < 16; ++c)
#pragma unroll
      for (int r = 0; r < 4; ++r) o_acc[c][r] *= alpha[r];

    bf16_t* Pw = Plds[wave];
#pragma unroll
    for (int r = 0; r < 4; ++r)
#pragma unroll
      for (int gg = 0; gg < 2; ++gg)
        Pw[(quad * 4 + r) * 32 + gg * 16 + l16] = __float2bfloat16(p[gg][r]);
    fragAB pf = *(const fragAB*)((const char*)Pw + l16 * 64 + quad * 16);

    __builtin_amdgcn_s_setprio(1);
#pragma unroll
    for (int c = 0; c < 16; ++c) {
      int d = c * 16 + l16;
      int offv = (d * 4 + (quad ^ (d & 3))) * 16;
      fragAB vf = *(const fragAB*)(VB + offv);
      o_acc[c] = __builtin_amdgcn_mfma_f32_16x16x32_bf16(pf, vf, o_acc[c], 0, 0, 0);
    }
    __builtin_amdgcn_s_setprio(0);
    cur ^= 1;
  }

  float inv_l[4];
#pragma unroll
  for (int r = 0; r < 4; ++r) inv_l[r] = 1.0f / l_run[r];
#pragma unroll
  for (int c = 0; c < 16; ++c)
#pragma unroll
    for (int r = 0; r < 4; ++r) {
      int row = qw + quad * 4 + r;
      int col = h * DHEAD + c * 16 + l16;
      Aout[(size_t)row * (NHQ * DHEAD) + col] = __float2bfloat16(o_acc[c][r] * inv_l[r]);
    }
#undef ASTAGE
}

// ---------------------------------------------------------------------------
extern "C" void kernel_launch(void* const* d_in, const int* in_sizes, int n_in,
                              void* d_out, int out_size, void* d_ws, size_t ws_size,
                              hipStream_t stream) {
  const float* hid  = (const float*)d_in[0];
  const float* w_q  = (const float*)d_in[1];
  const float* w_k  = (const float*)d_in[2];
  const float* w_v  = (const float*)d_in[3];
  const float* w_o  = (const float*)d_in[4];
  const float* qnw  = (const float*)d_in[5];
  const float* knw  = (const float*)d_in[6];
  const float* cosb = (const float*)d_in[7];
  const float* sinb = (const float*)d_in[8];
  float* outp = (float*)d_out;

  // Workspace (bf16 slots, M1 = 1<<20), peak 52M slots = 104 MiB:
  //  [ 0: 8M)  hidh  -> qh  (after qkv gemm)
  //  [ 8:16M)  hidl  -> ql
  //  [16:22M)  wTh (3072x2048) -> kh[16:18M), kl[18:20M), vt[20:22M) after gemm
  //  [22:28M)  wTl   -> woT[22:26M) after gemm  (LIFETIME: woT writes must
  //            come AFTER gemm_split2 — rounds 6/7 bug wrote it at phase 0)
  //  [28:52M)  projqkv f32 (4096x3072) -> aout[28:36M) after norms
  const size_t M1 = 1048576;
  bf16_t* w = (bf16_t*)d_ws;
  bf16_t* hidh  = w;
  bf16_t* qh    = w;                         // alias hidh
  bf16_t* hidl  = w + 8 * M1;
  bf16_t* ql    = w + 8 * M1;                // alias hidl
  bf16_t* wTh   = w + 16 * M1;
  bf16_t* kh    = w + 16 * M1;               // alias wTh
  bf16_t* kl    = w + 18 * M1;
  bf16_t* vt    = w + 20 * M1;
  bf16_t* wTl   = w + 22 * M1;
  bf16_t* woT   = w + 22 * M1;               // alias wTl
  float*  projqkv = (float*)(w + 28 * M1);
  bf16_t* aout  = w + 28 * M1;               // alias projqkv (after norms)

  // phase 0: split hidden; fused split-transpose [wq|wk|wv] -> wT [3072][2048]
  split_f32<<<(S_LEN * HDIM) / 1024, 256, 0, stream>>>(hid, hidh, hidl, S_LEN * HDIM);
  transpose_split_fused<<<dim3(NQKV / 32, HDIM / 32), 256, 0, stream>>>(
      w_q, w_k, w_v, wTh, wTl);

  // phase 1: fused q+k+v split projection, pipelined 256x192 tiles
  //          grid 16x16 = 256 blocks = exactly 1 per CU (8-wave verified)
  gemm_split2<<<dim3(NQKV / 192, S_LEN / 256), 512, 0, stream>>>(
      hidh, hidl, wTh, wTl, projqkv, S_LEN, NQKV, HDIM);

  // phase 2: norms (hid/wT dead -> qh/ql/kh/kl/vt targets), q+k fused;
  //          w_o transpose into dead wTl region (AFTER gemm_split2!)
  rmsnorm_rope_split_qk<<<dim3(S_LEN, NHQ + NKVH), 256, 0, stream>>>(
      projqkv, qnw, knw, cosb, sinb, qh, ql, kh, kl);
  rmsnorm_vT2<<<dim3(S_LEN / 32, NKVH), 256, 0, stream>>>(
      projqkv, vt, NHQ * DHEAD + NKVH * DHEAD);
  transpose_cvt<<<dim3(HDIM / 32, (NHQ * DHEAD) / 32), 256, 0, stream>>>(
      w_o, woT, NHQ * DHEAD, HDIM);

  // phase 3: attention -> aout (dead projqkv region)
  //          grid 32x8 = 256 blocks = exactly 1 per CU
  attn_split<<<dim3(S_LEN / 128, NHQ), 512, 0, stream>>>(qh, ql, kh, kl, vt, aout);

  // phase 4: output projection -> fp32 d_out, pipelined 256x128 tiles
  gemm_bt2<<<dim3(HDIM / 128, S_LEN / 256), 512, 0, stream>>>(
      aout, woT, outp, S_LEN, HDIM, NHQ * DHEAD);
}

// Round 9
// 399.315 us; speedup vs baseline: 1.3174x; 1.0117x over previous
//
#include <hip/hip_runtime.h>
#include <hip/hip_bf16.h>

#define S_LEN 4096
#define HDIM  2048
#define NHQ   8
#define NKVH  2
#define DHEAD 256
#define WIN   512
#define NQKV  3072   // fused q+k+v projection width (2048 + 512 + 512)

typedef __hip_bfloat16 bf16_t;
using fragAB = __attribute__((ext_vector_type(8))) short;  // 8 bf16
using fragC  = __attribute__((ext_vector_type(4))) float;  // 4 fp32

struct __align__(8)  bf16x4 { bf16_t v[4]; };
struct __align__(16) bf16x8 { bf16_t v[8]; };

typedef unsigned int u32;
typedef const __attribute__((address_space(1))) u32* gas_ptr;
typedef __attribute__((address_space(3))) u32* las_ptr;

__device__ __forceinline__ void async_copy16(const void* g, void* l) {
  __builtin_amdgcn_global_load_lds((gas_ptr)g, (las_ptr)l, 16, 0, 0);
}

#define NEG_BIG (-3.0e38f)

__device__ __forceinline__ void split2(float x, bf16_t& hi, bf16_t& lo) {
  bf16_t h = __float2bfloat16(x);
  hi = h;
  lo = __float2bfloat16(x - (float)h);
}

// ---------------------------------------------------------------------------
// Elementwise split fp32 -> bf16 hi + bf16 lo (n multiple of 2048).
// 8 elem/thread, 16B vector stores (G13: never scalar bf16 stores).
// ---------------------------------------------------------------------------
__global__ __launch_bounds__(256) void split_f32(
    const float* __restrict__ in, bf16_t* __restrict__ hi,
    bf16_t* __restrict__ lo, int n) {
  int i = (blockIdx.x * 256 + threadIdx.x) * 8;
  if (i >= n) return;
  float4 a = *(const float4*)(in + i);
  float4 b = *(const float4*)(in + i + 4);
  float xs[8] = {a.x, a.y, a.z, a.w, b.x, b.y, b.z, b.w};
  bf16x8 hv, lv;
#pragma unroll
  for (int j = 0; j < 8; ++j) split2(xs[j], hv.v[j], lv.v[j]);
  *(bf16x8*)(hi + i) = hv;
  *(bf16x8*)(lo + i) = lv;
}

// ---------------------------------------------------------------------------
// Transpose+convert fp32 [R][C] -> bf16 [C][R]
// LIFETIME NOTE: launched for w_o -> woT which ALIASES wTl; must run AFTER
// gemm_split2 has consumed wTl (round-6/7 bug: running it at phase 0
// clobbered the low-split weights before the QKV GEMM read them).
// ---------------------------------------------------------------------------
__global__ __launch_bounds__(256) void transpose_cvt(
    const float* __restrict__ in, bf16_t* __restrict__ out, int R, int C) {
  __shared__ bf16_t tile[32][33];
  int c0 = blockIdx.x * 32, r0 = blockIdx.y * 32;
  int tx = threadIdx.x & 31, ty = threadIdx.x >> 5;
#pragma unroll
  for (int i = 0; i < 4; ++i)
    tile[ty + i * 8][tx] = __float2bfloat16(in[(size_t)(r0 + ty + i * 8) * C + c0 + tx]);
  __syncthreads();
#pragma unroll
  for (int i = 0; i < 4; ++i)
    out[(size_t)(c0 + ty + i * 8) * R + r0 + tx] = tile[tx][ty + i * 8];
}

// ---------------------------------------------------------------------------
// Fused transpose+split of [wq|wk|wv] -> wT hi/lo [3072][2048]
// output rows [0,2048) <- wq cols, [2048,2560) <- wk, [2560,3072) <- wv
// ---------------------------------------------------------------------------
__global__ __launch_bounds__(256) void transpose_split_fused(
    const float* __restrict__ wq, const float* __restrict__ wk,
    const float* __restrict__ wv, bf16_t* __restrict__ hiT,
    bf16_t* __restrict__ loT) {
  __shared__ bf16_t th[32][33];
  __shared__ bf16_t tl[32][33];
  int oc = blockIdx.x * 32;   // output row group (input col)
  int r0 = blockIdx.y * 32;   // input row
  const float* src; int C, c0;
  if (oc < 2048)      { src = wq; C = 2048; c0 = oc; }
  else if (oc < 2560) { src = wk; C = 512;  c0 = oc - 2048; }
  else                { src = wv; C = 512;  c0 = oc - 2560; }
  int tx = threadIdx.x & 31, ty = threadIdx.x >> 5;
#pragma unroll
  for (int i = 0; i < 4; ++i) {
    float x = src[(size_t)(r0 + ty + i * 8) * C + c0 + tx];
    bf16_t h, l; split2(x, h, l);
    th[ty + i * 8][tx] = h;
    tl[ty + i * 8][tx] = l;
  }
  __syncthreads();
#pragma unroll
  for (int i = 0; i < 4; ++i) {
    hiT[(size_t)(oc + ty + i * 8) * HDIM + r0 + tx] = th[tx][ty + i * 8];
    loT[(size_t)(oc + ty + i * 8) * HDIM + r0 + tx] = tl[tx][ty + i * 8];
  }
}

// ---------------------------------------------------------------------------
// Shared helpers for pipelined GEMMs
// ---------------------------------------------------------------------------
#define VMCNT_(n) asm volatile("s_waitcnt vmcnt(" #n ")" ::: "memory")
#define VMCNT(n) VMCNT_(n)
#define BARRIER()                     \
  {                                   \
    asm volatile("" ::: "memory");    \
    __builtin_amdgcn_s_barrier();     \
    asm volatile("" ::: "memory");    \
  }

#define MFMA_(a, b, c) __builtin_amdgcn_mfma_f32_16x16x32_bf16(a, b, c, 0, 0, 0)

// ---------------------------------------------------------------------------
// Split-precision GEMM v5: C = Ah*Bh + Ah*Bl + Al*Bh, pipelined.
// BM=256, BN=192, BK=32, 768 threads (12 waves = 3 waves/SIMD), wave tile
// 64x64 (acc 4x4). Staging on waves 0-7 (identical to verified 8-wave
// template); waves 8-11 compute only. Double-buffered LDS (112 KB), ONE
// barrier + one vmcnt(0) per K-step (same sync proof as 8-wave). Per-element
// MFMA order unchanged -> bitwise-identical output. XCD-chunked swizzle.
// (Round-6 version of this was never proven wrong — the failure was the woT
// lifetime bug, which persisted through round 7's gemm revert.)
// ---------------------------------------------------------------------------
#define OFF_AH 0
#define OFF_AL 16384
#define OFF_BH 32768
#define OFF_BL 45056
#define BUFSZ  57344

#define SPLIT_STEP()                                                    \
  {                                                                     \
    fragAB bh[4], bl[4];                                                \
    _Pragma("unroll") for (int j = 0; j < 4; ++j) {                     \
      const char* bp = bufc + (wn + j * 16 + l16) * 64 + rdq;           \
      bh[j] = *(const fragAB*)(bp + OFF_BH);                            \
      bl[j] = *(const fragAB*)(bp + OFF_BL);                            \
    }                                                                   \
    _Pragma("unroll") for (int p = 0; p < 2; ++p) {                     \
      fragAB ah[2], al[2];                                              \
      _Pragma("unroll") for (int u = 0; u < 2; ++u) {                   \
        const char* ap = bufc + (wm + (2 * p + u) * 16 + l16) * 64 + rdq;\
        ah[u] = *(const fragAB*)(ap + OFF_AH);                          \
        al[u] = *(const fragAB*)(ap + OFF_AL);                          \
      }                                                                 \
      __builtin_amdgcn_s_setprio(1);                                    \
      _Pragma("unroll") for (int j = 0; j < 4; ++j)                     \
        _Pragma("unroll") for (int u = 0; u < 2; ++u)                   \
          acc[2 * p + u][j] = MFMA_(al[u], bh[j], acc[2 * p + u][j]);   \
      _Pragma("unroll") for (int j = 0; j < 4; ++j)                     \
        _Pragma("unroll") for (int u = 0; u < 2; ++u)                   \
          acc[2 * p + u][j] = MFMA_(ah[u], bl[j], acc[2 * p + u][j]);   \
      _Pragma("unroll") for (int j = 0; j < 4; ++j)                     \
        _Pragma("unroll") for (int u = 0; u < 2; ++u)                   \
          acc[2 * p + u][j] = MFMA_(ah[u], bh[j], acc[2 * p + u][j]);   \
      __builtin_amdgcn_s_setprio(0);                                    \
    }                                                                   \
  }

__global__ __launch_bounds__(768, 3) void gemm_split2(
    const bf16_t* __restrict__ Ah, const bf16_t* __restrict__ Al,
    const bf16_t* __restrict__ Bh, const bf16_t* __restrict__ Bl,
    float* __restrict__ C, int M, int N, int K) {
  __shared__ __align__(16) char lds[2 * BUFSZ];
  const int t = threadIdx.x;
  const int wave = t >> 6, lane = t & 63;
  const int quad = lane >> 4, l16 = lane & 15;
  // XCD-chunked swizzle (grid 16x16 = 256 = 32/XCD): bijective relabel.
  const int g = blockIdx.y * 16 + blockIdx.x;
  const int lby = (g & 7) * 2 + ((g >> 3) >> 4);
  const int lbx = (g >> 3) & 15;
  const int m0 = lby * 256, n0 = lbx * 192;
  const int wm = (wave / 3) * 64, wn = (wave % 3) * 64;
  // T2 read swizzle: phys 16B-slot of (row r, col-16B q) = q ^ ((r>>1)&3).
  const int rdq = (quad ^ ((l16 >> 1) & 3)) * 16;

  // Per-lane global source offset inside a 16-row x 32-col chunk (inverse swizzle).
  const size_t laneOff =
      (size_t)(lane >> 2) * K * 2 + 16 * ((lane & 3) ^ ((lane >> 3) & 3));

  // 7 staging chunks per wave (waves 0-7 only), identical to 8-wave template.
  const char* gbase[7];
  int ldsOff[7];
  if (wave < 8) {
#pragma unroll
    for (int pos = 0; pos < 3; ++pos) {
      int c = wave + 8 * pos;          // 0..23: Bh chunks 0..11, Bl chunks 0..11
      if (c < 12) {
        gbase[pos]  = (const char*)Bh + (size_t)(n0 + 16 * c) * K * 2;
        ldsOff[pos] = OFF_BH + c * 1024;
      } else {
        gbase[pos]  = (const char*)Bl + (size_t)(n0 + 16 * (c - 12)) * K * 2;
        ldsOff[pos] = OFF_BL + (c - 12) * 1024;
      }
    }
#pragma unroll
    for (int p = 0; p < 4; ++p) {
      int sub = wave & 3;
      int R0 = ((sub >> 1) & 1) * 128 + 32 * p + (sub & 1) * 16;
      const char* base = (const char*)(wave < 4 ? Ah : Al);
      gbase[3 + p]  = base + (size_t)(m0 + R0) * K * 2;
      ldsOff[3 + p] = (wave < 4 ? OFF_AH : OFF_AL) + R0 * 64;
    }
  }

  fragC zero4 = {0.f, 0.f, 0.f, 0.f};
  fragC acc[4][4];
#pragma unroll
  for (int i = 0; i < 4; ++i)
#pragma unroll
    for (int j = 0; j < 4; ++j) acc[i][j] = zero4;

  char* ldsc = (char*)lds;
  // prologue: stage K-step 0 into buffer 0
  if (wave < 8) {
#pragma unroll
    for (int ps = 0; ps < 7; ++ps)
      async_copy16(gbase[ps] + laneOff, ldsc + ldsOff[ps]);
  }

  size_t kk = 64;  // byte offset of next K-step (32 bf16 = 64 B)
  int cur = 0;
  const int NS = K / 32;
  for (int it = 0; it < NS - 1; ++it) {
    const char* bufc = ldsc + cur * BUFSZ;
    char* nb = ldsc + (cur ^ 1) * BUFSZ;
    // drain own loads (issued a full K-step ago -> free) and rendezvous;
    // after the barrier, nb is safe to overwrite.
    VMCNT(0); BARRIER();
    if (wave < 8) {
#pragma unroll
      for (int ps = 0; ps < 7; ++ps)
        async_copy16(gbase[ps] + kk + laneOff, nb + ldsOff[ps]);
    }
    kk += 64;
    SPLIT_STEP();
    cur ^= 1;
  }
  {  // final K-step
    const char* bufc = ldsc + cur * BUFSZ;
    VMCNT(0); BARRIER();
    SPLIT_STEP();
  }

#pragma unroll
  for (int i = 0; i < 4; ++i)
#pragma unroll
    for (int j = 0; j < 4; ++j)
#pragma unroll
      for (int r = 0; r < 4; ++r) {
        int row = m0 + wm + i * 16 + quad * 4 + r;
        int col = n0 + wn + j * 16 + l16;
        C[(size_t)row * N + col] = acc[i][j][r];
      }
}

// ---------------------------------------------------------------------------
// Plain GEMM v3 (output projection): C[M][N] = A[M][K]*Bt[N][K]^T, fp32 out.
// BM=256, BN=128, BK=64, 512 threads (8 waves as 2M x 4N -> wave tile 128x32).
// 1-barrier-per-K-step schedule + XCD-chunked block swizzle.
// ---------------------------------------------------------------------------
#define BT_OFF_A 0
#define BT_OFF_B 32768
#define BT_BUFSZ 49152

struct ARegs2 { fragAB a[2][2]; };  // [row-in-pair][k-slice]

__device__ __forceinline__ void lda_bt(ARegs2& r, const char* bufc, int wm,
                                       int p, int l16, int quad, int rx) {
#pragma unroll
  for (int u = 0; u < 2; ++u)
#pragma unroll
    for (int ks = 0; ks < 2; ++ks)
      r.a[u][ks] = *(const fragAB*)(bufc + BT_OFF_A +
                                    (wm + (2 * p + u) * 16 + l16) * 128 +
                                    (((ks * 4 + quad) ^ rx) * 16));
}

__device__ __forceinline__ void mfma_bt(fragC (&acc)[8][2], const ARegs2& r,
                                        const fragAB (&b)[2][2], int p) {
  __builtin_amdgcn_s_setprio(1);
#pragma unroll
  for (int ks = 0; ks < 2; ++ks)
#pragma unroll
    for (int j = 0; j < 2; ++j) {
      acc[2 * p][j]     = MFMA_(r.a[0][ks], b[j][ks], acc[2 * p][j]);
      acc[2 * p + 1][j] = MFMA_(r.a[1][ks], b[j][ks], acc[2 * p + 1][j]);
    }
  __builtin_amdgcn_s_setprio(0);
}

#define BT_LOADB()                                                        \
  _Pragma("unroll")                                                       \
  for (int j = 0; j < 2; ++j)                                             \
  _Pragma("unroll")                                                       \
    for (int ks = 0; ks < 2; ++ks)                                        \
      bfr[j][ks] = *(const fragAB*)(bufc + BT_OFF_B +                     \
                                    (wn + j * 16 + l16) * 128 +           \
                                    (((ks * 4 + quad) ^ rx) * 16));

#define BT_STEP()                                 \
  {                                               \
    BT_LOADB();                                   \
    lda_bt(r0, bufc, wm, 0, l16, quad, rx);       \
    lda_bt(r1, bufc, wm, 1, l16, quad, rx);       \
    mfma_bt(acc, r0, bfr, 0);                     \
    lda_bt(r0, bufc, wm, 2, l16, quad, rx);       \
    mfma_bt(acc, r1, bfr, 1);                     \
    lda_bt(r1, bufc, wm, 3, l16, quad, rx);       \
    mfma_bt(acc, r0, bfr, 2);                     \
    mfma_bt(acc, r1, bfr, 3);                     \
  }

__global__ __launch_bounds__(512, 2) void gemm_bt2(
    const bf16_t* __restrict__ A, const bf16_t* __restrict__ Bt,
    float* __restrict__ C, int M, int N, int K) {
  __shared__ __align__(16) char lds[2 * BT_BUFSZ];
  const int t = threadIdx.x;
  const int wave = t >> 6, lane = t & 63;
  const int quad = lane >> 4, l16 = lane & 15;
  const int g = blockIdx.y * 16 + blockIdx.x;
  const int lby = (g & 7) * 2 + ((g >> 3) >> 4);
  const int lbx = (g >> 3) & 15;
  const int m0 = lby * 256, n0 = lbx * 128;
  const int wm = (wave >> 2) * 128, wn = (wave & 3) * 32;
  const int rx = l16 & 7;  // row-XOR for 8-slot swizzle (128B rows)

  // chunk = 8 rows x 64 cols (128B rows). lane l stages row l>>3,
  // logical col16 (l&7)^((l>>3)&7) -> LDS phys slot l&7 (inverse swizzle).
  const size_t laneOff =
      (size_t)(lane >> 3) * K * 2 + 16 * ((lane & 7) ^ ((lane >> 3) & 7));

  // 6 staging chunks per wave per K-step: B,B,A0..A3.
  const char* gsrc[6];
  int ldsOff[6];
#pragma unroll
  for (int pos = 0; pos < 2; ++pos) {
    int c = wave + 8 * pos;  // B chunks 0..15, rows [8c,8c+8)
    gsrc[pos]   = (const char*)Bt + (size_t)(n0 + 8 * c) * K * 2 + laneOff;
    ldsOff[pos] = BT_OFF_B + c * 1024;
  }
#pragma unroll
  for (int p = 0; p < 4; ++p) {
    int R0 = (wave >> 2) * 128 + 32 * p + (wave & 3) * 8;
    gsrc[2 + p]   = (const char*)A + (size_t)(m0 + R0) * K * 2 + laneOff;
    ldsOff[2 + p] = BT_OFF_A + R0 * 128;
  }

  fragC zero4 = {0.f, 0.f, 0.f, 0.f};
  fragC acc[8][2];
#pragma unroll
  for (int i = 0; i < 8; ++i)
#pragma unroll
    for (int j = 0; j < 2; ++j) acc[i][j] = zero4;

  char* ldsc = (char*)lds;
#pragma unroll
  for (int ps = 0; ps < 6; ++ps) async_copy16(gsrc[ps], ldsc + ldsOff[ps]);
#pragma unroll
  for (int ps = 0; ps < 6; ++ps) gsrc[ps] += 128;

  fragAB bfr[2][2];
  ARegs2 r0, r1;
  int cur = 0;
  const int NS = K / 64;
  for (int it = 0; it < NS - 1; ++it) {
    const char* bufc = ldsc + cur * BT_BUFSZ;
    char* nb = ldsc + (cur ^ 1) * BT_BUFSZ;
    VMCNT(0); BARRIER();
#pragma unroll
    for (int ps = 0; ps < 6; ++ps) async_copy16(gsrc[ps], nb + ldsOff[ps]);
#pragma unroll
    for (int ps = 0; ps < 6; ++ps) gsrc[ps] += 128;
    BT_STEP();
    cur ^= 1;
  }
  {
    const char* bufc = ldsc + cur * BT_BUFSZ;
    VMCNT(0); BARRIER();
    BT_STEP();
  }

#pragma unroll
  for (int i = 0; i < 8; ++i)
#pragma unroll
    for (int j = 0; j < 2; ++j)
#pragma unroll
      for (int r = 0; r < 4; ++r) {
        int row = m0 + wm + i * 16 + quad * 4 + r;
        int col = n0 + wn + j * 16 + l16;
        C[(size_t)row * N + col] = acc[i][j][r];
      }
}

// ---------------------------------------------------------------------------
// Fused RMS-norm (+fp32 weight) + RoPE for q and k heads, wave-per-(s,head).
// float4 loads, pure-shuffle reduction (no LDS/barriers), rotate_half via
// shfl_xor(·,32) (d = 4*lane+j pairs with (d+128)%256 = lane^32's float4),
// 8B bf16x4 stores. blockIdx.x*4+wave -> idx; s = idx/10, hb = idx%10
// (hb 0..7 = q heads, 8..9 = k heads).
// ---------------------------------------------------------------------------
__global__ __launch_bounds__(256) void rmsnorm_rope_qk2(
    const float* __restrict__ proj, const float* __restrict__ qnw,
    const float* __restrict__ knw, const float* __restrict__ cosb,
    const float* __restrict__ sinb, bf16_t* __restrict__ qhi,
    bf16_t* __restrict__ qlo, bf16_t* __restrict__ khi,
    bf16_t* __restrict__ klo) {
  const int wv = threadIdx.x >> 6, lane = threadIdx.x & 63;
  const int idx = blockIdx.x * 4 + wv;
  const int s = idx / (NHQ + NKVH), hb = idx % (NHQ + NKVH);
  const float* w; bf16_t* oh; bf16_t* ol; int inOff, outStride, oBase;
  if (hb < NHQ) {
    w = qnw; oh = qhi; ol = qlo;
    inOff = hb * DHEAD; outStride = NHQ * DHEAD; oBase = hb * DHEAD;
  } else {
    int hk = hb - NHQ;
    w = knw; oh = khi; ol = klo;
    inOff = NHQ * DHEAD + hk * DHEAD; outStride = NKVH * DHEAD; oBase = hk * DHEAD;
  }
  const int d = lane * 4;
  float4 x = *(const float4*)(proj + (size_t)s * NQKV + inOff + d);
  float ss = x.x * x.x + x.y * x.y + x.z * x.z + x.w * x.w;
  ss += __shfl_xor(ss, 1);  ss += __shfl_xor(ss, 2);  ss += __shfl_xor(ss, 4);
  ss += __shfl_xor(ss, 8);  ss += __shfl_xor(ss, 16); ss += __shfl_xor(ss, 32);
  float r = rsqrtf(ss * (1.0f / DHEAD) + 1e-6f);
  float4 w4 = *(const float4*)(w + d);
  float xn[4] = {x.x * r * w4.x, x.y * r * w4.y, x.z * r * w4.z, x.w * r * w4.w};
  float ot[4];
#pragma unroll
  for (int j = 0; j < 4; ++j) ot[j] = __shfl_xor(xn[j], 32);
  float sgn = (lane < 32) ? -1.0f : 1.0f;
  float4 c4 = *(const float4*)(cosb + (size_t)s * DHEAD + d);
  float4 s4 = *(const float4*)(sinb + (size_t)s * DHEAD + d);
  float cc[4] = {c4.x, c4.y, c4.z, c4.w};
  float sn[4] = {s4.x, s4.y, s4.z, s4.w};
  bf16x4 hv, lv;
#pragma unroll
  for (int j = 0; j < 4; ++j) {
    float y = xn[j] * cc[j] + sgn * ot[j] * sn[j];
    split2(y, hv.v[j], lv.v[j]);
  }
  size_t o = (size_t)s * outStride + oBase + d;
  *(bf16x4*)(oh + o) = hv;
  *(bf16x4*)(ol + o) = lv;
}

// ---------------------------------------------------------------------------
// RMS-norm (no weight) + transposed write [NKV][D][S], fully coalesced.
// ---------------------------------------------------------------------------
__global__ __launch_bounds__(256) void rmsnorm_vT2(
    const float* __restrict__ proj, bf16_t* __restrict__ vt, int inOff) {
  __shared__ float rs_[32];
  __shared__ bf16_t tile[32][33];
  int s0 = blockIdx.x * 32, hh = blockIdx.y;
  const float* base = proj + (size_t)s0 * NQKV + inOff + hh * DHEAD;
  int t = threadIdx.x;
  int sl = t >> 3, c8 = t & 7;
  const float4* rowp = (const float4*)(base + (size_t)sl * NQKV + c8 * 32);
  float ss = 0.f;
#pragma unroll
  for (int i = 0; i < 8; ++i) {
    float4 v = rowp[i];
    ss += v.x * v.x + v.y * v.y + v.z * v.z + v.w * v.w;
  }
  ss += __shfl_xor(ss, 1); ss += __shfl_xor(ss, 2); ss += __shfl_xor(ss, 4);
  if (c8 == 0) rs_[sl] = rsqrtf(ss * (1.0f / DHEAD) + 1e-6f);
  __syncthreads();
  int tx = t & 31, ty = t >> 5;
#pragma unroll
  for (int ch = 0; ch < 8; ++ch) {
#pragma unroll
    for (int i = 0; i < 4; ++i) {
      int s_ = ty + i * 8;
      float x = base[(size_t)s_ * NQKV + ch * 32 + tx];
      tile[s_][tx] = __float2bfloat16(x * rs_[s_]);
    }
    __syncthreads();
#pragma unroll
    for (int i = 0; i < 4; ++i) {
      int dl = ty + i * 8;
      vt[((size_t)hh * DHEAD + ch * 32 + dl) * S_LEN + s0 + tx] = tile[tx][dl];
    }
    __syncthreads();
  }
}

// ---------------------------------------------------------------------------
// Flash attention v4: Q=128, KV=32, dbuf, 1 barrier/step, setprio around
// MFMA clusters, XCD-chunked block swizzle.
// ---------------------------------------------------------------------------
__global__ __launch_bounds__(512, 2) void attn_split(
    const bf16_t* __restrict__ Qhi, const bf16_t* __restrict__ Qlo,
    const bf16_t* __restrict__ Khi, const bf16_t* __restrict__ Klo,
    const bf16_t* __restrict__ Vt, bf16_t* __restrict__ Aout) {
  const int g = blockIdx.y * 32 + blockIdx.x;
  const int lbx = (g & 7) * 4 + ((g >> 3) & 3);
  const int h = g >> 5;
  const int qb = lbx * 128;
  const int wave = threadIdx.x >> 6, lane = threadIdx.x & 63;
  const int quad = lane >> 4, l16 = lane & 15;
  const int qw = qb + wave * 16;
  const int kv = h >> 2;  // G = 4
  const bf16_t* Qh_ = Qhi + h * DHEAD;   // row stride NHQ*DHEAD
  const bf16_t* Ql_ = Qlo + h * DHEAD;
  const bf16_t* Kh_ = Khi + kv * DHEAD;  // row stride NKVH*DHEAD
  const bf16_t* Kl_ = Klo + kv * DHEAD;
  const bf16_t* Vh_ = Vt + (size_t)kv * DHEAD * S_LEN;

  __shared__ __align__(16) bf16_t KshH[2][32 * 256];  // 2x16 KB (keys x d)
  __shared__ __align__(16) bf16_t KshL[2][32 * 256];  // 2x16 KB
  __shared__ __align__(16) bf16_t Vsh[2][256 * 32];   // 2x16 KB (d x keys)
  __shared__ __align__(16) bf16_t Plds[8][16 * 32];   // 8 KB

  fragAB qfh[8], qfl[8];
#pragma unroll
  for (int c = 0; c < 8; ++c) {
    size_t off = (size_t)(qw + l16) * (NHQ * DHEAD) + c * 32 + quad * 8;
    qfh[c] = *(const fragAB*)(Qh_ + off);
    qfl[c] = *(const fragAB*)(Ql_ + off);
  }

  int kRow[2], kCol[2], vRow[2], vCol[2];
#pragma unroll
  for (int i = 0; i < 2; ++i) {
    int ci = i * 512 + threadIdx.x;
    kRow[i] = ci >> 5;
    kCol[i] = ((ci & 31) ^ (kRow[i] & 31)) * 8;
    vRow[i] = ci >> 2;
    vCol[i] = ((ci & 3) ^ (vRow[i] & 3)) * 8;
  }

#define ASTAGE(buf, kb_)                                                     \
  _Pragma("unroll")                                                          \
  for (int i = 0; i < 2; ++i) {                                              \
    size_t dst = (size_t)(i * 512 + threadIdx.x) * 16;                       \
    size_t koff = (size_t)((kb_) + kRow[i]) * (NKVH * DHEAD) + kCol[i];      \
    async_copy16(Kh_ + koff, (char*)KshH[buf] + dst);                        \
    async_copy16(Kl_ + koff, (char*)KshL[buf] + dst);                        \
    async_copy16(Vh_ + (size_t)vRow[i] * S_LEN + (kb_) + vCol[i],            \
                 (char*)Vsh[buf] + dst);                                     \
  }

  fragC zero4 = {0.f, 0.f, 0.f, 0.f};
  fragC o_acc[16];
#pragma unroll
  for (int c = 0; c < 16; ++c) o_acc[c] = zero4;
  float m_run[4] = {NEG_BIG, NEG_BIG, NEG_BIG, NEG_BIG};
  float l_run[4] = {0.f, 0.f, 0.f, 0.f};
  const float LOG2E = 1.4426950408889634f;

  int k_lo = qb - (WIN - 1);
  if (k_lo < 0) k_lo = 0;
  k_lo &= ~31;

  // prologue: stage first KV tile into buffer 0
  ASTAGE(0, k_lo);
  int cur = 0;

  for (int kb = k_lo; kb < qb + 128; kb += 32) {
    VMCNT(0); BARRIER();
    if (kb + 32 < qb + 128) {
      int nbuf = cur ^ 1;
      ASTAGE(nbuf, kb + 32);
    }
    const char* KH = (const char*)KshH[cur];
    const char* KL = (const char*)KshL[cur];
    const char* VB = (const char*)Vsh[cur];

    fragC s[2] = {zero4, zero4};
    __builtin_amdgcn_s_setprio(1);
#pragma unroll
    for (int c = 0; c < 8; ++c) {
      int j = c * 4 + quad;
#pragma unroll
      for (int gg = 0; gg < 2; ++gg) {
        int row = gg * 16 + l16;
        int off = (row * 32 + (j ^ (row & 31))) * 16;
        fragAB kh = *(const fragAB*)(KH + off);
        fragAB kl = *(const fragAB*)(KL + off);
        s[gg] = __builtin_amdgcn_mfma_f32_16x16x32_bf16(qfl[c], kh, s[gg], 0, 0, 0);
        s[gg] = __builtin_amdgcn_mfma_f32_16x16x32_bf16(qfh[c], kl, s[gg], 0, 0, 0);
        s[gg] = __builtin_amdgcn_mfma_f32_16x16x32_bf16(qfh[c], kh, s[gg], 0, 0, 0);
      }
    }
    __builtin_amdgcn_s_setprio(0);

    float p[2][4], alpha[4];
#pragma unroll
    for (int r = 0; r < 4; ++r) {
      int qi = qw + quad * 4 + r;
      bool vld[2];
      float mx = NEG_BIG;
#pragma unroll
      for (int gg = 0; gg < 2; ++gg) {
        int ki = kb + gg * 16 + l16;
        vld[gg] = (ki <= qi) && (qi - ki < WIN);
        mx = fmaxf(mx, vld[gg] ? s[gg][r] : NEG_BIG);
      }
      mx = fmaxf(mx, __shfl_xor(mx, 1));
      mx = fmaxf(mx, __shfl_xor(mx, 2));
      mx = fmaxf(mx, __shfl_xor(mx, 4));
      mx = fmaxf(mx, __shfl_xor(mx, 8));
      float mn = fmaxf(m_run[r], mx);
      float a  = exp2f(fmaxf(m_run[r] - mn, -80.f) * LOG2E);
      float rs = 0.f;
#pragma unroll
      for (int gg = 0; gg < 2; ++gg) {
        float e = vld[gg] ? exp2f(fmaxf(s[gg][r] - mn, -80.f) * LOG2E) : 0.f;
        p[gg][r] = e;
        rs += e;
      }
      rs += __shfl_xor(rs, 1);
      rs += __shfl_xor(rs, 2);
      rs += __shfl_xor(rs, 4);
      rs += __shfl_xor(rs, 8);
      l_run[r] = l_run[r] * a + rs;
      m_run[r] = mn;
      alpha[r] = a;
    }
#pragma unroll
    for (int c = 0; c < 16; ++c)
#pragma unroll
      for (int r = 0; r < 4; ++r) o_acc[c][r] *= alpha[r];

    bf16_t* Pw = Plds[wave];
#pragma unroll
    for (int r = 0; r < 4; ++r)
#pragma unroll
      for (int gg = 0; gg < 2; ++gg)
        Pw[(quad * 4 + r) * 32 + gg * 16 + l16] = __float2bfloat16(p[gg][r]);
    fragAB pf = *(const fragAB*)((const char*)Pw + l16 * 64 + quad * 16);

    __builtin_amdgcn_s_setprio(1);
#pragma unroll
    for (int c = 0; c < 16; ++c) {
      int d = c * 16 + l16;
      int offv = (d * 4 + (quad ^ (d & 3))) * 16;
      fragAB vf = *(const fragAB*)(VB + offv);
      o_acc[c] = __builtin_amdgcn_mfma_f32_16x16x32_bf16(pf, vf, o_acc[c], 0, 0, 0);
    }
    __builtin_amdgcn_s_setprio(0);
    cur ^= 1;
  }

  float inv_l[4];
#pragma unroll
  for (int r = 0; r < 4; ++r) inv_l[r] = 1.0f / l_run[r];
#pragma unroll
  for (int c = 0; c < 16; ++c)
#pragma unroll
    for (int r = 0; r < 4; ++r) {
      int row = qw + quad * 4 + r;
      int col = h * DHEAD + c * 16 + l16;
      Aout[(size_t)row * (NHQ * DHEAD) + col] = __float2bfloat16(o_acc[c][r] * inv_l[r]);
    }
#undef ASTAGE
}

// ---------------------------------------------------------------------------
extern "C" void kernel_launch(void* const* d_in, const int* in_sizes, int n_in,
                              void* d_out, int out_size, void* d_ws, size_t ws_size,
                              hipStream_t stream) {
  const float* hid  = (const float*)d_in[0];
  const float* w_q  = (const float*)d_in[1];
  const float* w_k  = (const float*)d_in[2];
  const float* w_v  = (const float*)d_in[3];
  const float* w_o  = (const float*)d_in[4];
  const float* qnw  = (const float*)d_in[5];
  const float* knw  = (const float*)d_in[6];
  const float* cosb = (const float*)d_in[7];
  const float* sinb = (const float*)d_in[8];
  float* outp = (float*)d_out;

  // Workspace (bf16 slots, M1 = 1<<20), peak 52M slots = 104 MiB:
  //  [ 0: 8M)  hidh  -> qh  (after qkv gemm)
  //  [ 8:16M)  hidl  -> ql
  //  [16:22M)  wTh (3072x2048) -> kh[16:18M), kl[18:20M), vt[20:22M) after gemm
  //  [22:28M)  wTl   -> woT[22:26M) after gemm  (LIFETIME: woT writes must
  //            come AFTER gemm_split2 — rounds 6/7 bug wrote it at phase 0)
  //  [28:52M)  projqkv f32 (4096x3072) -> aout[28:36M) after norms
  const size_t M1 = 1048576;
  bf16_t* w = (bf16_t*)d_ws;
  bf16_t* hidh  = w;
  bf16_t* qh    = w;                         // alias hidh
  bf16_t* hidl  = w + 8 * M1;
  bf16_t* ql    = w + 8 * M1;                // alias hidl
  bf16_t* wTh   = w + 16 * M1;
  bf16_t* kh    = w + 16 * M1;               // alias wTh
  bf16_t* kl    = w + 18 * M1;
  bf16_t* vt    = w + 20 * M1;
  bf16_t* wTl   = w + 22 * M1;
  bf16_t* woT   = w + 22 * M1;               // alias wTl
  float*  projqkv = (float*)(w + 28 * M1);
  bf16_t* aout  = w + 28 * M1;               // alias projqkv (after norms)

  // phase 0: split hidden; fused split-transpose [wq|wk|wv] -> wT [3072][2048]
  split_f32<<<(S_LEN * HDIM) / 2048, 256, 0, stream>>>(hid, hidh, hidl, S_LEN * HDIM);
  transpose_split_fused<<<dim3(NQKV / 32, HDIM / 32), 256, 0, stream>>>(
      w_q, w_k, w_v, wTh, wTl);

  // phase 1: fused q+k+v split projection, pipelined 256x192 tiles
  //          grid 16x16 = 256 blocks = exactly 1 per CU, 12 waves (3/SIMD)
  gemm_split2<<<dim3(NQKV / 192, S_LEN / 256), 768, 0, stream>>>(
      hidh, hidl, wTh, wTl, projqkv, S_LEN, NQKV, HDIM);

  // phase 2: norms (hid/wT dead -> qh/ql/kh/kl/vt targets), q+k fused;
  //          w_o transpose into dead wTl region (AFTER gemm_split2!)
  rmsnorm_rope_qk2<<<(S_LEN * (NHQ + NKVH)) / 4, 256, 0, stream>>>(
      projqkv, qnw, knw, cosb, sinb, qh, ql, kh, kl);
  rmsnorm_vT2<<<dim3(S_LEN / 32, NKVH), 256, 0, stream>>>(
      projqkv, vt, NHQ * DHEAD + NKVH * DHEAD);
  transpose_cvt<<<dim3(HDIM / 32, (NHQ * DHEAD) / 32), 256, 0, stream>>>(
      w_o, woT, NHQ * DHEAD, HDIM);

  // phase 3: attention -> aout (dead projqkv region)
  //          grid 32x8 = 256 blocks = exactly 1 per CU
  attn_split<<<dim3(S_LEN / 128, NHQ), 512, 0, stream>>>(qh, ql, kh, kl, vt, aout);

  // phase 4: output projection -> fp32 d_out, pipelined 256x128 tiles
  gemm_bt2<<<dim3(HDIM / 128, S_LEN / 256), 512, 0, stream>>>(
      aout, woT, outp, S_LEN, HDIM, NHQ * DHEAD);
}

// Round 10
// 381.940 us; speedup vs baseline: 1.3773x; 1.0455x over previous
//
#include <hip/hip_runtime.h>
#include <hip/hip_bf16.h>

#define S_LEN 4096
#define HDIM  2048
#define NHQ   8
#define NKVH  2
#define DHEAD 256
#define WIN   512
#define NQKV  3072   // fused q+k+v projection width (2048 + 512 + 512)

typedef __hip_bfloat16 bf16_t;
using fragAB = __attribute__((ext_vector_type(8))) short;  // 8 bf16
using fragC  = __attribute__((ext_vector_type(4))) float;  // 4 fp32

struct __align__(8)  bf16x4 { bf16_t v[4]; };
struct __align__(16) bf16x8 { bf16_t v[8]; };

typedef unsigned int u32;
typedef const __attribute__((address_space(1))) u32* gas_ptr;
typedef __attribute__((address_space(3))) u32* las_ptr;

__device__ __forceinline__ void async_copy16(const void* g, void* l) {
  __builtin_amdgcn_global_load_lds((gas_ptr)g, (las_ptr)l, 16, 0, 0);
}

#define NEG_BIG (-3.0e38f)

__device__ __forceinline__ void split2(float x, bf16_t& hi, bf16_t& lo) {
  bf16_t h = __float2bfloat16(x);
  hi = h;
  lo = __float2bfloat16(x - (float)h);
}

// ---------------------------------------------------------------------------
// prep0: fused phase-0 prep (one dispatch instead of two).
//  blockIdx.x <  4096 : split hidden fp32 -> bf16 hi/lo (8 elem/thread, 16B st)
//  blockIdx.x >= 4096 : transpose+split [wq|wk|wv] -> wT hi/lo [3072][2048]
// ---------------------------------------------------------------------------
__global__ __launch_bounds__(256) void prep0(
    const float* __restrict__ hid, bf16_t* __restrict__ hidh,
    bf16_t* __restrict__ hidl, const float* __restrict__ wq,
    const float* __restrict__ wk, const float* __restrict__ wv,
    bf16_t* __restrict__ hiT, bf16_t* __restrict__ loT) {
  __shared__ bf16_t th[32][33];
  __shared__ bf16_t tl[32][33];
  int bx = blockIdx.x;
  if (bx < 4096) {
    int i = (bx * 256 + threadIdx.x) * 8;
    float4 a = *(const float4*)(hid + i);
    float4 b = *(const float4*)(hid + i + 4);
    float xs[8] = {a.x, a.y, a.z, a.w, b.x, b.y, b.z, b.w};
    bf16x8 hv, lv;
#pragma unroll
    for (int j = 0; j < 8; ++j) split2(xs[j], hv.v[j], lv.v[j]);
    *(bf16x8*)(hidh + i) = hv;
    *(bf16x8*)(hidl + i) = lv;
  } else {
    int b2 = bx - 4096;
    int oc = (b2 % 96) * 32;   // output row group (input col)
    int r0 = (b2 / 96) * 32;   // input row
    const float* src; int C, c0;
    if (oc < 2048)      { src = wq; C = 2048; c0 = oc; }
    else if (oc < 2560) { src = wk; C = 512;  c0 = oc - 2048; }
    else                { src = wv; C = 512;  c0 = oc - 2560; }
    int tx = threadIdx.x & 31, ty = threadIdx.x >> 5;
#pragma unroll
    for (int i = 0; i < 4; ++i) {
      float x = src[(size_t)(r0 + ty + i * 8) * C + c0 + tx];
      bf16_t h, l; split2(x, h, l);
      th[ty + i * 8][tx] = h;
      tl[ty + i * 8][tx] = l;
    }
    __syncthreads();
#pragma unroll
    for (int i = 0; i < 4; ++i) {
      hiT[(size_t)(oc + ty + i * 8) * HDIM + r0 + tx] = th[tx][ty + i * 8];
      loT[(size_t)(oc + ty + i * 8) * HDIM + r0 + tx] = tl[tx][ty + i * 8];
    }
  }
}

// ---------------------------------------------------------------------------
// Shared helpers for pipelined GEMMs
// ---------------------------------------------------------------------------
#define VMCNT_(n) asm volatile("s_waitcnt vmcnt(" #n ")" ::: "memory")
#define VMCNT(n) VMCNT_(n)
#define BARRIER()                     \
  {                                   \
    asm volatile("" ::: "memory");    \
    __builtin_amdgcn_s_barrier();     \
    asm volatile("" ::: "memory");    \
  }

#define MFMA_(a, b, c) __builtin_amdgcn_mfma_f32_16x16x32_bf16(a, b, c, 0, 0, 0)

// ---------------------------------------------------------------------------
// Split-precision GEMM v5: C = Ah*Bh + Ah*Bl + Al*Bh, pipelined.
// BM=256, BN=192, BK=32, 768 threads (12 waves = 3 waves/SIMD), wave tile
// 64x64 (acc 4x4 in AGPR). Staging on waves 0-7; waves 8-11 compute only.
// Double-buffered LDS (112 KB), ONE barrier + one vmcnt(0) per K-step.
// XCD-chunked swizzle. Verified round 9: 117.5 us, MfmaUtil 59%.
// ---------------------------------------------------------------------------
#define OFF_AH 0
#define OFF_AL 16384
#define OFF_BH 32768
#define OFF_BL 45056
#define BUFSZ  57344

#define SPLIT_STEP()                                                    \
  {                                                                     \
    fragAB bh[4], bl[4];                                                \
    _Pragma("unroll") for (int j = 0; j < 4; ++j) {                     \
      const char* bp = bufc + (wn + j * 16 + l16) * 64 + rdq;           \
      bh[j] = *(const fragAB*)(bp + OFF_BH);                            \
      bl[j] = *(const fragAB*)(bp + OFF_BL);                            \
    }                                                                   \
    _Pragma("unroll") for (int p = 0; p < 2; ++p) {                     \
      fragAB ah[2], al[2];                                              \
      _Pragma("unroll") for (int u = 0; u < 2; ++u) {                   \
        const char* ap = bufc + (wm + (2 * p + u) * 16 + l16) * 64 + rdq;\
        ah[u] = *(const fragAB*)(ap + OFF_AH);                          \
        al[u] = *(const fragAB*)(ap + OFF_AL);                          \
      }                                                                 \
      __builtin_amdgcn_s_setprio(1);                                    \
      _Pragma("unroll") for (int j = 0; j < 4; ++j)                     \
        _Pragma("unroll") for (int u = 0; u < 2; ++u)                   \
          acc[2 * p + u][j] = MFMA_(al[u], bh[j], acc[2 * p + u][j]);   \
      _Pragma("unroll") for (int j = 0; j < 4; ++j)                     \
        _Pragma("unroll") for (int u = 0; u < 2; ++u)                   \
          acc[2 * p + u][j] = MFMA_(ah[u], bl[j], acc[2 * p + u][j]);   \
      _Pragma("unroll") for (int j = 0; j < 4; ++j)                     \
        _Pragma("unroll") for (int u = 0; u < 2; ++u)                   \
          acc[2 * p + u][j] = MFMA_(ah[u], bh[j], acc[2 * p + u][j]);   \
      __builtin_amdgcn_s_setprio(0);                                    \
    }                                                                   \
  }

__global__ __launch_bounds__(768, 3) void gemm_split2(
    const bf16_t* __restrict__ Ah, const bf16_t* __restrict__ Al,
    const bf16_t* __restrict__ Bh, const bf16_t* __restrict__ Bl,
    float* __restrict__ C, int M, int N, int K) {
  __shared__ __align__(16) char lds[2 * BUFSZ];
  const int t = threadIdx.x;
  const int wave = t >> 6, lane = t & 63;
  const int quad = lane >> 4, l16 = lane & 15;
  // XCD-chunked swizzle (grid 16x16 = 256 = 32/XCD): bijective relabel.
  const int g = blockIdx.y * 16 + blockIdx.x;
  const int lby = (g & 7) * 2 + ((g >> 3) >> 4);
  const int lbx = (g >> 3) & 15;
  const int m0 = lby * 256, n0 = lbx * 192;
  const int wm = (wave / 3) * 64, wn = (wave % 3) * 64;
  // T2 read swizzle: phys 16B-slot of (row r, col-16B q) = q ^ ((r>>1)&3).
  const int rdq = (quad ^ ((l16 >> 1) & 3)) * 16;

  // Per-lane global source offset inside a 16-row x 32-col chunk (inverse swizzle).
  const size_t laneOff =
      (size_t)(lane >> 2) * K * 2 + 16 * ((lane & 3) ^ ((lane >> 3) & 3));

  // 7 staging chunks per wave (waves 0-7 only), identical to 8-wave template.
  const char* gbase[7];
  int ldsOff[7];
  if (wave < 8) {
#pragma unroll
    for (int pos = 0; pos < 3; ++pos) {
      int c = wave + 8 * pos;          // 0..23: Bh chunks 0..11, Bl chunks 0..11
      if (c < 12) {
        gbase[pos]  = (const char*)Bh + (size_t)(n0 + 16 * c) * K * 2;
        ldsOff[pos] = OFF_BH + c * 1024;
      } else {
        gbase[pos]  = (const char*)Bl + (size_t)(n0 + 16 * (c - 12)) * K * 2;
        ldsOff[pos] = OFF_BL + (c - 12) * 1024;
      }
    }
#pragma unroll
    for (int p = 0; p < 4; ++p) {
      int sub = wave & 3;
      int R0 = ((sub >> 1) & 1) * 128 + 32 * p + (sub & 1) * 16;
      const char* base = (const char*)(wave < 4 ? Ah : Al);
      gbase[3 + p]  = base + (size_t)(m0 + R0) * K * 2;
      ldsOff[3 + p] = (wave < 4 ? OFF_AH : OFF_AL) + R0 * 64;
    }
  }

  fragC zero4 = {0.f, 0.f, 0.f, 0.f};
  fragC acc[4][4];
#pragma unroll
  for (int i = 0; i < 4; ++i)
#pragma unroll
    for (int j = 0; j < 4; ++j) acc[i][j] = zero4;

  char* ldsc = (char*)lds;
  // prologue: stage K-step 0 into buffer 0
  if (wave < 8) {
#pragma unroll
    for (int ps = 0; ps < 7; ++ps)
      async_copy16(gbase[ps] + laneOff, ldsc + ldsOff[ps]);
  }

  size_t kk = 64;  // byte offset of next K-step (32 bf16 = 64 B)
  int cur = 0;
  const int NS = K / 32;
  for (int it = 0; it < NS - 1; ++it) {
    const char* bufc = ldsc + cur * BUFSZ;
    char* nb = ldsc + (cur ^ 1) * BUFSZ;
    // drain own loads (issued a full K-step ago -> free) and rendezvous;
    // after the barrier, nb is safe to overwrite.
    VMCNT(0); BARRIER();
    if (wave < 8) {
#pragma unroll
      for (int ps = 0; ps < 7; ++ps)
        async_copy16(gbase[ps] + kk + laneOff, nb + ldsOff[ps]);
    }
    kk += 64;
    SPLIT_STEP();
    cur ^= 1;
  }
  {  // final K-step
    const char* bufc = ldsc + cur * BUFSZ;
    VMCNT(0); BARRIER();
    SPLIT_STEP();
  }

#pragma unroll
  for (int i = 0; i < 4; ++i)
#pragma unroll
    for (int j = 0; j < 4; ++j)
#pragma unroll
      for (int r = 0; r < 4; ++r) {
        int row = m0 + wm + i * 16 + quad * 4 + r;
        int col = n0 + wn + j * 16 + l16;
        C[(size_t)row * N + col] = acc[i][j][r];
      }
}

// ---------------------------------------------------------------------------
// Plain GEMM v3 (output projection): C[M][N] = A[M][K]*Bt[N][K]^T, fp32 out.
// BM=256, BN=128, BK=64, 512 threads (8 waves as 2M x 4N -> wave tile 128x32).
// 1-barrier-per-K-step schedule + XCD-chunked block swizzle.
// ---------------------------------------------------------------------------
#define BT_OFF_A 0
#define BT_OFF_B 32768
#define BT_BUFSZ 49152

struct ARegs2 { fragAB a[2][2]; };  // [row-in-pair][k-slice]

__device__ __forceinline__ void lda_bt(ARegs2& r, const char* bufc, int wm,
                                       int p, int l16, int quad, int rx) {
#pragma unroll
  for (int u = 0; u < 2; ++u)
#pragma unroll
    for (int ks = 0; ks < 2; ++ks)
      r.a[u][ks] = *(const fragAB*)(bufc + BT_OFF_A +
                                    (wm + (2 * p + u) * 16 + l16) * 128 +
                                    (((ks * 4 + quad) ^ rx) * 16));
}

__device__ __forceinline__ void mfma_bt(fragC (&acc)[8][2], const ARegs2& r,
                                        const fragAB (&b)[2][2], int p) {
  __builtin_amdgcn_s_setprio(1);
#pragma unroll
  for (int ks = 0; ks < 2; ++ks)
#pragma unroll
    for (int j = 0; j < 2; ++j) {
      acc[2 * p][j]     = MFMA_(r.a[0][ks], b[j][ks], acc[2 * p][j]);
      acc[2 * p + 1][j] = MFMA_(r.a[1][ks], b[j][ks], acc[2 * p + 1][j]);
    }
  __builtin_amdgcn_s_setprio(0);
}

#define BT_LOADB()                                                        \
  _Pragma("unroll")                                                       \
  for (int j = 0; j < 2; ++j)                                             \
  _Pragma("unroll")                                                       \
    for (int ks = 0; ks < 2; ++ks)                                        \
      bfr[j][ks] = *(const fragAB*)(bufc + BT_OFF_B +                     \
                                    (wn + j * 16 + l16) * 128 +           \
                                    (((ks * 4 + quad) ^ rx) * 16));

#define BT_STEP()                                 \
  {                                               \
    BT_LOADB();                                   \
    lda_bt(r0, bufc, wm, 0, l16, quad, rx);       \
    lda_bt(r1, bufc, wm, 1, l16, quad, rx);       \
    mfma_bt(acc, r0, bfr, 0);                     \
    lda_bt(r0, bufc, wm, 2, l16, quad, rx);       \
    mfma_bt(acc, r1, bfr, 1);                     \
    lda_bt(r1, bufc, wm, 3, l16, quad, rx);       \
    mfma_bt(acc, r0, bfr, 2);                     \
    mfma_bt(acc, r1, bfr, 3);                     \
  }

__global__ __launch_bounds__(512, 2) void gemm_bt2(
    const bf16_t* __restrict__ A, const bf16_t* __restrict__ Bt,
    float* __restrict__ C, int M, int N, int K) {
  __shared__ __align__(16) char lds[2 * BT_BUFSZ];
  const int t = threadIdx.x;
  const int wave = t >> 6, lane = t & 63;
  const int quad = lane >> 4, l16 = lane & 15;
  const int g = blockIdx.y * 16 + blockIdx.x;
  const int lby = (g & 7) * 2 + ((g >> 3) >> 4);
  const int lbx = (g >> 3) & 15;
  const int m0 = lby * 256, n0 = lbx * 128;
  const int wm = (wave >> 2) * 128, wn = (wave & 3) * 32;
  const int rx = l16 & 7;  // row-XOR for 8-slot swizzle (128B rows)

  // chunk = 8 rows x 64 cols (128B rows). lane l stages row l>>3,
  // logical col16 (l&7)^((l>>3)&7) -> LDS phys slot l&7 (inverse swizzle).
  const size_t laneOff =
      (size_t)(lane >> 3) * K * 2 + 16 * ((lane & 7) ^ ((lane >> 3) & 7));

  // 6 staging chunks per wave per K-step: B,B,A0..A3.
  const char* gsrc[6];
  int ldsOff[6];
#pragma unroll
  for (int pos = 0; pos < 2; ++pos) {
    int c = wave + 8 * pos;  // B chunks 0..15, rows [8c,8c+8)
    gsrc[pos]   = (const char*)Bt + (size_t)(n0 + 8 * c) * K * 2 + laneOff;
    ldsOff[pos] = BT_OFF_B + c * 1024;
  }
#pragma unroll
  for (int p = 0; p < 4; ++p) {
    int R0 = (wave >> 2) * 128 + 32 * p + (wave & 3) * 8;
    gsrc[2 + p]   = (const char*)A + (size_t)(m0 + R0) * K * 2 + laneOff;
    ldsOff[2 + p] = BT_OFF_A + R0 * 128;
  }

  fragC zero4 = {0.f, 0.f, 0.f, 0.f};
  fragC acc[8][2];
#pragma unroll
  for (int i = 0; i < 8; ++i)
#pragma unroll
    for (int j = 0; j < 2; ++j) acc[i][j] = zero4;

  char* ldsc = (char*)lds;
#pragma unroll
  for (int ps = 0; ps < 6; ++ps) async_copy16(gsrc[ps], ldsc + ldsOff[ps]);
#pragma unroll
  for (int ps = 0; ps < 6; ++ps) gsrc[ps] += 128;

  fragAB bfr[2][2];
  ARegs2 r0, r1;
  int cur = 0;
  const int NS = K / 64;
  for (int it = 0; it < NS - 1; ++it) {
    const char* bufc = ldsc + cur * BT_BUFSZ;
    char* nb = ldsc + (cur ^ 1) * BT_BUFSZ;
    VMCNT(0); BARRIER();
#pragma unroll
    for (int ps = 0; ps < 6; ++ps) async_copy16(gsrc[ps], nb + ldsOff[ps]);
#pragma unroll
    for (int ps = 0; ps < 6; ++ps) gsrc[ps] += 128;
    BT_STEP();
    cur ^= 1;
  }
  {
    const char* bufc = ldsc + cur * BT_BUFSZ;
    VMCNT(0); BARRIER();
    BT_STEP();
  }

#pragma unroll
  for (int i = 0; i < 8; ++i)
#pragma unroll
    for (int j = 0; j < 2; ++j)
#pragma unroll
      for (int r = 0; r < 4; ++r) {
        int row = m0 + wm + i * 16 + quad * 4 + r;
        int col = n0 + wn + j * 16 + l16;
        C[(size_t)row * N + col] = acc[i][j][r];
      }
}

// ---------------------------------------------------------------------------
// prep2: fused phase-2 norms + w_o transpose (one dispatch instead of three).
//  bx <  10240         : RMS-norm+RoPE q/k, wave-per-(s,head), split output
//  10240 <= bx < 10496 : RMS-norm v + transposed write [NKV][D][S]
//  bx >= 10496         : transpose+convert w_o -> woT  (woT ALIASES wTl;
//                        this kernel runs AFTER gemm_split2 -- lifetime OK)
// ---------------------------------------------------------------------------
__global__ __launch_bounds__(256) void prep2(
    const float* __restrict__ proj, const float* __restrict__ qnw,
    const float* __restrict__ knw, const float* __restrict__ cosb,
    const float* __restrict__ sinb, bf16_t* __restrict__ qhi,
    bf16_t* __restrict__ qlo, bf16_t* __restrict__ khi,
    bf16_t* __restrict__ klo, bf16_t* __restrict__ vt,
    const float* __restrict__ wo, bf16_t* __restrict__ woT) {
  __shared__ float rs_[32];
  __shared__ bf16_t tile[32][33];
  int bx = blockIdx.x;
  if (bx < 10240) {
    // ---- RMS-norm + RoPE for q/k heads (wave-per-(s,head)) ----
    const int wv = threadIdx.x >> 6, lane = threadIdx.x & 63;
    const int idx = bx * 4 + wv;
    const int s = idx / (NHQ + NKVH), hb = idx % (NHQ + NKVH);
    const float* w; bf16_t* oh; bf16_t* ol; int inOff, outStride, oBase;
    if (hb < NHQ) {
      w = qnw; oh = qhi; ol = qlo;
      inOff = hb * DHEAD; outStride = NHQ * DHEAD; oBase = hb * DHEAD;
    } else {
      int hk = hb - NHQ;
      w = knw; oh = khi; ol = klo;
      inOff = NHQ * DHEAD + hk * DHEAD; outStride = NKVH * DHEAD; oBase = hk * DHEAD;
    }
    const int d = lane * 4;
    float4 x = *(const float4*)(proj + (size_t)s * NQKV + inOff + d);
    float ss = x.x * x.x + x.y * x.y + x.z * x.z + x.w * x.w;
    ss += __shfl_xor(ss, 1);  ss += __shfl_xor(ss, 2);  ss += __shfl_xor(ss, 4);
    ss += __shfl_xor(ss, 8);  ss += __shfl_xor(ss, 16); ss += __shfl_xor(ss, 32);
    float r = rsqrtf(ss * (1.0f / DHEAD) + 1e-6f);
    float4 w4 = *(const float4*)(w + d);
    float xn[4] = {x.x * r * w4.x, x.y * r * w4.y, x.z * r * w4.z, x.w * r * w4.w};
    float ot[4];
#pragma unroll
    for (int j = 0; j < 4; ++j) ot[j] = __shfl_xor(xn[j], 32);
    float sgn = (lane < 32) ? -1.0f : 1.0f;
    float4 c4 = *(const float4*)(cosb + (size_t)s * DHEAD + d);
    float4 s4 = *(const float4*)(sinb + (size_t)s * DHEAD + d);
    float cc[4] = {c4.x, c4.y, c4.z, c4.w};
    float sn[4] = {s4.x, s4.y, s4.z, s4.w};
    bf16x4 hv, lv;
#pragma unroll
    for (int j = 0; j < 4; ++j) {
      float y = xn[j] * cc[j] + sgn * ot[j] * sn[j];
      split2(y, hv.v[j], lv.v[j]);
    }
    size_t o = (size_t)s * outStride + oBase + d;
    *(bf16x4*)(oh + o) = hv;
    *(bf16x4*)(ol + o) = lv;
  } else if (bx < 10240 + 256) {
    // ---- RMS-norm v (no weight) + transposed write [NKV][D][S] ----
    int b2 = bx - 10240;
    int s0 = (b2 & 127) * 32, hh = b2 >> 7;
    const int inOff = NHQ * DHEAD + NKVH * DHEAD;
    const float* base = proj + (size_t)s0 * NQKV + inOff + hh * DHEAD;
    int t = threadIdx.x;
    int sl = t >> 3, c8 = t & 7;
    const float4* rowp = (const float4*)(base + (size_t)sl * NQKV + c8 * 32);
    float ss = 0.f;
#pragma unroll
    for (int i = 0; i < 8; ++i) {
      float4 v = rowp[i];
      ss += v.x * v.x + v.y * v.y + v.z * v.z + v.w * v.w;
    }
    ss += __shfl_xor(ss, 1); ss += __shfl_xor(ss, 2); ss += __shfl_xor(ss, 4);
    if (c8 == 0) rs_[sl] = rsqrtf(ss * (1.0f / DHEAD) + 1e-6f);
    __syncthreads();
    int tx = t & 31, ty = t >> 5;
#pragma unroll
    for (int ch = 0; ch < 8; ++ch) {
#pragma unroll
      for (int i = 0; i < 4; ++i) {
        int s_ = ty + i * 8;
        float x = base[(size_t)s_ * NQKV + ch * 32 + tx];
        tile[s_][tx] = __float2bfloat16(x * rs_[s_]);
      }
      __syncthreads();
#pragma unroll
      for (int i = 0; i < 4; ++i) {
        int dl = ty + i * 8;
        vt[((size_t)hh * DHEAD + ch * 32 + dl) * S_LEN + s0 + tx] = tile[tx][dl];
      }
      __syncthreads();
    }
  } else {
    // ---- transpose+convert w_o [2048][2048] -> woT ----
    int b2 = bx - 10496;
    int c0 = (b2 & 63) * 32, r0 = (b2 >> 6) * 32;
    int tx = threadIdx.x & 31, ty = threadIdx.x >> 5;
#pragma unroll
    for (int i = 0; i < 4; ++i)
      tile[ty + i * 8][tx] =
          __float2bfloat16(wo[(size_t)(r0 + ty + i * 8) * HDIM + c0 + tx]);
    __syncthreads();
#pragma unroll
    for (int i = 0; i < 4; ++i)
      woT[(size_t)(c0 + ty + i * 8) * (NHQ * DHEAD) + r0 + tx] = tile[tx][ty + i * 8];
  }
}

// ---------------------------------------------------------------------------
// Flash attention v4: Q=128, KV=32, dbuf, 1 barrier/step, setprio around
// MFMA clusters, XCD-chunked block swizzle.
// ---------------------------------------------------------------------------
__global__ __launch_bounds__(512, 2) void attn_split(
    const bf16_t* __restrict__ Qhi, const bf16_t* __restrict__ Qlo,
    const bf16_t* __restrict__ Khi, const bf16_t* __restrict__ Klo,
    const bf16_t* __restrict__ Vt, bf16_t* __restrict__ Aout) {
  const int g = blockIdx.y * 32 + blockIdx.x;
  const int lbx = (g & 7) * 4 + ((g >> 3) & 3);
  const int h = g >> 5;
  const int qb = lbx * 128;
  const int wave = threadIdx.x >> 6, lane = threadIdx.x & 63;
  const int quad = lane >> 4, l16 = lane & 15;
  const int qw = qb + wave * 16;
  const int kv = h >> 2;  // G = 4
  const bf16_t* Qh_ = Qhi + h * DHEAD;   // row stride NHQ*DHEAD
  const bf16_t* Ql_ = Qlo + h * DHEAD;
  const bf16_t* Kh_ = Khi + kv * DHEAD;  // row stride NKVH*DHEAD
  const bf16_t* Kl_ = Klo + kv * DHEAD;
  const bf16_t* Vh_ = Vt + (size_t)kv * DHEAD * S_LEN;

  __shared__ __align__(16) bf16_t KshH[2][32 * 256];  // 2x16 KB (keys x d)
  __shared__ __align__(16) bf16_t KshL[2][32 * 256];  // 2x16 KB
  __shared__ __align__(16) bf16_t Vsh[2][256 * 32];   // 2x16 KB (d x keys)
  __shared__ __align__(16) bf16_t Plds[8][16 * 32];   // 8 KB

  fragAB qfh[8], qfl[8];
#pragma unroll
  for (int c = 0; c < 8; ++c) {
    size_t off = (size_t)(qw + l16) * (NHQ * DHEAD) + c * 32 + quad * 8;
    qfh[c] = *(const fragAB*)(Qh_ + off);
    qfl[c] = *(const fragAB*)(Ql_ + off);
  }

  int kRow[2], kCol[2], vRow[2], vCol[2];
#pragma unroll
  for (int i = 0; i < 2; ++i) {
    int ci = i * 512 + threadIdx.x;
    kRow[i] = ci >> 5;
    kCol[i] = ((ci & 31) ^ (kRow[i] & 31)) * 8;
    vRow[i] = ci >> 2;
    vCol[i] = ((ci & 3) ^ (vRow[i] & 3)) * 8;
  }

#define ASTAGE(buf, kb_)                                                     \
  _Pragma("unroll")                                                          \
  for (int i = 0; i < 2; ++i) {                                              \
    size_t dst = (size_t)(i * 512 + threadIdx.x) * 16;                       \
    size_t koff = (size_t)((kb_) + kRow[i]) * (NKVH * DHEAD) + kCol[i];      \
    async_copy16(Kh_ + koff, (char*)KshH[buf] + dst);                        \
    async_copy16(Kl_ + koff, (char*)KshL[buf] + dst);                        \
    async_copy16(Vh_ + (size_t)vRow[i] * S_LEN + (kb_) + vCol[i],            \
                 (char*)Vsh[buf] + dst);                                     \
  }

  fragC zero4 = {0.f, 0.f, 0.f, 0.f};
  fragC o_acc[16];
#pragma unroll
  for (int c = 0; c < 16; ++c) o_acc[c] = zero4;
  float m_run[4] = {NEG_BIG, NEG_BIG, NEG_BIG, NEG_BIG};
  float l_run[4] = {0.f, 0.f, 0.f, 0.f};
  const float LOG2E = 1.4426950408889634f;

  int k_lo = qb - (WIN - 1);
  if (k_lo < 0) k_lo = 0;
  k_lo &= ~31;

  // prologue: stage first KV tile into buffer 0
  ASTAGE(0, k_lo);
  int cur = 0;

  for (int kb = k_lo; kb < qb + 128; kb += 32) {
    VMCNT(0); BARRIER();
    if (kb + 32 < qb + 128) {
      int nbuf = cur ^ 1;
      ASTAGE(nbuf, kb + 32);
    }
    const char* KH = (const char*)KshH[cur];
    const char* KL = (const char*)KshL[cur];
    const char* VB = (const char*)Vsh[cur];

    fragC s[2] = {zero4, zero4};
    __builtin_amdgcn_s_setprio(1);
#pragma unroll
    for (int c = 0; c < 8; ++c) {
      int j = c * 4 + quad;
#pragma unroll
      for (int gg = 0; gg < 2; ++gg) {
        int row = gg * 16 + l16;
        int off = (row * 32 + (j ^ (row & 31))) * 16;
        fragAB kh = *(const fragAB*)(KH + off);
        fragAB kl = *(const fragAB*)(KL + off);
        s[gg] = __builtin_amdgcn_mfma_f32_16x16x32_bf16(qfl[c], kh, s[gg], 0, 0, 0);
        s[gg] = __builtin_amdgcn_mfma_f32_16x16x32_bf16(qfh[c], kl, s[gg], 0, 0, 0);
        s[gg] = __builtin_amdgcn_mfma_f32_16x16x32_bf16(qfh[c], kh, s[gg], 0, 0, 0);
      }
    }
    __builtin_amdgcn_s_setprio(0);

    float p[2][4], alpha[4];
#pragma unroll
    for (int r = 0; r < 4; ++r) {
      int qi = qw + quad * 4 + r;
      bool vld[2];
      float mx = NEG_BIG;
#pragma unroll
      for (int gg = 0; gg < 2; ++gg) {
        int ki = kb + gg * 16 + l16;
        vld[gg] = (ki <= qi) && (qi - ki < WIN);
        mx = fmaxf(mx, vld[gg] ? s[gg][r] : NEG_BIG);
      }
      mx = fmaxf(mx, __shfl_xor(mx, 1));
      mx = fmaxf(mx, __shfl_xor(mx, 2));
      mx = fmaxf(mx, __shfl_xor(mx, 4));
      mx = fmaxf(mx, __shfl_xor(mx, 8));
      float mn = fmaxf(m_run[r], mx);
      float a  = exp2f(fmaxf(m_run[r] - mn, -80.f) * LOG2E);
      float rs = 0.f;
#pragma unroll
      for (int gg = 0; gg < 2; ++gg) {
        float e = vld[gg] ? exp2f(fmaxf(s[gg][r] - mn, -80.f) * LOG2E) : 0.f;
        p[gg][r] = e;
        rs += e;
      }
      rs += __shfl_xor(rs, 1);
      rs += __shfl_xor(rs, 2);
      rs += __shfl_xor(rs, 4);
      rs += __shfl_xor(rs, 8);
      l_run[r] = l_run[r] * a + rs;
      m_run[r] = mn;
      alpha[r] = a;
    }
#pragma unroll
    for (int c = 0; c < 16; ++c)
#pragma unroll
      for (int r = 0; r < 4; ++r) o_acc[c][r] *= alpha[r];

    bf16_t* Pw = Plds[wave];
#pragma unroll
    for (int r = 0; r < 4; ++r)
#pragma unroll
      for (int gg = 0; gg < 2; ++gg)
        Pw[(quad * 4 + r) * 32 + gg * 16 + l16] = __float2bfloat16(p[gg][r]);
    fragAB pf = *(const fragAB*)((const char*)Pw + l16 * 64 + quad * 16);

    __builtin_amdgcn_s_setprio(1);
#pragma unroll
    for (int c = 0; c < 16; ++c) {
      int d = c * 16 + l16;
      int offv = (d * 4 + (quad ^ (d & 3))) * 16;
      fragAB vf = *(const fragAB*)(VB + offv);
      o_acc[c] = __builtin_amdgcn_mfma_f32_16x16x32_bf16(pf, vf, o_acc[c], 0, 0, 0);
    }
    __builtin_amdgcn_s_setprio(0);
    cur ^= 1;
  }

  float inv_l[4];
#pragma unroll
  for (int r = 0; r < 4; ++r) inv_l[r] = 1.0f / l_run[r];
#pragma unroll
  for (int c = 0; c < 16; ++c)
#pragma unroll
    for (int r = 0; r < 4; ++r) {
      int row = qw + quad * 4 + r;
      int col = h * DHEAD + c * 16 + l16;
      Aout[(size_t)row * (NHQ * DHEAD) + col] = __float2bfloat16(o_acc[c][r] * inv_l[r]);
    }
#undef ASTAGE
}

// ---------------------------------------------------------------------------
extern "C" void kernel_launch(void* const* d_in, const int* in_sizes, int n_in,
                              void* d_out, int out_size, void* d_ws, size_t ws_size,
                              hipStream_t stream) {
  const float* hid  = (const float*)d_in[0];
  const float* w_q  = (const float*)d_in[1];
  const float* w_k  = (const float*)d_in[2];
  const float* w_v  = (const float*)d_in[3];
  const float* w_o  = (const float*)d_in[4];
  const float* qnw  = (const float*)d_in[5];
  const float* knw  = (const float*)d_in[6];
  const float* cosb = (const float*)d_in[7];
  const float* sinb = (const float*)d_in[8];
  float* outp = (float*)d_out;

  // Workspace (bf16 slots, M1 = 1<<20), peak 52M slots = 104 MiB:
  //  [ 0: 8M)  hidh  -> qh  (after qkv gemm)
  //  [ 8:16M)  hidl  -> ql
  //  [16:22M)  wTh (3072x2048) -> kh[16:18M), kl[18:20M), vt[20:22M) after gemm
  //  [22:28M)  wTl   -> woT[22:26M) after gemm  (LIFETIME: woT writes must
  //            come AFTER gemm_split2 — rounds 6/7 bug wrote it at phase 0)
  //  [28:52M)  projqkv f32 (4096x3072) -> aout[28:36M) after norms
  const size_t M1 = 1048576;
  bf16_t* w = (bf16_t*)d_ws;
  bf16_t* hidh  = w;
  bf16_t* qh    = w;                         // alias hidh
  bf16_t* hidl  = w + 8 * M1;
  bf16_t* ql    = w + 8 * M1;                // alias hidl
  bf16_t* wTh   = w + 16 * M1;
  bf16_t* kh    = w + 16 * M1;               // alias wTh
  bf16_t* kl    = w + 18 * M1;
  bf16_t* vt    = w + 20 * M1;
  bf16_t* wTl   = w + 22 * M1;
  bf16_t* woT   = w + 22 * M1;               // alias wTl
  float*  projqkv = (float*)(w + 28 * M1);
  bf16_t* aout  = w + 28 * M1;               // alias projqkv (after norms)

  // phase 0: ONE dispatch — split hidden + split-transpose [wq|wk|wv]
  prep0<<<4096 + 96 * 64, 256, 0, stream>>>(
      hid, hidh, hidl, w_q, w_k, w_v, wTh, wTl);

  // phase 1: fused q+k+v split projection, pipelined 256x192 tiles
  //          grid 16x16 = 256 blocks = exactly 1 per CU, 12 waves (3/SIMD)
  gemm_split2<<<dim3(NQKV / 192, S_LEN / 256), 768, 0, stream>>>(
      hidh, hidl, wTh, wTl, projqkv, S_LEN, NQKV, HDIM);

  // phase 2: ONE dispatch — q/k norm+rope, v norm+transpose, w_o transpose
  //          (woT aliases wTl: safe only AFTER gemm_split2)
  prep2<<<10240 + 256 + 4096, 256, 0, stream>>>(
      projqkv, qnw, knw, cosb, sinb, qh, ql, kh, kl, vt, w_o, woT);

  // phase 3: attention -> aout (dead projqkv region)
  //          grid 32x8 = 256 blocks = exactly 1 per CU
  attn_split<<<dim3(S_LEN / 128, NHQ), 512, 0, stream>>>(qh, ql, kh, kl, vt, aout);

  // phase 4: output projection -> fp32 d_out, pipelined 256x128 tiles
  gemm_bt2<<<dim3(HDIM / 128, S_LEN / 256), 512, 0, stream>>>(
      aout, woT, outp, S_LEN, HDIM, NHQ * DHEAD);
}